// Round 8
// baseline (847.430 us; speedup 1.0000x reference)
//
#include <hip/hip_runtime.h>
#include <math.h>

// GAT model, MI355X. Round 21: k_dec "denseL" — weights staged into LDS via
// double-buffered 4KB tiles, ONE float4/thread staging register (no arrays ->
// no spill, unlike R19's r[16]). Hot loop: ds_read_b32 weights (conflict-free)
// + b128 act broadcasts + FMA; zero global access. Diagnosis basis: R20
// falsified the occupancy theory (occ 52%, still 216us, VALUBusy 36%) -> the
// per-thread global weight stream's latency x queue-depth is the invariant
// cost across all 200-265us designs. Acts stride-20 (aligned, de-conflicted).

typedef long long ll;
typedef unsigned short u16;

__device__ __forceinline__ float bf(u16 u) { return __uint_as_float(((unsigned)u) << 16); }
__device__ __forceinline__ u16 f2bf(float f) {
  unsigned u = __float_as_uint(f);
  u += 0x7fffu + ((u >> 16) & 1u);   // RNE
  return (u16)(u >> 16);
}
__device__ __forceinline__ float bflo(unsigned u) { return __uint_as_float(u << 16); }
__device__ __forceinline__ float bfhi(unsigned u) { return __uint_as_float(u & 0xffff0000u); }
__device__ __forceinline__ float elu_f(float x) { return x > 0.f ? x : (__expf(x) - 1.f); }

// ---------------- probe: is edge_index int32 (flag=1) or int64 (flag=0)?
__global__ void k_probe64(const int* __restrict__ ei, int cnt, int* __restrict__ flag) {
  int tid = threadIdx.x;
  int nz = 0;
  for (int k = tid; k < cnt; k += 256) {
    if (ei[2 * k + 1] != 0) nz = 1;
  }
  if (nz) atomicOr(flag, 1);
}

// ---------------- stats of x ----------------
__global__ void k_stats_x(const float* __restrict__ x, int N, double* __restrict__ s0) {
  __shared__ float red[256];
  int tid = threadIdx.x;
  int c = tid & 63;
  float s = 0.f, ss = 0.f;
  for (int r = blockIdx.x * 4 + (tid >> 6); r < N; r += gridDim.x * 4) {
    float v = x[r * 64 + c];
    s += v; ss += v * v;
  }
  red[tid] = s; __syncthreads();
  if (tid < 64) atomicAdd(&s0[tid], (double)(red[tid] + red[tid + 64] + red[tid + 128] + red[tid + 192]));
  __syncthreads();
  red[tid] = ss; __syncthreads();
  if (tid < 64) atomicAdd(&s0[64 + tid], (double)(red[tid] + red[tid + 64] + red[tid + 128] + red[tid + 192]));
}

__device__ __forceinline__ void norm_coeffs(const double* s, int tid, int N,
                                            const float* w, const float* b,
                                            float* na, float* nb) {
  double invN = 1.0 / (double)N;
  double mean = s[tid] * invN;
  double var = s[64 + tid] * invN - mean * mean;
  float a = rsqrtf((float)var + 1e-5f) * w[tid];
  na[tid] = a; nb[tid] = b[tid] - (float)mean * a;
}

// ---------------- encoder layer ----------------
template <bool ACT>
__global__ void k_enc(const float* __restrict__ in, const float* __restrict__ w,
                      const float* __restrict__ b, const float* __restrict__ Wg,
                      const double* __restrict__ sin_, float* __restrict__ out,
                      double* __restrict__ sout, int N) {
  __shared__ float W[4096];
  __shared__ float hl[4][64];
  __shared__ float na[64], nb[64];
  __shared__ float red[256];
  int tid = threadIdx.x;
  if (tid < 64) norm_coeffs(sin_, tid, N, w, b, na, nb);
  for (int k = tid; k < 4096; k += 256) W[k] = Wg[k];
  __syncthreads();
  int nl = tid >> 6, j = tid & 63;
  int Nc = (N + 3) >> 2;
  float ssum = 0.f, ssq = 0.f;
  for (int chunk = blockIdx.x; chunk < Nc; chunk += gridDim.x) {
    int node = chunk * 4 + nl;
    bool valid = node < N;
    float hv = valid ? (in[node * 64 + j] * na[j] + nb[j]) : 0.f;
    hl[nl][j] = ACT ? elu_f(hv) : hv;
    __syncthreads();
    if (valid) {
      float acc = 0.f;
#pragma unroll
      for (int i = 0; i < 64; i++) acc += hl[nl][i] * W[i * 64 + j];
      out[node * 64 + j] = acc;
      ssum += acc; ssq += acc * acc;
    }
    __syncthreads();
  }
  red[tid] = ssum; __syncthreads();
  if (tid < 64) atomicAdd(&sout[tid], (double)(red[tid] + red[tid + 64] + red[tid + 128] + red[tid + 192]));
  __syncthreads();
  red[tid] = ssq; __syncthreads();
  if (tid < 64) atomicAdd(&sout[64 + tid], (double)(red[tid] + red[tid + 64] + red[tid + 128] + red[tid + 192]));
}

// ---------------- encoder layer 3 + xl(bf16)/xr projections ----------------
__global__ void k_enc3(const float* __restrict__ tB, const float* __restrict__ w,
                       const float* __restrict__ b, const float* __restrict__ Wlw,
                       const float* __restrict__ Wrw, const double* __restrict__ s2,
                       float* __restrict__ jk, u16* __restrict__ xlb, float* __restrict__ xr,
                       int N) {
  __shared__ float WL[4096], WR[4096];
  __shared__ float hl[4][64];
  __shared__ float na[64], nb[64];
  int tid = threadIdx.x;
  if (tid < 64) norm_coeffs(s2, tid, N, w, b, na, nb);
  for (int k = tid; k < 4096; k += 256) { WL[k] = Wlw[k]; WR[k] = Wrw[k]; }
  __syncthreads();
  int nl = tid >> 6, j = tid & 63;
  int Nc = (N + 3) >> 2;
  for (int chunk = blockIdx.x; chunk < Nc; chunk += gridDim.x) {
    int node = chunk * 4 + nl;
    bool valid = node < N;
    float h3 = valid ? elu_f(tB[node * 64 + j] * na[j] + nb[j]) : 0.f;
    hl[nl][j] = h3;
    __syncthreads();
    if (valid) {
      jk[node * 64 + j] = h3;
      float al = 0.f, ar = 0.f;
#pragma unroll
      for (int i = 0; i < 64; i++) {
        float h = hl[nl][i];
        al += h * WL[i * 64 + j];
        ar += h * WR[i * 64 + j];
      }
      xlb[node * 64 + j] = f2bf(al);
      xr[node * 64 + j] = ar;
    }
    __syncthreads();
  }
}

// ---------------- degree count: 8-way XCD-replicated ----------------
__global__ void k_deg(const int* __restrict__ ei, int* __restrict__ deg8, int E, int N,
                      const int* __restrict__ i32flag) {
  int e = blockIdx.x * 256 + threadIdx.x;
  if (e >= E + N) return;
  int r = blockIdx.x & 7;
  int dst;
  if (e < E) {
    if (*i32flag) dst = ei[E + e];
    else { const ll* el = (const ll*)ei; dst = (int)el[E + e]; }
  } else dst = e - E;
  atomicAdd(&deg8[r * N + dst], 1);
}

// ---------------- coalesced scan: A (block sums), B (scan sums), C (final) --
__global__ void k_scanA(const int* __restrict__ deg8, int* __restrict__ bsum, int N) {
  __shared__ int red[256];
  int tid = threadIdx.x;
  int base = blockIdx.x * 1024;
  int s = 0;
#pragma unroll
  for (int q = 0; q < 4; q++) {
    int n = base + q * 256 + tid;
    if (n < N) {
#pragma unroll
      for (int r = 0; r < 8; r++) s += deg8[r * N + n];
    }
  }
  red[tid] = s; __syncthreads();
  for (int o = 128; o > 0; o >>= 1) {
    if (tid < o) red[tid] += red[tid + o];
    __syncthreads();
  }
  if (tid == 0) bsum[blockIdx.x] = red[0];
}

__global__ void k_scanB(const int* __restrict__ bsum, int* __restrict__ bscan,
                        int* __restrict__ offs, int NB, int N) {
  if (threadIdx.x == 0) {
    int run = 0;
    for (int b = 0; b < NB; b++) { bscan[b] = run; run += bsum[b]; }
    offs[N] = run;
  }
}

__global__ void k_scanC(const int* __restrict__ deg8, const int* __restrict__ bscan,
                        int* __restrict__ offs, int* __restrict__ cursor8, int N) {
  __shared__ int dt[1024];
  __shared__ int tp[256];
  int tid = threadIdx.x;
  int base = blockIdx.x * 1024;
#pragma unroll
  for (int q = 0; q < 4; q++) {
    int n = base + q * 256 + tid;
    int s = 0;
    if (n < N) {
#pragma unroll
      for (int r = 0; r < 8; r++) s += deg8[r * N + n];
    }
    dt[q * 256 + tid] = s;
  }
  __syncthreads();
  int t4 = tid * 4;
  int l0 = dt[t4], l1 = dt[t4 + 1], l2 = dt[t4 + 2], l3 = dt[t4 + 3];
  int tot = l0 + l1 + l2 + l3;
  tp[tid] = tot; __syncthreads();
  for (int o = 1; o < 256; o <<= 1) {
    int v = (tid >= o) ? tp[tid - o] : 0;
    __syncthreads();
    tp[tid] += v;
    __syncthreads();
  }
  int run = bscan[blockIdx.x] + tp[tid] - tot;
#pragma unroll
  for (int k = 0; k < 4; k++) {
    int n = base + t4 + k;
    if (n < N) {
      offs[n] = run;
      int b = run;
#pragma unroll
      for (int r = 0; r < 8; r++) { cursor8[r * N + n] = b; b += deg8[r * N + n]; }
      run = b;
    }
  }
}

// ---------------- scatter: src + bf16x8 eattr into CSR order ----------------
__global__ void k_scatter(const int* __restrict__ ei, const float* __restrict__ eattr,
                          int* __restrict__ cursor8, int* __restrict__ csr_src,
                          uint4* __restrict__ ea2, int E, int N,
                          const int* __restrict__ i32flag) {
  int e = blockIdx.x * 256 + threadIdx.x;
  if (e >= E + N) return;
  int r = blockIdx.x & 7;
  int src, dst;
  u16 p[8];
  if (e < E) {
    if (*i32flag) { src = ei[e]; dst = ei[E + e]; }
    else { const ll* el = (const ll*)ei; src = (int)el[e]; dst = (int)el[E + e]; }
    const float* ea = eattr + (size_t)e * 7;
#pragma unroll
    for (int q = 0; q < 7; q++) p[q] = f2bf(ea[q]);
    p[7] = 0;
  } else {
    src = e - E; dst = src;
#pragma unroll
    for (int q = 0; q < 8; q++) p[q] = 0;
    p[6] = 0x3F80;   // FILL: e_6 = 1.0
  }
  int pos = atomicAdd(&cursor8[r * N + dst], 1);
  csr_src[pos] = src;
  uint4 U;
  U.x = ((unsigned)p[1] << 16) | p[0];
  U.y = ((unsigned)p[3] << 16) | p[2];
  U.z = ((unsigned)p[5] << 16) | p[4];
  U.w = ((unsigned)p[7] << 16) | p[6];
  ea2[pos] = U;
}

// ---------------- fused GAT: persistent, wave/node, 16 lanes/edge ----------
__global__ void k_gat(const int* __restrict__ offs, const int* __restrict__ csr_src,
                      const uint4* __restrict__ ea2,
                      const u16* __restrict__ xlb, const float* __restrict__ xr,
                      const float* __restrict__ Wew, const float* __restrict__ attw,
                      float* __restrict__ gat, double* __restrict__ s3, int N) {
  __shared__ float sb[4][64];
  int tid = threadIdx.x;
  int wid = tid >> 6;          // wave id in block = node slot
  int lane = tid & 63;
  int g = lane >> 4;           // edge slot within 4-edge batch
  int l = lane & 15;           // channel quad index: owns channels 4l..4l+3
  int Nc = (N + 3) >> 2;

  // per-lane constants in registers
  float4 wq[7];
#pragma unroll
  for (int q = 0; q < 7; q++) wq[q] = *(const float4*)(Wew + q * 64 + 4 * l);
  float4 attv = *(const float4*)(attw + 4 * l);

  // running per-channel stats (meaningful on g==0 lanes only)
  float ts0 = 0.f, ts1 = 0.f, ts2 = 0.f, ts3 = 0.f;
  float tq0 = 0.f, tq1 = 0.f, tq2 = 0.f, tq3 = 0.f;

  for (int chunk = blockIdx.x; chunk < Nc; chunk += gridDim.x) {
    int node = chunk * 4 + wid;
    if (node >= N) continue;
    float4 xrv = *(const float4*)(xr + node * 64 + 4 * l);
    int st = offs[node];
    int dg = offs[node + 1] - st;
    int nb = (dg + 3) >> 2;
    float sden = 0.f;
    float a0 = 0.f, a1 = 0.f, a2 = 0.f, a3 = 0.f;

    // ---- pipeline prologue: batches 0 and 1 ptr-loads, batch 0 gather ----
    int i0 = st + g;
    int scC = csr_src[i0];           // batch 0 src
    uint4 UC = ea2[i0];              // batch 0 eattr
    int scN = csr_src[i0 + 4];       // batch 1 src (pad-safe)
    uint4 UN = ea2[i0 + 4];          // batch 1 eattr
    scC = ((unsigned)scC < (unsigned)N) ? scC : 0;
    uint2 xwC = *(const uint2*)(xlb + scC * 64 + 4 * l);   // batch 0 gather

    for (int b = 0; b < nb; b++) {
      // stage A: issue ptr loads for batch b+2 (max idx st+dg+10 < pad 16)
      int iA = st + (b + 2) * 4 + g;
      int scA = csr_src[iA];
      uint4 UA = ea2[iA];
      // stage B: issue gather for batch b+1 (scN issued one iteration ago)
      int scg = ((unsigned)scN < (unsigned)N) ? scN : 0;
      uint2 xwN = *(const uint2*)(xlb + scg * 64 + 4 * l);
      // stage C: compute batch b from xwC/UC (issued >=1 iteration ago)
      bool valid = (b * 4 + g) < dg;
      float x0 = bflo(xwC.x), x1 = bfhi(xwC.x), x2 = bflo(xwC.y), x3 = bfhi(xwC.y);
      float e0 = bflo(UC.x), e1 = bfhi(UC.x), e2 = bflo(UC.y), e3 = bfhi(UC.y);
      float e4 = bflo(UC.z), e5 = bfhi(UC.z), e6 = bflo(UC.w);
      float m0 = x0 + xrv.x + e0*wq[0].x + e1*wq[1].x + e2*wq[2].x + e3*wq[3].x + e4*wq[4].x + e5*wq[5].x + e6*wq[6].x;
      float m1 = x1 + xrv.y + e0*wq[0].y + e1*wq[1].y + e2*wq[2].y + e3*wq[3].y + e4*wq[4].y + e5*wq[5].y + e6*wq[6].y;
      float m2 = x2 + xrv.z + e0*wq[0].z + e1*wq[1].z + e2*wq[2].z + e3*wq[3].z + e4*wq[4].z + e5*wq[5].z + e6*wq[6].z;
      float m3 = x3 + xrv.w + e0*wq[0].w + e1*wq[1].w + e2*wq[2].w + e3*wq[3].w + e4*wq[4].w + e5*wq[5].w + e6*wq[6].w;
      m0 = m0 > 0.f ? m0 : 0.2f * m0;
      m1 = m1 > 0.f ? m1 : 0.2f * m1;
      m2 = m2 > 0.f ? m2 : 0.2f * m2;
      m3 = m3 > 0.f ? m3 : 0.2f * m3;
      float pp = m0 * attv.x + m1 * attv.y + m2 * attv.z + m3 * attv.w;
      pp += __shfl_xor(pp, 1, 64);     // quad reduce: 4 lanes = 16 channels = head
      pp += __shfl_xor(pp, 2, 64);
      float ex = valid ? __expf(pp) : 0.f;
      sden += ex;
      a0 += ex * x0; a1 += ex * x1; a2 += ex * x2; a3 += ex * x3;
      // rotate pipeline registers
      xwC = xwN; UC = UN; UN = UA; scN = scA;
    }
    // sum over the 4 edge-groups
    a0 += __shfl_xor(a0, 16, 64); a0 += __shfl_xor(a0, 32, 64);
    a1 += __shfl_xor(a1, 16, 64); a1 += __shfl_xor(a1, 32, 64);
    a2 += __shfl_xor(a2, 16, 64); a2 += __shfl_xor(a2, 32, 64);
    a3 += __shfl_xor(a3, 16, 64); a3 += __shfl_xor(a3, 32, 64);
    sden += __shfl_xor(sden, 16, 64); sden += __shfl_xor(sden, 32, 64);
    float inv = 1.f / (sden * (float)dg);
    float val0 = a0 * inv, val1 = a1 * inv, val2 = a2 * inv, val3 = a3 * inv;
    if (g == 0) {
      float4 o = make_float4(val0, val1, val2, val3);
      *(float4*)(gat + node * 64 + 4 * l) = o;
      ts0 += val0; ts1 += val1; ts2 += val2; ts3 += val3;
      tq0 += val0 * val0; tq1 += val1 * val1; tq2 += val2 * val2; tq3 += val3 * val3;
    }
  }

  // ---- block-exit stats reduction: transpose to per-channel, 128 atomics ----
  if (g == 0) {
    sb[wid][4 * l + 0] = ts0; sb[wid][4 * l + 1] = ts1;
    sb[wid][4 * l + 2] = ts2; sb[wid][4 * l + 3] = ts3;
  }
  __syncthreads();
  if (tid < 64) {
    float v = sb[0][tid] + sb[1][tid] + sb[2][tid] + sb[3][tid];
    atomicAdd(&s3[tid], (double)v);
  }
  __syncthreads();
  if (g == 0) {
    sb[wid][4 * l + 0] = tq0; sb[wid][4 * l + 1] = tq1;
    sb[wid][4 * l + 2] = tq2; sb[wid][4 * l + 3] = tq3;
  }
  __syncthreads();
  if (tid < 64) {
    float v = sb[0][tid] + sb[1][tid] + sb[2][tid] + sb[3][tid];
    atomicAdd(&s3[64 + tid], (double)v);
  }
}

// ---------------- atomic fallback (if CSR doesn't fit) ----------------
__global__ void k_edge2(const int* __restrict__ ei, const float* __restrict__ eattr,
                        const u16* __restrict__ xlb, const float* __restrict__ xr,
                        const float* __restrict__ Wew, const float* __restrict__ attw,
                        float* __restrict__ agg, float* __restrict__ denom,
                        int* __restrict__ deg, int E, int N,
                        const int* __restrict__ i32flag) {
  __shared__ float sWe[448];
  __shared__ float satt[64];
  int tid = threadIdx.x;
  for (int k = tid; k < 448; k += 256) sWe[k] = Wew[k];
  if (tid < 64) satt[tid] = attw[tid];
  __syncthreads();
  int e = blockIdx.x * 4 + (tid >> 6);
  if (e >= E + N) return;
  int lane = tid & 63;
  int src, dst;
  if (e < E) {
    if (*i32flag) { src = ei[e]; dst = ei[E + e]; }
    else { const ll* el = (const ll*)ei; src = (int)el[e]; dst = (int)el[E + e]; }
  } else { src = e - E; dst = src; }
  float xlv = bf(xlb[src * 64 + lane]);
  float m = xlv + xr[dst * 64 + lane];
  if (e < E) {
#pragma unroll
    for (int k = 0; k < 7; k++) m += eattr[e * 7 + k] * sWe[k * 64 + lane];
  } else {
    m += sWe[6 * 64 + lane];
  }
  float lr = m > 0.f ? m : 0.2f * m;
  float p = lr * satt[lane];
  p += __shfl_xor(p, 1, 64);
  p += __shfl_xor(p, 2, 64);
  p += __shfl_xor(p, 4, 64);
  p += __shfl_xor(p, 8, 64);
  float ex = __expf(p);
  atomicAdd(&agg[dst * 64 + lane], ex * xlv);
  if ((lane & 15) == 0) atomicAdd(&denom[dst * 4 + (lane >> 4)], ex);
  if (lane == 0) atomicAdd(&deg[dst], 1);
}

__global__ void k_gatnorm(float* __restrict__ agg, const float* __restrict__ denom,
                          const int* __restrict__ deg, double* __restrict__ s3, int N) {
  __shared__ float red[256];
  int tid = threadIdx.x;
  int idx = blockIdx.x * 256 + tid;
  float v = 0.f;
  if (idx < N * 64) {
    int n = idx >> 6, c = idx & 63, h = c >> 4;
    v = agg[idx] / (denom[n * 4 + h] * (float)deg[n]);
    agg[idx] = v;
  }
  red[tid] = v; __syncthreads();
  if (tid < 64) atomicAdd(&s3[tid], (double)(red[tid] + red[tid + 64] + red[tid + 128] + red[tid + 192]));
  __syncthreads();
  red[tid] = v * v; __syncthreads();
  if (tid < 64) atomicAdd(&s3[64 + tid], (double)(red[tid] + red[tid + 64] + red[tid + 128] + red[tid + 192]));
}

// ---------------- h4 = elu(h3 + inorm(gat)) ----------------
__global__ void k_h4(const float* __restrict__ jk, const float* __restrict__ gat,
                     const float* __restrict__ gn_w, const float* __restrict__ gn_b,
                     const double* __restrict__ s3, float* __restrict__ h4, int N) {
  __shared__ float na[64], nb[64];
  int tid = threadIdx.x;
  if (tid < 64) norm_coeffs(s3, tid, N, gn_w, gn_b, na, nb);
  __syncthreads();
  int idx = blockIdx.x * 256 + tid;
  if (idx >= N * 64) return;
  int c = idx & 63;
  h4[idx] = elu_f(jk[idx] + gat[idx] * na[c] + nb[c]);
}

// ---------------- decoder: denseL — LDS-staged weight tiles, 16-node chunks -
// Weights: double-buffered 1024-float tiles; each thread stages ONE float4
// (r = 4 VGPRs, no arrays -> no spill). Per tile: issue next tile's global
// float4, compute current from LDS (ds_read_b32 weights, conflict-free:
// lane j consecutive; act rows stride-20, b128 broadcasts), write r to the
// other buffer, barrier. Hot loop has zero global accesses.
template <int LIN, int LOUT, int TI, bool ACT>
__device__ __forceinline__ void denseL(const float* __restrict__ W, const float* __restrict__ B,
                                       const float* __restrict__ inT, float* __restrict__ outT,
                                       float* __restrict__ wbuf, int tid) {
  constexpr int T = LIN / TI;          // tiles
  constexpr int TE = TI * LOUT;        // floats per tile (<=1024)
  constexpr int NG = 256 / LOUT;       // node groups
  constexpr int NPG = 16 / NG;         // nodes per thread: 16,8,4,2,1
  int j = tid % LOUT;
  int g = tid / LOUT;
  int n0 = g * NPG;
  float acc[NPG];
  float bj = B[j];
#pragma unroll
  for (int m = 0; m < NPG; m++) acc[m] = bj;
  // prologue: stage tile 0
  float4 r = make_float4(0.f, 0.f, 0.f, 0.f);
  if (tid * 4 < TE) {
    r = *(const float4*)(W + tid * 4);
    *(float4*)(wbuf + tid * 4) = r;
  }
  __syncthreads();
  for (int t = 0; t < T; t++) {
    const float* wb = wbuf + (t & 1) * 1024;
    if (t + 1 < T && tid * 4 < TE) r = *(const float4*)(W + (t + 1) * TE + tid * 4);
    int ib = t * TI;
#pragma unroll 4
    for (int di = 0; di < TI; di++) {
      float w = wb[di * LOUT + j];
      const float* row = inT + (ib + di) * 20 + n0;
      if constexpr (NPG >= 4) {
#pragma unroll
        for (int q = 0; q < NPG / 4; q++) {
          float4 a = *(const float4*)(row + q * 4);
          acc[q * 4 + 0] += a.x * w;
          acc[q * 4 + 1] += a.y * w;
          acc[q * 4 + 2] += a.z * w;
          acc[q * 4 + 3] += a.w * w;
        }
      } else {
#pragma unroll
        for (int m = 0; m < NPG; m++) acc[m] += row[m] * w;
      }
    }
    if (t + 1 < T && tid * 4 < TE) *(float4*)(wbuf + ((t + 1) & 1) * 1024 + tid * 4) = r;
    __syncthreads();
  }
#pragma unroll
  for (int m = 0; m < NPG; m++) outT[j * 20 + n0 + m] = ACT ? elu_f(acc[m]) : acc[m];
}

__global__ void k_dec(const float* __restrict__ jk, const float* __restrict__ h4,
                      const float* __restrict__ dW1, const float* __restrict__ db1,
                      const float* __restrict__ dW2, const float* __restrict__ db2,
                      const float* __restrict__ dW3, const float* __restrict__ db3,
                      const float* __restrict__ dW4, const float* __restrict__ db4,
                      const float* __restrict__ dW5, const float* __restrict__ db5,
                      const float* __restrict__ dW6, const float* __restrict__ db6,
                      float* __restrict__ outdec, int N) {
  __shared__ float A[256 * 20];    // 20 KB  (rows = channels, 16 nodes + pad4)
  __shared__ float Bb[128 * 20];   // 10 KB
  __shared__ float wbuf[2 * 1024]; // 8 KB double-buffered weight tiles
  int tid = threadIdx.x;
  int Nc = (N + 15) >> 4;
  for (int chunk = blockIdx.x; chunk < Nc; chunk += gridDim.x) {
    int g0 = chunk * 16;
    for (int k = tid; k < 16 * 128; k += 256) {
      int i = k & 127, node = k >> 7;
      int gn = g0 + node;
      float v = 0.f;
      if (gn < N) v = (i < 64) ? jk[gn * 64 + i] : h4[gn * 64 + (i - 64)];
      Bb[i * 20 + node] = v;
    }
    __syncthreads();
    denseL<128, 256, 4, true>(dW1, db1, Bb, A, wbuf, tid); __syncthreads();
    denseL<256, 128, 8, true>(dW2, db2, A, Bb, wbuf, tid); __syncthreads();
    denseL<128, 64, 16, true>(dW3, db3, Bb, A, wbuf, tid); __syncthreads();
    denseL<64, 32, 32, true>(dW4, db4, A, Bb, wbuf, tid); __syncthreads();
    denseL<32, 16, 32, true>(dW5, db5, Bb, A, wbuf, tid); __syncthreads();
    // final 16 -> 2
    if (tid < 32) {
      int node = tid >> 1, jx = tid & 1;
      int gn = g0 + node;
      if (gn < N) {
        float s = db6[jx];
#pragma unroll
        for (int i = 0; i < 16; i++) s += A[i * 20 + node] * dW6[i * 2 + jx];
        outdec[gn * 2 + jx] = s;
      }
    }
    __syncthreads();
  }
}

// ---------------- recon MLP: 16-node chunks, transposed LDS ----------------
__global__ void k_recon(const float* __restrict__ h4,
                        const float* __restrict__ rW1, const float* __restrict__ rb1,
                        const float* __restrict__ rW2, const float* __restrict__ rb2,
                        const float* __restrict__ rW3, const float* __restrict__ rb3,
                        float* __restrict__ outrec, int N) {
  __shared__ float W1[4096], W2[4096], W3[4096];
  __shared__ float b1[64], b2[64], b3[64];
  __shared__ float A[64 * 16], Bb[64 * 16];
  int tid = threadIdx.x;
  for (int k = tid; k < 4096; k += 256) { W1[k] = rW1[k]; W2[k] = rW2[k]; W3[k] = rW3[k]; }
  if (tid < 64) { b1[tid] = rb1[tid]; b2[tid] = rb2[tid]; b3[tid] = rb3[tid]; }
  __syncthreads();
  int j = tid & 63, g = tid >> 6;
  int Nc = (N + 15) >> 4;
  for (int chunk = blockIdx.x; chunk < Nc; chunk += gridDim.x) {
    int g0 = chunk * 16;
    for (int k = tid; k < 16 * 64; k += 256) {
      int i = k & 63, node = k >> 6;
      int gn = g0 + node;
      A[i * 16 + node] = (gn < N) ? h4[gn * 64 + i] : 0.f;
    }
    __syncthreads();
    {
      float a0 = b1[j], a1 = b1[j], a2 = b1[j], a3 = b1[j];
#pragma unroll 4
      for (int i = 0; i < 64; i++) {
        float w = W1[i * 64 + j];
        float4 a = *(const float4*)(&A[i * 16 + g * 4]);
        a0 += a.x * w; a1 += a.y * w; a2 += a.z * w; a3 += a.w * w;
      }
      Bb[j * 16 + g * 4 + 0] = elu_f(a0);
      Bb[j * 16 + g * 4 + 1] = elu_f(a1);
      Bb[j * 16 + g * 4 + 2] = elu_f(a2);
      Bb[j * 16 + g * 4 + 3] = elu_f(a3);
    }
    __syncthreads();
    {
      float a0 = b2[j], a1 = b2[j], a2 = b2[j], a3 = b2[j];
#pragma unroll 4
      for (int i = 0; i < 64; i++) {
        float w = W2[i * 64 + j];
        float4 a = *(const float4*)(&Bb[i * 16 + g * 4]);
        a0 += a.x * w; a1 += a.y * w; a2 += a.z * w; a3 += a.w * w;
      }
      A[j * 16 + g * 4 + 0] = elu_f(a0);
      A[j * 16 + g * 4 + 1] = elu_f(a1);
      A[j * 16 + g * 4 + 2] = elu_f(a2);
      A[j * 16 + g * 4 + 3] = elu_f(a3);
    }
    __syncthreads();
    {
      float a0 = b3[j], a1 = b3[j], a2 = b3[j], a3 = b3[j];
#pragma unroll 4
      for (int i = 0; i < 64; i++) {
        float w = W3[i * 64 + j];
        float4 a = *(const float4*)(&A[i * 16 + g * 4]);
        a0 += a.x * w; a1 += a.y * w; a2 += a.z * w; a3 += a.w * w;
      }
      float o[4] = {a0, a1, a2, a3};
#pragma unroll
      for (int u = 0; u < 4; u++) {
        int gn = g0 + g * 4 + u;
        if (gn < N) outrec[gn * 64 + j] = o[u];
      }
    }
    __syncthreads();
  }
}

// ---------------- sentinel ----------------
__global__ void k_sentinel(float* __restrict__ out, float v) {
  if (threadIdx.x == 0) out[0] = v;
}

extern "C" void kernel_launch(void* const* d_in, const int* in_sizes, int n_in,
                              void* d_out, int out_size, void* d_ws, size_t ws_size,
                              hipStream_t stream) {
  (void)n_in; (void)out_size;
  const float* x     = (const float*)d_in[0];
  const int*   ei    = (const int*)d_in[1];
  const float* ea    = (const float*)d_in[2];
  const float* pre_w = (const float*)d_in[3];
  const float* pre_b = (const float*)d_in[4];
  const float* eW1   = (const float*)d_in[5];
  const float* en1w  = (const float*)d_in[6];
  const float* en1b  = (const float*)d_in[7];
  const float* eW2   = (const float*)d_in[8];
  const float* en2w  = (const float*)d_in[9];
  const float* en2b  = (const float*)d_in[10];
  const float* Wl    = (const float*)d_in[11];
  const float* Wr    = (const float*)d_in[12];
  const float* Wew   = (const float*)d_in[13];
  const float* attw  = (const float*)d_in[14];
  const float* gn_w  = (const float*)d_in[15];
  const float* gn_b  = (const float*)d_in[16];
  const float* dW1 = (const float*)d_in[17]; const float* db1 = (const float*)d_in[18];
  const float* dW2 = (const float*)d_in[19]; const float* db2 = (const float*)d_in[20];
  const float* dW3 = (const float*)d_in[21]; const float* db3 = (const float*)d_in[22];
  const float* dW4 = (const float*)d_in[23]; const float* db4 = (const float*)d_in[24];
  const float* dW5 = (const float*)d_in[25]; const float* db5 = (const float*)d_in[26];
  const float* dW6 = (const float*)d_in[27]; const float* db6 = (const float*)d_in[28];
  const float* rW1 = (const float*)d_in[29]; const float* rb1 = (const float*)d_in[30];
  const float* rW2 = (const float*)d_in[31]; const float* rb2 = (const float*)d_in[32];
  const float* rW3 = (const float*)d_in[33]; const float* rb3 = (const float*)d_in[34];

  int D  = in_sizes[3];
  int N  = in_sizes[0] / (D > 0 ? D : 1);
  int E  = in_sizes[1] / 2;
  int ED = E > 0 ? in_sizes[2] / E : 0;
  float* outdec = (float*)d_out;
  float* outrec = outdec + (size_t)N * 2;
  if (D != 64 || ED != 7 || in_sizes[14] != 64) {
    k_sentinel<<<1, 64, 0, stream>>>(outdec, 2000.f);
    return;
  }
  int Etot = E + N;

  char* w = (char*)d_ws;
  size_t off = 0;
  auto alloc = [&](size_t bytes) -> void* {
    void* p = w + off;
    off += (bytes + 255) & ~(size_t)255;
    return p;
  };
  const size_t FEATF = (size_t)N * 64 * 4;
  float* B1    = (float*)alloc(FEATF);             // t1 -> gat (or agg fallback)
  size_t ea2_bytes = ((size_t)Etot + 16) * 16;     // +16 pad: pipeline prefetch depth
  size_t b2ext = ea2_bytes > FEATF ? ea2_bytes : FEATF;
  float* B2    = (float*)alloc(b2ext);
  float* jk    = (float*)alloc(FEATF);
  u16*   xlb   = (u16*)  alloc((size_t)N * 64 * 2);
  float* xr    = (float*)alloc(FEATF);
  int*   offs  = (int*)  alloc(((size_t)N + 1) * 4);
  int*   deg8  = (int*)  alloc((size_t)N * 8 * 4);
  int*   cursor8=(int*)  alloc((size_t)N * 8 * 4);
  int*   bsum  = (int*)  alloc(4096);
  int*   bscan = (int*)  alloc(4096);
  double* stats = (double*)alloc(4 * 128 * 8);
  int* i32flag = (int*)alloc(256);
  float* denom = (float*)alloc((size_t)N * 4 * 4);  // fallback only
  size_t base_off = off;
  int* csr_src = (int*)alloc(((size_t)Etot + 16) * 4);  // +16 pad
  size_t csr_off = off;

  double* s0 = stats, *s1 = stats + 128, *s2 = stats + 256, *s3 = stats + 384;
  float* t1 = B1; float* gat = B1; float* agg = B1;
  float* t2 = B2; float* h4 = B2;
  uint4* ea2 = (uint4*)B2;   // aliases t2 (dead after k_enc3)

  bool use_csr = (csr_off <= ws_size);
  if (!use_csr && base_off > ws_size) {
    k_sentinel<<<1, 64, 0, stream>>>(outdec, 1000.f);
    return;
  }

  hipMemsetAsync(stats, 0, 4 * 128 * 8, stream);
  hipMemsetAsync(i32flag, 0, 256, stream);
  hipMemsetAsync(deg8, 0, (size_t)N * 8 * 4, stream);

  int gN64 = (N * 64 + 255) / 256;
  int gE = (Etot + 255) / 256;
  int probeCnt = E < 1024 ? E : 1024;
  int NB = (N + 1023) / 1024;

  k_probe64<<<1, 256, 0, stream>>>(ei, probeCnt, i32flag);
  k_stats_x<<<1024, 256, 0, stream>>>(x, N, s0);
  k_enc<false><<<1024, 256, 0, stream>>>(x, pre_w, pre_b, eW1, s0, t1, s1, N);
  k_enc<true><<<1024, 256, 0, stream>>>(t1, en1w, en1b, eW2, s1, t2, s2, N);
  k_enc3<<<1024, 256, 0, stream>>>(t2, en2w, en2b, Wl, Wr, s2, jk, xlb, xr, N);

  if (use_csr) {
    k_deg<<<gE, 256, 0, stream>>>(ei, deg8, E, N, i32flag);
    k_scanA<<<NB, 256, 0, stream>>>(deg8, bsum, N);
    k_scanB<<<1, 64, 0, stream>>>(bsum, bscan, offs, NB, N);
    k_scanC<<<NB, 256, 0, stream>>>(deg8, bscan, offs, cursor8, N);
    k_scatter<<<gE, 256, 0, stream>>>(ei, ea, cursor8, csr_src, ea2, E, N, i32flag);
    int ggat = 2048;
    int NcG = (N + 3) / 4;
    if (ggat > NcG) ggat = NcG;
    k_gat<<<ggat, 256, 0, stream>>>(offs, csr_src, ea2, xlb, xr, Wew, attw,
                                    gat, s3, N);
  } else {
    hipMemsetAsync(agg, 0, FEATF, stream);
    hipMemsetAsync(denom, 0, (size_t)N * 4 * 4, stream);
    k_edge2<<<(Etot + 3) / 4, 256, 0, stream>>>(ei, ea, xlb, xr, Wew, attw, agg, denom,
                                                deg8, E, N, i32flag);
    k_gatnorm<<<gN64, 256, 0, stream>>>(agg, denom, deg8, s3, N);
  }

  k_h4<<<gN64, 256, 0, stream>>>(jk, gat, gn_w, gn_b, s3, h4, N);
  int NcD = (N + 15) / 16;
  k_dec<<<NcD, 256, 0, stream>>>(jk, h4, dW1, db1, dW2, db2, dW3, db3, dW4, db4,
                                 dW5, db5, dW6, db6, outdec, N);
  k_recon<<<1024, 256, 0, stream>>>(h4, rW1, rb1, rW2, rb2, rW3, rb3, outrec, N);
}

// Round 9
// 682.602 us; speedup vs baseline: 1.2415x; 1.2415x over previous
//
#include <hip/hip_runtime.h>
#include <math.h>

// GAT model, MI355X. Round 22: k_dec rewritten on MFMA (16x16x32 bf16) with
// SPLIT-bf16 weights/acts (hi+lo; 3 MFMAs per tile) => fp32-accurate to
// ~2^-18, isolating fragment-layout risk from accuracy risk. Rationale: 7
// scalar k_dec designs all landed 200-265us (VALUBusy ~33%, every other pipe
// idle; fp32-FMA issue floor alone is 48us) — scalar path exhausted. k_wprep
// pre-swizzles dW1..dW5 into fragment-ordered bf16 hi/lo (B-frag = one
// coalesced b128/lane). Acts ping-pong in LDS [node][LIN+8] bf16 hi/lo
// (aligned, 2-way-conflict-free A-frag b128 reads). Other kernels = R15 build.

typedef long long ll;
typedef unsigned short u16;
typedef float f32x4 __attribute__((ext_vector_type(4)));
typedef short s16x8 __attribute__((ext_vector_type(8)));

__device__ __forceinline__ float bf(u16 u) { return __uint_as_float(((unsigned)u) << 16); }
__device__ __forceinline__ u16 f2bf(float f) {
  unsigned u = __float_as_uint(f);
  u += 0x7fffu + ((u >> 16) & 1u);   // RNE
  return (u16)(u >> 16);
}
__device__ __forceinline__ float bflo(unsigned u) { return __uint_as_float(u << 16); }
__device__ __forceinline__ float bfhi(unsigned u) { return __uint_as_float(u & 0xffff0000u); }
__device__ __forceinline__ float elu_f(float x) { return x > 0.f ? x : (__expf(x) - 1.f); }

// ---------------- probe: is edge_index int32 (flag=1) or int64 (flag=0)?
__global__ void k_probe64(const int* __restrict__ ei, int cnt, int* __restrict__ flag) {
  int tid = threadIdx.x;
  int nz = 0;
  for (int k = tid; k < cnt; k += 256) {
    if (ei[2 * k + 1] != 0) nz = 1;
  }
  if (nz) atomicOr(flag, 1);
}

// ---------------- stats of x ----------------
__global__ void k_stats_x(const float* __restrict__ x, int N, double* __restrict__ s0) {
  __shared__ float red[256];
  int tid = threadIdx.x;
  int c = tid & 63;
  float s = 0.f, ss = 0.f;
  for (int r = blockIdx.x * 4 + (tid >> 6); r < N; r += gridDim.x * 4) {
    float v = x[r * 64 + c];
    s += v; ss += v * v;
  }
  red[tid] = s; __syncthreads();
  if (tid < 64) atomicAdd(&s0[tid], (double)(red[tid] + red[tid + 64] + red[tid + 128] + red[tid + 192]));
  __syncthreads();
  red[tid] = ss; __syncthreads();
  if (tid < 64) atomicAdd(&s0[64 + tid], (double)(red[tid] + red[tid + 64] + red[tid + 128] + red[tid + 192]));
}

__device__ __forceinline__ void norm_coeffs(const double* s, int tid, int N,
                                            const float* w, const float* b,
                                            float* na, float* nb) {
  double invN = 1.0 / (double)N;
  double mean = s[tid] * invN;
  double var = s[64 + tid] * invN - mean * mean;
  float a = rsqrtf((float)var + 1e-5f) * w[tid];
  na[tid] = a; nb[tid] = b[tid] - (float)mean * a;
}

// ---------------- encoder layer ----------------
template <bool ACT>
__global__ void k_enc(const float* __restrict__ in, const float* __restrict__ w,
                      const float* __restrict__ b, const float* __restrict__ Wg,
                      const double* __restrict__ sin_, float* __restrict__ out,
                      double* __restrict__ sout, int N) {
  __shared__ float W[4096];
  __shared__ float hl[4][64];
  __shared__ float na[64], nb[64];
  __shared__ float red[256];
  int tid = threadIdx.x;
  if (tid < 64) norm_coeffs(sin_, tid, N, w, b, na, nb);
  for (int k = tid; k < 4096; k += 256) W[k] = Wg[k];
  __syncthreads();
  int nl = tid >> 6, j = tid & 63;
  int Nc = (N + 3) >> 2;
  float ssum = 0.f, ssq = 0.f;
  for (int chunk = blockIdx.x; chunk < Nc; chunk += gridDim.x) {
    int node = chunk * 4 + nl;
    bool valid = node < N;
    float hv = valid ? (in[node * 64 + j] * na[j] + nb[j]) : 0.f;
    hl[nl][j] = ACT ? elu_f(hv) : hv;
    __syncthreads();
    if (valid) {
      float acc = 0.f;
#pragma unroll
      for (int i = 0; i < 64; i++) acc += hl[nl][i] * W[i * 64 + j];
      out[node * 64 + j] = acc;
      ssum += acc; ssq += acc * acc;
    }
    __syncthreads();
  }
  red[tid] = ssum; __syncthreads();
  if (tid < 64) atomicAdd(&sout[tid], (double)(red[tid] + red[tid + 64] + red[tid + 128] + red[tid + 192]));
  __syncthreads();
  red[tid] = ssq; __syncthreads();
  if (tid < 64) atomicAdd(&sout[64 + tid], (double)(red[tid] + red[tid + 64] + red[tid + 128] + red[tid + 192]));
}

// ---------------- encoder layer 3 + xl(bf16)/xr projections ----------------
__global__ void k_enc3(const float* __restrict__ tB, const float* __restrict__ w,
                       const float* __restrict__ b, const float* __restrict__ Wlw,
                       const float* __restrict__ Wrw, const double* __restrict__ s2,
                       float* __restrict__ jk, u16* __restrict__ xlb, float* __restrict__ xr,
                       int N) {
  __shared__ float WL[4096], WR[4096];
  __shared__ float hl[4][64];
  __shared__ float na[64], nb[64];
  int tid = threadIdx.x;
  if (tid < 64) norm_coeffs(s2, tid, N, w, b, na, nb);
  for (int k = tid; k < 4096; k += 256) { WL[k] = Wlw[k]; WR[k] = Wrw[k]; }
  __syncthreads();
  int nl = tid >> 6, j = tid & 63;
  int Nc = (N + 3) >> 2;
  for (int chunk = blockIdx.x; chunk < Nc; chunk += gridDim.x) {
    int node = chunk * 4 + nl;
    bool valid = node < N;
    float h3 = valid ? elu_f(tB[node * 64 + j] * na[j] + nb[j]) : 0.f;
    hl[nl][j] = h3;
    __syncthreads();
    if (valid) {
      jk[node * 64 + j] = h3;
      float al = 0.f, ar = 0.f;
#pragma unroll
      for (int i = 0; i < 64; i++) {
        float h = hl[nl][i];
        al += h * WL[i * 64 + j];
        ar += h * WR[i * 64 + j];
      }
      xlb[node * 64 + j] = f2bf(al);
      xr[node * 64 + j] = ar;
    }
    __syncthreads();
  }
}

// ---------------- degree count: 8-way XCD-replicated ----------------
__global__ void k_deg(const int* __restrict__ ei, int* __restrict__ deg8, int E, int N,
                      const int* __restrict__ i32flag) {
  int e = blockIdx.x * 256 + threadIdx.x;
  if (e >= E + N) return;
  int r = blockIdx.x & 7;
  int dst;
  if (e < E) {
    if (*i32flag) dst = ei[E + e];
    else { const ll* el = (const ll*)ei; dst = (int)el[E + e]; }
  } else dst = e - E;
  atomicAdd(&deg8[r * N + dst], 1);
}

// ---------------- coalesced scan: A (block sums), B (scan sums), C (final) --
__global__ void k_scanA(const int* __restrict__ deg8, int* __restrict__ bsum, int N) {
  __shared__ int red[256];
  int tid = threadIdx.x;
  int base = blockIdx.x * 1024;
  int s = 0;
#pragma unroll
  for (int q = 0; q < 4; q++) {
    int n = base + q * 256 + tid;
    if (n < N) {
#pragma unroll
      for (int r = 0; r < 8; r++) s += deg8[r * N + n];
    }
  }
  red[tid] = s; __syncthreads();
  for (int o = 128; o > 0; o >>= 1) {
    if (tid < o) red[tid] += red[tid + o];
    __syncthreads();
  }
  if (tid == 0) bsum[blockIdx.x] = red[0];
}

__global__ void k_scanB(const int* __restrict__ bsum, int* __restrict__ bscan,
                        int* __restrict__ offs, int NB, int N) {
  if (threadIdx.x == 0) {
    int run = 0;
    for (int b = 0; b < NB; b++) { bscan[b] = run; run += bsum[b]; }
    offs[N] = run;
  }
}

__global__ void k_scanC(const int* __restrict__ deg8, const int* __restrict__ bscan,
                        int* __restrict__ offs, int* __restrict__ cursor8, int N) {
  __shared__ int dt[1024];
  __shared__ int tp[256];
  int tid = threadIdx.x;
  int base = blockIdx.x * 1024;
#pragma unroll
  for (int q = 0; q < 4; q++) {
    int n = base + q * 256 + tid;
    int s = 0;
    if (n < N) {
#pragma unroll
      for (int r = 0; r < 8; r++) s += deg8[r * N + n];
    }
    dt[q * 256 + tid] = s;
  }
  __syncthreads();
  int t4 = tid * 4;
  int l0 = dt[t4], l1 = dt[t4 + 1], l2 = dt[t4 + 2], l3 = dt[t4 + 3];
  int tot = l0 + l1 + l2 + l3;
  tp[tid] = tot; __syncthreads();
  for (int o = 1; o < 256; o <<= 1) {
    int v = (tid >= o) ? tp[tid - o] : 0;
    __syncthreads();
    tp[tid] += v;
    __syncthreads();
  }
  int run = bscan[blockIdx.x] + tp[tid] - tot;
#pragma unroll
  for (int k = 0; k < 4; k++) {
    int n = base + t4 + k;
    if (n < N) {
      offs[n] = run;
      int b = run;
#pragma unroll
      for (int r = 0; r < 8; r++) { cursor8[r * N + n] = b; b += deg8[r * N + n]; }
      run = b;
    }
  }
}

// ---------------- scatter: src + bf16x8 eattr into CSR order ----------------
__global__ void k_scatter(const int* __restrict__ ei, const float* __restrict__ eattr,
                          int* __restrict__ cursor8, int* __restrict__ csr_src,
                          uint4* __restrict__ ea2, int E, int N,
                          const int* __restrict__ i32flag) {
  int e = blockIdx.x * 256 + threadIdx.x;
  if (e >= E + N) return;
  int r = blockIdx.x & 7;
  int src, dst;
  u16 p[8];
  if (e < E) {
    if (*i32flag) { src = ei[e]; dst = ei[E + e]; }
    else { const ll* el = (const ll*)ei; src = (int)el[e]; dst = (int)el[E + e]; }
    const float* ea = eattr + (size_t)e * 7;
#pragma unroll
    for (int q = 0; q < 7; q++) p[q] = f2bf(ea[q]);
    p[7] = 0;
  } else {
    src = e - E; dst = src;
#pragma unroll
    for (int q = 0; q < 8; q++) p[q] = 0;
    p[6] = 0x3F80;   // FILL: e_6 = 1.0
  }
  int pos = atomicAdd(&cursor8[r * N + dst], 1);
  csr_src[pos] = src;
  uint4 U;
  U.x = ((unsigned)p[1] << 16) | p[0];
  U.y = ((unsigned)p[3] << 16) | p[2];
  U.z = ((unsigned)p[5] << 16) | p[4];
  U.w = ((unsigned)p[7] << 16) | p[6];
  ea2[pos] = U;
}

// ---------------- fused GAT: persistent, wave/node, 16 lanes/edge ----------
__global__ void k_gat(const int* __restrict__ offs, const int* __restrict__ csr_src,
                      const uint4* __restrict__ ea2,
                      const u16* __restrict__ xlb, const float* __restrict__ xr,
                      const float* __restrict__ Wew, const float* __restrict__ attw,
                      float* __restrict__ gat, double* __restrict__ s3, int N) {
  __shared__ float sb[4][64];
  int tid = threadIdx.x;
  int wid = tid >> 6;          // wave id in block = node slot
  int lane = tid & 63;
  int g = lane >> 4;           // edge slot within 4-edge batch
  int l = lane & 15;           // channel quad index: owns channels 4l..4l+3
  int Nc = (N + 3) >> 2;

  // per-lane constants in registers
  float4 wq[7];
#pragma unroll
  for (int q = 0; q < 7; q++) wq[q] = *(const float4*)(Wew + q * 64 + 4 * l);
  float4 attv = *(const float4*)(attw + 4 * l);

  // running per-channel stats (meaningful on g==0 lanes only)
  float ts0 = 0.f, ts1 = 0.f, ts2 = 0.f, ts3 = 0.f;
  float tq0 = 0.f, tq1 = 0.f, tq2 = 0.f, tq3 = 0.f;

  for (int chunk = blockIdx.x; chunk < Nc; chunk += gridDim.x) {
    int node = chunk * 4 + wid;
    if (node >= N) continue;
    float4 xrv = *(const float4*)(xr + node * 64 + 4 * l);
    int st = offs[node];
    int dg = offs[node + 1] - st;
    int nb = (dg + 3) >> 2;
    float sden = 0.f;
    float a0 = 0.f, a1 = 0.f, a2 = 0.f, a3 = 0.f;

    // ---- pipeline prologue: batches 0 and 1 ptr-loads, batch 0 gather ----
    int i0 = st + g;
    int scC = csr_src[i0];           // batch 0 src
    uint4 UC = ea2[i0];              // batch 0 eattr
    int scN = csr_src[i0 + 4];       // batch 1 src (pad-safe)
    uint4 UN = ea2[i0 + 4];          // batch 1 eattr
    scC = ((unsigned)scC < (unsigned)N) ? scC : 0;
    uint2 xwC = *(const uint2*)(xlb + scC * 64 + 4 * l);   // batch 0 gather

    for (int b = 0; b < nb; b++) {
      // stage A: issue ptr loads for batch b+2 (max idx st+dg+10 < pad 16)
      int iA = st + (b + 2) * 4 + g;
      int scA = csr_src[iA];
      uint4 UA = ea2[iA];
      // stage B: issue gather for batch b+1 (scN issued one iteration ago)
      int scg = ((unsigned)scN < (unsigned)N) ? scN : 0;
      uint2 xwN = *(const uint2*)(xlb + scg * 64 + 4 * l);
      // stage C: compute batch b from xwC/UC (issued >=1 iteration ago)
      bool valid = (b * 4 + g) < dg;
      float x0 = bflo(xwC.x), x1 = bfhi(xwC.x), x2 = bflo(xwC.y), x3 = bfhi(xwC.y);
      float e0 = bflo(UC.x), e1 = bfhi(UC.x), e2 = bflo(UC.y), e3 = bfhi(UC.y);
      float e4 = bflo(UC.z), e5 = bfhi(UC.z), e6 = bflo(UC.w);
      float m0 = x0 + xrv.x + e0*wq[0].x + e1*wq[1].x + e2*wq[2].x + e3*wq[3].x + e4*wq[4].x + e5*wq[5].x + e6*wq[6].x;
      float m1 = x1 + xrv.y + e0*wq[0].y + e1*wq[1].y + e2*wq[2].y + e3*wq[3].y + e4*wq[4].y + e5*wq[5].y + e6*wq[6].y;
      float m2 = x2 + xrv.z + e0*wq[0].z + e1*wq[1].z + e2*wq[2].z + e3*wq[3].z + e4*wq[4].z + e5*wq[5].z + e6*wq[6].z;
      float m3 = x3 + xrv.w + e0*wq[0].w + e1*wq[1].w + e2*wq[2].w + e3*wq[3].w + e4*wq[4].w + e5*wq[5].w + e6*wq[6].w;
      m0 = m0 > 0.f ? m0 : 0.2f * m0;
      m1 = m1 > 0.f ? m1 : 0.2f * m1;
      m2 = m2 > 0.f ? m2 : 0.2f * m2;
      m3 = m3 > 0.f ? m3 : 0.2f * m3;
      float pp = m0 * attv.x + m1 * attv.y + m2 * attv.z + m3 * attv.w;
      pp += __shfl_xor(pp, 1, 64);     // quad reduce: 4 lanes = 16 channels = head
      pp += __shfl_xor(pp, 2, 64);
      float ex = valid ? __expf(pp) : 0.f;
      sden += ex;
      a0 += ex * x0; a1 += ex * x1; a2 += ex * x2; a3 += ex * x3;
      // rotate pipeline registers
      xwC = xwN; UC = UN; UN = UA; scN = scA;
    }
    // sum over the 4 edge-groups
    a0 += __shfl_xor(a0, 16, 64); a0 += __shfl_xor(a0, 32, 64);
    a1 += __shfl_xor(a1, 16, 64); a1 += __shfl_xor(a1, 32, 64);
    a2 += __shfl_xor(a2, 16, 64); a2 += __shfl_xor(a2, 32, 64);
    a3 += __shfl_xor(a3, 16, 64); a3 += __shfl_xor(a3, 32, 64);
    sden += __shfl_xor(sden, 16, 64); sden += __shfl_xor(sden, 32, 64);
    float inv = 1.f / (sden * (float)dg);
    float val0 = a0 * inv, val1 = a1 * inv, val2 = a2 * inv, val3 = a3 * inv;
    if (g == 0) {
      float4 o = make_float4(val0, val1, val2, val3);
      *(float4*)(gat + node * 64 + 4 * l) = o;
      ts0 += val0; ts1 += val1; ts2 += val2; ts3 += val3;
      tq0 += val0 * val0; tq1 += val1 * val1; tq2 += val2 * val2; tq3 += val3 * val3;
    }
  }

  // ---- block-exit stats reduction: transpose to per-channel, 128 atomics ----
  if (g == 0) {
    sb[wid][4 * l + 0] = ts0; sb[wid][4 * l + 1] = ts1;
    sb[wid][4 * l + 2] = ts2; sb[wid][4 * l + 3] = ts3;
  }
  __syncthreads();
  if (tid < 64) {
    float v = sb[0][tid] + sb[1][tid] + sb[2][tid] + sb[3][tid];
    atomicAdd(&s3[tid], (double)v);
  }
  __syncthreads();
  if (g == 0) {
    sb[wid][4 * l + 0] = tq0; sb[wid][4 * l + 1] = tq1;
    sb[wid][4 * l + 2] = tq2; sb[wid][4 * l + 3] = tq3;
  }
  __syncthreads();
  if (tid < 64) {
    float v = sb[0][tid] + sb[1][tid] + sb[2][tid] + sb[3][tid];
    atomicAdd(&s3[64 + tid], (double)v);
  }
}

// ---------------- atomic fallback (if CSR doesn't fit) ----------------
__global__ void k_edge2(const int* __restrict__ ei, const float* __restrict__ eattr,
                        const u16* __restrict__ xlb, const float* __restrict__ xr,
                        const float* __restrict__ Wew, const float* __restrict__ attw,
                        float* __restrict__ agg, float* __restrict__ denom,
                        int* __restrict__ deg, int E, int N,
                        const int* __restrict__ i32flag) {
  __shared__ float sWe[448];
  __shared__ float satt[64];
  int tid = threadIdx.x;
  for (int k = tid; k < 448; k += 256) sWe[k] = Wew[k];
  if (tid < 64) satt[tid] = attw[tid];
  __syncthreads();
  int e = blockIdx.x * 4 + (tid >> 6);
  if (e >= E + N) return;
  int lane = tid & 63;
  int src, dst;
  if (e < E) {
    if (*i32flag) { src = ei[e]; dst = ei[E + e]; }
    else { const ll* el = (const ll*)ei; src = (int)el[e]; dst = (int)el[E + e]; }
  } else { src = e - E; dst = src; }
  float xlv = bf(xlb[src * 64 + lane]);
  float m = xlv + xr[dst * 64 + lane];
  if (e < E) {
#pragma unroll
    for (int k = 0; k < 7; k++) m += eattr[e * 7 + k] * sWe[k * 64 + lane];
  } else {
    m += sWe[6 * 64 + lane];
  }
  float lr = m > 0.f ? m : 0.2f * m;
  float p = lr * satt[lane];
  p += __shfl_xor(p, 1, 64);
  p += __shfl_xor(p, 2, 64);
  p += __shfl_xor(p, 4, 64);
  p += __shfl_xor(p, 8, 64);
  float ex = __expf(p);
  atomicAdd(&agg[dst * 64 + lane], ex * xlv);
  if ((lane & 15) == 0) atomicAdd(&denom[dst * 4 + (lane >> 4)], ex);
  if (lane == 0) atomicAdd(&deg[dst], 1);
}

__global__ void k_gatnorm(float* __restrict__ agg, const float* __restrict__ denom,
                          const int* __restrict__ deg, double* __restrict__ s3, int N) {
  __shared__ float red[256];
  int tid = threadIdx.x;
  int idx = blockIdx.x * 256 + tid;
  float v = 0.f;
  if (idx < N * 64) {
    int n = idx >> 6, c = idx & 63, h = c >> 4;
    v = agg[idx] / (denom[n * 4 + h] * (float)deg[n]);
    agg[idx] = v;
  }
  red[tid] = v; __syncthreads();
  if (tid < 64) atomicAdd(&s3[tid], (double)(red[tid] + red[tid + 64] + red[tid + 128] + red[tid + 192]));
  __syncthreads();
  red[tid] = v * v; __syncthreads();
  if (tid < 64) atomicAdd(&s3[64 + tid], (double)(red[tid] + red[tid + 64] + red[tid + 128] + red[tid + 192]));
}

// ---------------- h4 = elu(h3 + inorm(gat)) ----------------
__global__ void k_h4(const float* __restrict__ jk, const float* __restrict__ gat,
                     const float* __restrict__ gn_w, const float* __restrict__ gn_b,
                     const double* __restrict__ s3, float* __restrict__ h4, int N) {
  __shared__ float na[64], nb[64];
  int tid = threadIdx.x;
  if (tid < 64) norm_coeffs(s3, tid, N, gn_w, gn_b, na, nb);
  __syncthreads();
  int idx = blockIdx.x * 256 + tid;
  if (idx >= N * 64) return;
  int c = idx & 63;
  h4[idx] = elu_f(jk[idx] + gat[idx] * na[c] + nb[c]);
}

// ---------------- weight prep: fragment-ordered bf16 hi/lo for dW1..dW5 -----
// Tile t covers B[k][n]: k = kt*32 + (lane>>4)*8 + i, n = nt*16 + (lane&15).
// Storage: whi[(t*64+lane)*8 + i] -> B-frag load is one coalesced b128/lane.
// Tile bases: L1[128->256]=0(64), L2[256->128]=64(64), L3[128->64]=128(16),
//             L4[64->32]=144(4), L5[32->16]=148(1). Total 149 tiles.
__global__ void k_wprep(const float* __restrict__ dW1, const float* __restrict__ dW2,
                        const float* __restrict__ dW3, const float* __restrict__ dW4,
                        const float* __restrict__ dW5,
                        u16* __restrict__ whi, u16* __restrict__ wlo) {
  int t = blockIdx.x;
  int tid = threadIdx.x;
  const float* W; int LIN, LOUT, base;
  if (t < 64)       { W = dW1; LIN = 128; LOUT = 256; base = 0; }
  else if (t < 128) { W = dW2; LIN = 256; LOUT = 128; base = 64; }
  else if (t < 144) { W = dW3; LIN = 128; LOUT = 64;  base = 128; }
  else if (t < 148) { W = dW4; LIN = 64;  LOUT = 32;  base = 144; }
  else              { W = dW5; LIN = 32;  LOUT = 16;  base = 148; }
  int KT = LIN >> 5;
  int tl = t - base;
  int nt = tl / KT, kt = tl % KT;
#pragma unroll
  for (int half = 0; half < 2; half++) {
    int lane = (tid >> 3) + half * 32;
    int i = tid & 7;
    int kg = kt * 32 + (lane >> 4) * 8 + i;
    int ng = nt * 16 + (lane & 15);
    float v = W[kg * LOUT + ng];
    u16 hi = f2bf(v);
    u16 lo = f2bf(v - bf(hi));
    whi[((size_t)t * 64 + lane) * 8 + i] = hi;
    wlo[((size_t)t * 64 + lane) * 8 + i] = lo;
  }
}

// ---------------- decoder: MFMA split-bf16 layer -----------------------------
// A-frag: A[m=lane&15][k=kt*32+(lane>>4)*8+i] from LDS bf16 rows [node][LIN+8].
// C/D:    row m=(lane>>4)*4+reg, col n=lane&15 (verified mapping).
// D = Ahi*Whi + Ahi*Wlo + Alo*Whi + bias; elu; re-split to hi/lo for next layer.
template <int LIN, int LOUT, int TBASE>
__device__ __forceinline__ void mfmaLayer(const u16* __restrict__ whi, const u16* __restrict__ wlo,
                                          const float* __restrict__ bias,
                                          const u16* __restrict__ Ahi, const u16* __restrict__ Alo,
                                          u16* __restrict__ Ohi, u16* __restrict__ Olo,
                                          int wid, int lane) {
  constexpr int KT = LIN / 32, NT = LOUT / 16;
  constexpr int SIN = LIN + 8, SOUT = LOUT + 8;
  int l15 = lane & 15, kg = lane >> 4;
  int aoff = l15 * SIN + kg * 8;
  for (int nt = wid; nt < NT; nt += 4) {
    float bn = bias[nt * 16 + l15];
    f32x4 acc = {bn, bn, bn, bn};
    for (int kt = 0; kt < KT; kt++) {
      s16x8 ah = *(const s16x8*)(Ahi + aoff + kt * 32);
      s16x8 al = *(const s16x8*)(Alo + aoff + kt * 32);
      const u16* wp = whi + ((size_t)(TBASE + nt * KT + kt) * 64 + lane) * 8;
      const u16* wq = wlo + ((size_t)(TBASE + nt * KT + kt) * 64 + lane) * 8;
      s16x8 wh = *(const s16x8*)(wp);
      s16x8 wl = *(const s16x8*)(wq);
      acc = __builtin_amdgcn_mfma_f32_16x16x32_bf16(ah, wh, acc, 0, 0, 0);
      acc = __builtin_amdgcn_mfma_f32_16x16x32_bf16(ah, wl, acc, 0, 0, 0);
      acc = __builtin_amdgcn_mfma_f32_16x16x32_bf16(al, wh, acc, 0, 0, 0);
    }
#pragma unroll
    for (int r = 0; r < 4; r++) {
      int m = kg * 4 + r;
      float v = elu_f(acc[r]);
      u16 hi = f2bf(v);
      u16 lo = f2bf(v - bf(hi));
      Ohi[m * SOUT + nt * 16 + l15] = hi;
      Olo[m * SOUT + nt * 16 + l15] = lo;
    }
  }
}

__global__ void k_dec(const float* __restrict__ jk, const float* __restrict__ h4,
                      const u16* __restrict__ whi, const u16* __restrict__ wlo,
                      const float* __restrict__ db1, const float* __restrict__ db2,
                      const float* __restrict__ db3, const float* __restrict__ db4,
                      const float* __restrict__ db5,
                      const float* __restrict__ dW6, const float* __restrict__ db6,
                      float* __restrict__ outdec, int N) {
  // ping-pong act buffers, bf16 hi/lo, [16 nodes][stride] (stride = LIN+8)
  __shared__ __align__(16) u16 bHi0[16 * 264], bLo0[16 * 264];
  __shared__ __align__(16) u16 bHi1[16 * 264], bLo1[16 * 264];
  int tid = threadIdx.x;
  int wid = tid >> 6, lane = tid & 63;
  int g0 = blockIdx.x * 16;
  // stage input: [node][136] = 128 ch of (jk | h4), bf16 hi/lo
  for (int k = tid; k < 16 * 128; k += 256) {
    int i = k & 127, node = k >> 7;
    int gn = g0 + node;
    float v = 0.f;
    if (gn < N) v = (i < 64) ? jk[gn * 64 + i] : h4[gn * 64 + (i - 64)];
    u16 hi = f2bf(v);
    u16 lo = f2bf(v - bf(hi));
    bHi0[node * 136 + i] = hi;
    bLo0[node * 136 + i] = lo;
  }
  __syncthreads();
  mfmaLayer<128, 256, 0>(whi, wlo, db1, bHi0, bLo0, bHi1, bLo1, wid, lane); __syncthreads();
  mfmaLayer<256, 128, 64>(whi, wlo, db2, bHi1, bLo1, bHi0, bLo0, wid, lane); __syncthreads();
  mfmaLayer<128, 64, 128>(whi, wlo, db3, bHi0, bLo0, bHi1, bLo1, wid, lane); __syncthreads();
  mfmaLayer<64, 32, 144>(whi, wlo, db4, bHi1, bLo1, bHi0, bLo0, wid, lane); __syncthreads();
  mfmaLayer<32, 16, 148>(whi, wlo, db5, bHi0, bLo0, bHi1, bLo1, wid, lane); __syncthreads();
  // final 16 -> 2 (fp32 scalar; act rows stride 24)
  if (tid < 32) {
    int node = tid >> 1, j = tid & 1;
    int gn = g0 + node;
    if (gn < N) {
      float s = db6[j];
#pragma unroll
      for (int i = 0; i < 16; i++) {
        float a = bf(bHi1[node * 24 + i]) + bf(bLo1[node * 24 + i]);
        s += a * dW6[i * 2 + j];
      }
      outdec[gn * 2 + j] = s;
    }
  }
}

// ---------------- recon MLP: 16-node chunks, transposed LDS ----------------
__global__ void k_recon(const float* __restrict__ h4,
                        const float* __restrict__ rW1, const float* __restrict__ rb1,
                        const float* __restrict__ rW2, const float* __restrict__ rb2,
                        const float* __restrict__ rW3, const float* __restrict__ rb3,
                        float* __restrict__ outrec, int N) {
  __shared__ float W1[4096], W2[4096], W3[4096];
  __shared__ float b1[64], b2[64], b3[64];
  __shared__ float A[64 * 16], Bb[64 * 16];
  int tid = threadIdx.x;
  for (int k = tid; k < 4096; k += 256) { W1[k] = rW1[k]; W2[k] = rW2[k]; W3[k] = rW3[k]; }
  if (tid < 64) { b1[tid] = rb1[tid]; b2[tid] = rb2[tid]; b3[tid] = rb3[tid]; }
  __syncthreads();
  int j = tid & 63, g = tid >> 6;
  int Nc = (N + 15) >> 4;
  for (int chunk = blockIdx.x; chunk < Nc; chunk += gridDim.x) {
    int g0 = chunk * 16;
    for (int k = tid; k < 16 * 64; k += 256) {
      int i = k & 63, node = k >> 6;
      int gn = g0 + node;
      A[i * 16 + node] = (gn < N) ? h4[gn * 64 + i] : 0.f;
    }
    __syncthreads();
    {
      float a0 = b1[j], a1 = b1[j], a2 = b1[j], a3 = b1[j];
#pragma unroll 4
      for (int i = 0; i < 64; i++) {
        float w = W1[i * 64 + j];
        float4 a = *(const float4*)(&A[i * 16 + g * 4]);
        a0 += a.x * w; a1 += a.y * w; a2 += a.z * w; a3 += a.w * w;
      }
      Bb[j * 16 + g * 4 + 0] = elu_f(a0);
      Bb[j * 16 + g * 4 + 1] = elu_f(a1);
      Bb[j * 16 + g * 4 + 2] = elu_f(a2);
      Bb[j * 16 + g * 4 + 3] = elu_f(a3);
    }
    __syncthreads();
    {
      float a0 = b2[j], a1 = b2[j], a2 = b2[j], a3 = b2[j];
#pragma unroll 4
      for (int i = 0; i < 64; i++) {
        float w = W2[i * 64 + j];
        float4 a = *(const float4*)(&Bb[i * 16 + g * 4]);
        a0 += a.x * w; a1 += a.y * w; a2 += a.z * w; a3 += a.w * w;
      }
      A[j * 16 + g * 4 + 0] = elu_f(a0);
      A[j * 16 + g * 4 + 1] = elu_f(a1);
      A[j * 16 + g * 4 + 2] = elu_f(a2);
      A[j * 16 + g * 4 + 3] = elu_f(a3);
    }
    __syncthreads();
    {
      float a0 = b3[j], a1 = b3[j], a2 = b3[j], a3 = b3[j];
#pragma unroll 4
      for (int i = 0; i < 64; i++) {
        float w = W3[i * 64 + j];
        float4 a = *(const float4*)(&A[i * 16 + g * 4]);
        a0 += a.x * w; a1 += a.y * w; a2 += a.z * w; a3 += a.w * w;
      }
      float o[4] = {a0, a1, a2, a3};
#pragma unroll
      for (int u = 0; u < 4; u++) {
        int gn = g0 + g * 4 + u;
        if (gn < N) outrec[gn * 64 + j] = o[u];
      }
    }
    __syncthreads();
  }
}

// ---------------- sentinel ----------------
__global__ void k_sentinel(float* __restrict__ out, float v) {
  if (threadIdx.x == 0) out[0] = v;
}

extern "C" void kernel_launch(void* const* d_in, const int* in_sizes, int n_in,
                              void* d_out, int out_size, void* d_ws, size_t ws_size,
                              hipStream_t stream) {
  (void)n_in; (void)out_size;
  const float* x     = (const float*)d_in[0];
  const int*   ei    = (const int*)d_in[1];
  const float* ea    = (const float*)d_in[2];
  const float* pre_w = (const float*)d_in[3];
  const float* pre_b = (const float*)d_in[4];
  const float* eW1   = (const float*)d_in[5];
  const float* en1w  = (const float*)d_in[6];
  const float* en1b  = (const float*)d_in[7];
  const float* eW2   = (const float*)d_in[8];
  const float* en2w  = (const float*)d_in[9];
  const float* en2b  = (const float*)d_in[10];
  const float* Wl    = (const float*)d_in[11];
  const float* Wr    = (const float*)d_in[12];
  const float* Wew   = (const float*)d_in[13];
  const float* attw  = (const float*)d_in[14];
  const float* gn_w  = (const float*)d_in[15];
  const float* gn_b  = (const float*)d_in[16];
  const float* dW1 = (const float*)d_in[17]; const float* db1 = (const float*)d_in[18];
  const float* dW2 = (const float*)d_in[19]; const float* db2 = (const float*)d_in[20];
  const float* dW3 = (const float*)d_in[21]; const float* db3 = (const float*)d_in[22];
  const float* dW4 = (const float*)d_in[23]; const float* db4 = (const float*)d_in[24];
  const float* dW5 = (const float*)d_in[25]; const float* db5 = (const float*)d_in[26];
  const float* dW6 = (const float*)d_in[27]; const float* db6 = (const float*)d_in[28];
  const float* rW1 = (const float*)d_in[29]; const float* rb1 = (const float*)d_in[30];
  const float* rW2 = (const float*)d_in[31]; const float* rb2 = (const float*)d_in[32];
  const float* rW3 = (const float*)d_in[33]; const float* rb3 = (const float*)d_in[34];

  int D  = in_sizes[3];
  int N  = in_sizes[0] / (D > 0 ? D : 1);
  int E  = in_sizes[1] / 2;
  int ED = E > 0 ? in_sizes[2] / E : 0;
  float* outdec = (float*)d_out;
  float* outrec = outdec + (size_t)N * 2;
  if (D != 64 || ED != 7 || in_sizes[14] != 64) {
    k_sentinel<<<1, 64, 0, stream>>>(outdec, 2000.f);
    return;
  }
  int Etot = E + N;

  char* w = (char*)d_ws;
  size_t off = 0;
  auto alloc = [&](size_t bytes) -> void* {
    void* p = w + off;
    off += (bytes + 255) & ~(size_t)255;
    return p;
  };
  const size_t FEATF = (size_t)N * 64 * 4;
  float* B1    = (float*)alloc(FEATF);             // t1 -> gat (or agg fallback)
  size_t ea2_bytes = ((size_t)Etot + 16) * 16;     // +16 pad: pipeline prefetch depth
  size_t b2ext = ea2_bytes > FEATF ? ea2_bytes : FEATF;
  float* B2    = (float*)alloc(b2ext);
  float* jk    = (float*)alloc(FEATF);
  u16*   xlb   = (u16*)  alloc((size_t)N * 64 * 2);
  float* xr    = (float*)alloc(FEATF);
  int*   offs  = (int*)  alloc(((size_t)N + 1) * 4);
  int*   deg8  = (int*)  alloc((size_t)N * 8 * 4);
  int*   cursor8=(int*)  alloc((size_t)N * 8 * 4);
  int*   bsum  = (int*)  alloc(4096);
  int*   bscan = (int*)  alloc(4096);
  double* stats = (double*)alloc(4 * 128 * 8);
  int* i32flag = (int*)alloc(256);
  float* denom = (float*)alloc((size_t)N * 4 * 4);  // fallback only
  u16* whi = (u16*)alloc((size_t)149 * 512 * 2);    // fragment-ordered bf16 hi
  u16* wlo = (u16*)alloc((size_t)149 * 512 * 2);    // fragment-ordered bf16 lo
  size_t base_off = off;
  int* csr_src = (int*)alloc(((size_t)Etot + 16) * 4);  // +16 pad
  size_t csr_off = off;

  double* s0 = stats, *s1 = stats + 128, *s2 = stats + 256, *s3 = stats + 384;
  float* t1 = B1; float* gat = B1; float* agg = B1;
  float* t2 = B2; float* h4 = B2;
  uint4* ea2 = (uint4*)B2;   // aliases t2 (dead after k_enc3)

  bool use_csr = (csr_off <= ws_size);
  if (!use_csr && base_off > ws_size) {
    k_sentinel<<<1, 64, 0, stream>>>(outdec, 1000.f);
    return;
  }

  hipMemsetAsync(stats, 0, 4 * 128 * 8, stream);
  hipMemsetAsync(i32flag, 0, 256, stream);
  hipMemsetAsync(deg8, 0, (size_t)N * 8 * 4, stream);

  int gN64 = (N * 64 + 255) / 256;
  int gE = (Etot + 255) / 256;
  int probeCnt = E < 1024 ? E : 1024;
  int NB = (N + 1023) / 1024;

  k_probe64<<<1, 256, 0, stream>>>(ei, probeCnt, i32flag);
  k_wprep<<<149, 256, 0, stream>>>(dW1, dW2, dW3, dW4, dW5, whi, wlo);
  k_stats_x<<<1024, 256, 0, stream>>>(x, N, s0);
  k_enc<false><<<1024, 256, 0, stream>>>(x, pre_w, pre_b, eW1, s0, t1, s1, N);
  k_enc<true><<<1024, 256, 0, stream>>>(t1, en1w, en1b, eW2, s1, t2, s2, N);
  k_enc3<<<1024, 256, 0, stream>>>(t2, en2w, en2b, Wl, Wr, s2, jk, xlb, xr, N);

  if (use_csr) {
    k_deg<<<gE, 256, 0, stream>>>(ei, deg8, E, N, i32flag);
    k_scanA<<<NB, 256, 0, stream>>>(deg8, bsum, N);
    k_scanB<<<1, 64, 0, stream>>>(bsum, bscan, offs, NB, N);
    k_scanC<<<NB, 256, 0, stream>>>(deg8, bscan, offs, cursor8, N);
    k_scatter<<<gE, 256, 0, stream>>>(ei, ea, cursor8, csr_src, ea2, E, N, i32flag);
    int ggat = 2048;
    int NcG = (N + 3) / 4;
    if (ggat > NcG) ggat = NcG;
    k_gat<<<ggat, 256, 0, stream>>>(offs, csr_src, ea2, xlb, xr, Wew, attw,
                                    gat, s3, N);
  } else {
    hipMemsetAsync(agg, 0, FEATF, stream);
    hipMemsetAsync(denom, 0, (size_t)N * 4 * 4, stream);
    k_edge2<<<(Etot + 3) / 4, 256, 0, stream>>>(ei, ea, xlb, xr, Wew, attw, agg, denom,
                                                deg8, E, N, i32flag);
    k_gatnorm<<<gN64, 256, 0, stream>>>(agg, denom, deg8, s3, N);
  }

  k_h4<<<gN64, 256, 0, stream>>>(jk, gat, gn_w, gn_b, s3, h4, N);
  int NcD = (N + 15) / 16;
  k_dec<<<NcD, 256, 0, stream>>>(jk, h4, whi, wlo, db1, db2, db3, db4, db5,
                                 dW6, db6, outdec, N);
  k_recon<<<1024, 256, 0, stream>>>(h4, rW1, rb1, rW2, rb2, rW3, rb3, outrec, N);
}

// Round 10
// 666.812 us; speedup vs baseline: 1.2709x; 1.0237x over previous
//
#include <hip/hip_runtime.h>
#include <math.h>

// GAT model, MI355X. Round 23: k_scatter/k_gat "packed" mode — src index
// packed into ea2.w high half (src<N<=65536 fits u16; p[7] was unused).
// One 16B scattered store/edge instead of 4B+16B to two different lines
// (R22 counters: WRITE_SIZE 148MB vs 33MB payload = line-occupancy bound).
// k_gat drops the csr_src load stream entirely. i64/N>65536 fallback kept.
// R22's MFMA split-bf16 k_dec retained (847->682us win, absmax unchanged).

typedef long long ll;
typedef unsigned short u16;
typedef float f32x4 __attribute__((ext_vector_type(4)));
typedef short s16x8 __attribute__((ext_vector_type(8)));

__device__ __forceinline__ float bf(u16 u) { return __uint_as_float(((unsigned)u) << 16); }
__device__ __forceinline__ u16 f2bf(float f) {
  unsigned u = __float_as_uint(f);
  u += 0x7fffu + ((u >> 16) & 1u);   // RNE
  return (u16)(u >> 16);
}
__device__ __forceinline__ float bflo(unsigned u) { return __uint_as_float(u << 16); }
__device__ __forceinline__ float bfhi(unsigned u) { return __uint_as_float(u & 0xffff0000u); }
__device__ __forceinline__ float elu_f(float x) { return x > 0.f ? x : (__expf(x) - 1.f); }

// ---------------- probe: is edge_index int32 (flag=1) or int64 (flag=0)?
__global__ void k_probe64(const int* __restrict__ ei, int cnt, int* __restrict__ flag) {
  int tid = threadIdx.x;
  int nz = 0;
  for (int k = tid; k < cnt; k += 256) {
    if (ei[2 * k + 1] != 0) nz = 1;
  }
  if (nz) atomicOr(flag, 1);
}

// ---------------- stats of x ----------------
__global__ void k_stats_x(const float* __restrict__ x, int N, double* __restrict__ s0) {
  __shared__ float red[256];
  int tid = threadIdx.x;
  int c = tid & 63;
  float s = 0.f, ss = 0.f;
  for (int r = blockIdx.x * 4 + (tid >> 6); r < N; r += gridDim.x * 4) {
    float v = x[r * 64 + c];
    s += v; ss += v * v;
  }
  red[tid] = s; __syncthreads();
  if (tid < 64) atomicAdd(&s0[tid], (double)(red[tid] + red[tid + 64] + red[tid + 128] + red[tid + 192]));
  __syncthreads();
  red[tid] = ss; __syncthreads();
  if (tid < 64) atomicAdd(&s0[64 + tid], (double)(red[tid] + red[tid + 64] + red[tid + 128] + red[tid + 192]));
}

__device__ __forceinline__ void norm_coeffs(const double* s, int tid, int N,
                                            const float* w, const float* b,
                                            float* na, float* nb) {
  double invN = 1.0 / (double)N;
  double mean = s[tid] * invN;
  double var = s[64 + tid] * invN - mean * mean;
  float a = rsqrtf((float)var + 1e-5f) * w[tid];
  na[tid] = a; nb[tid] = b[tid] - (float)mean * a;
}

// ---------------- encoder layer ----------------
template <bool ACT>
__global__ void k_enc(const float* __restrict__ in, const float* __restrict__ w,
                      const float* __restrict__ b, const float* __restrict__ Wg,
                      const double* __restrict__ sin_, float* __restrict__ out,
                      double* __restrict__ sout, int N) {
  __shared__ float W[4096];
  __shared__ float hl[4][64];
  __shared__ float na[64], nb[64];
  __shared__ float red[256];
  int tid = threadIdx.x;
  if (tid < 64) norm_coeffs(sin_, tid, N, w, b, na, nb);
  for (int k = tid; k < 4096; k += 256) W[k] = Wg[k];
  __syncthreads();
  int nl = tid >> 6, j = tid & 63;
  int Nc = (N + 3) >> 2;
  float ssum = 0.f, ssq = 0.f;
  for (int chunk = blockIdx.x; chunk < Nc; chunk += gridDim.x) {
    int node = chunk * 4 + nl;
    bool valid = node < N;
    float hv = valid ? (in[node * 64 + j] * na[j] + nb[j]) : 0.f;
    hl[nl][j] = ACT ? elu_f(hv) : hv;
    __syncthreads();
    if (valid) {
      float acc = 0.f;
#pragma unroll
      for (int i = 0; i < 64; i++) acc += hl[nl][i] * W[i * 64 + j];
      out[node * 64 + j] = acc;
      ssum += acc; ssq += acc * acc;
    }
    __syncthreads();
  }
  red[tid] = ssum; __syncthreads();
  if (tid < 64) atomicAdd(&sout[tid], (double)(red[tid] + red[tid + 64] + red[tid + 128] + red[tid + 192]));
  __syncthreads();
  red[tid] = ssq; __syncthreads();
  if (tid < 64) atomicAdd(&sout[64 + tid], (double)(red[tid] + red[tid + 64] + red[tid + 128] + red[tid + 192]));
}

// ---------------- encoder layer 3 + xl(bf16)/xr projections ----------------
__global__ void k_enc3(const float* __restrict__ tB, const float* __restrict__ w,
                       const float* __restrict__ b, const float* __restrict__ Wlw,
                       const float* __restrict__ Wrw, const double* __restrict__ s2,
                       float* __restrict__ jk, u16* __restrict__ xlb, float* __restrict__ xr,
                       int N) {
  __shared__ float WL[4096], WR[4096];
  __shared__ float hl[4][64];
  __shared__ float na[64], nb[64];
  int tid = threadIdx.x;
  if (tid < 64) norm_coeffs(s2, tid, N, w, b, na, nb);
  for (int k = tid; k < 4096; k += 256) { WL[k] = Wlw[k]; WR[k] = Wrw[k]; }
  __syncthreads();
  int nl = tid >> 6, j = tid & 63;
  int Nc = (N + 3) >> 2;
  for (int chunk = blockIdx.x; chunk < Nc; chunk += gridDim.x) {
    int node = chunk * 4 + nl;
    bool valid = node < N;
    float h3 = valid ? elu_f(tB[node * 64 + j] * na[j] + nb[j]) : 0.f;
    hl[nl][j] = h3;
    __syncthreads();
    if (valid) {
      jk[node * 64 + j] = h3;
      float al = 0.f, ar = 0.f;
#pragma unroll
      for (int i = 0; i < 64; i++) {
        float h = hl[nl][i];
        al += h * WL[i * 64 + j];
        ar += h * WR[i * 64 + j];
      }
      xlb[node * 64 + j] = f2bf(al);
      xr[node * 64 + j] = ar;
    }
    __syncthreads();
  }
}

// ---------------- degree count: 8-way XCD-replicated ----------------
__global__ void k_deg(const int* __restrict__ ei, int* __restrict__ deg8, int E, int N,
                      const int* __restrict__ i32flag) {
  int e = blockIdx.x * 256 + threadIdx.x;
  if (e >= E + N) return;
  int r = blockIdx.x & 7;
  int dst;
  if (e < E) {
    if (*i32flag) dst = ei[E + e];
    else { const ll* el = (const ll*)ei; dst = (int)el[E + e]; }
  } else dst = e - E;
  atomicAdd(&deg8[r * N + dst], 1);
}

// ---------------- coalesced scan: A (block sums), B (scan sums), C (final) --
__global__ void k_scanA(const int* __restrict__ deg8, int* __restrict__ bsum, int N) {
  __shared__ int red[256];
  int tid = threadIdx.x;
  int base = blockIdx.x * 1024;
  int s = 0;
#pragma unroll
  for (int q = 0; q < 4; q++) {
    int n = base + q * 256 + tid;
    if (n < N) {
#pragma unroll
      for (int r = 0; r < 8; r++) s += deg8[r * N + n];
    }
  }
  red[tid] = s; __syncthreads();
  for (int o = 128; o > 0; o >>= 1) {
    if (tid < o) red[tid] += red[tid + o];
    __syncthreads();
  }
  if (tid == 0) bsum[blockIdx.x] = red[0];
}

__global__ void k_scanB(const int* __restrict__ bsum, int* __restrict__ bscan,
                        int* __restrict__ offs, int NB, int N) {
  if (threadIdx.x == 0) {
    int run = 0;
    for (int b = 0; b < NB; b++) { bscan[b] = run; run += bsum[b]; }
    offs[N] = run;
  }
}

__global__ void k_scanC(const int* __restrict__ deg8, const int* __restrict__ bscan,
                        int* __restrict__ offs, int* __restrict__ cursor8, int N) {
  __shared__ int dt[1024];
  __shared__ int tp[256];
  int tid = threadIdx.x;
  int base = blockIdx.x * 1024;
#pragma unroll
  for (int q = 0; q < 4; q++) {
    int n = base + q * 256 + tid;
    int s = 0;
    if (n < N) {
#pragma unroll
      for (int r = 0; r < 8; r++) s += deg8[r * N + n];
    }
    dt[q * 256 + tid] = s;
  }
  __syncthreads();
  int t4 = tid * 4;
  int l0 = dt[t4], l1 = dt[t4 + 1], l2 = dt[t4 + 2], l3 = dt[t4 + 3];
  int tot = l0 + l1 + l2 + l3;
  tp[tid] = tot; __syncthreads();
  for (int o = 1; o < 256; o <<= 1) {
    int v = (tid >= o) ? tp[tid - o] : 0;
    __syncthreads();
    tp[tid] += v;
    __syncthreads();
  }
  int run = bscan[blockIdx.x] + tp[tid] - tot;
#pragma unroll
  for (int k = 0; k < 4; k++) {
    int n = base + t4 + k;
    if (n < N) {
      offs[n] = run;
      int b = run;
#pragma unroll
      for (int r = 0; r < 8; r++) { cursor8[r * N + n] = b; b += deg8[r * N + n]; }
      run = b;
    }
  }
}

// ---------------- scatter: bf16x8 eattr (+packed src) into CSR order --------
// PACKED (N<=65536): U.w = (src<<16)|p[6]; ONE 16B scattered store per edge.
// else: separate csr_src store (old path).
template <bool PACKED>
__global__ void k_scatter(const int* __restrict__ ei, const float* __restrict__ eattr,
                          int* __restrict__ cursor8, int* __restrict__ csr_src,
                          uint4* __restrict__ ea2, int E, int N,
                          const int* __restrict__ i32flag) {
  int e = blockIdx.x * 256 + threadIdx.x;
  if (e >= E + N) return;
  int r = blockIdx.x & 7;
  int src, dst;
  u16 p[8];
  if (e < E) {
    if (*i32flag) { src = ei[e]; dst = ei[E + e]; }
    else { const ll* el = (const ll*)ei; src = (int)el[e]; dst = (int)el[E + e]; }
    const float* ea = eattr + (size_t)e * 7;
#pragma unroll
    for (int q = 0; q < 7; q++) p[q] = f2bf(ea[q]);
    p[7] = 0;
  } else {
    src = e - E; dst = src;
#pragma unroll
    for (int q = 0; q < 8; q++) p[q] = 0;
    p[6] = 0x3F80;   // FILL: e_6 = 1.0
  }
  int pos = atomicAdd(&cursor8[r * N + dst], 1);
  uint4 U;
  U.x = ((unsigned)p[1] << 16) | p[0];
  U.y = ((unsigned)p[3] << 16) | p[2];
  U.z = ((unsigned)p[5] << 16) | p[4];
  if (PACKED) {
    U.w = ((unsigned)src << 16) | p[6];
  } else {
    U.w = ((unsigned)p[7] << 16) | p[6];
    csr_src[pos] = src;
  }
  ea2[pos] = U;
}

// ---------------- fused GAT: persistent, wave/node, 16 lanes/edge ----------
// PACKED: src decoded from ea2.w>>16 (no csr_src stream). 3-stage pipeline:
// ptr-load b+2 | xlb gather b+1 | compute b. Stats in regs, block-exit atomics.
template <bool PACKED>
__global__ void k_gat(const int* __restrict__ offs, const int* __restrict__ csr_src,
                      const uint4* __restrict__ ea2,
                      const u16* __restrict__ xlb, const float* __restrict__ xr,
                      const float* __restrict__ Wew, const float* __restrict__ attw,
                      float* __restrict__ gat, double* __restrict__ s3, int N) {
  __shared__ float sb[4][64];
  int tid = threadIdx.x;
  int wid = tid >> 6;          // wave id in block = node slot
  int lane = tid & 63;
  int g = lane >> 4;           // edge slot within 4-edge batch
  int l = lane & 15;           // channel quad index: owns channels 4l..4l+3
  int Nc = (N + 3) >> 2;

  // per-lane constants in registers
  float4 wq[7];
#pragma unroll
  for (int q = 0; q < 7; q++) wq[q] = *(const float4*)(Wew + q * 64 + 4 * l);
  float4 attv = *(const float4*)(attw + 4 * l);

  // running per-channel stats (meaningful on g==0 lanes only)
  float ts0 = 0.f, ts1 = 0.f, ts2 = 0.f, ts3 = 0.f;
  float tq0 = 0.f, tq1 = 0.f, tq2 = 0.f, tq3 = 0.f;

  for (int chunk = blockIdx.x; chunk < Nc; chunk += gridDim.x) {
    int node = chunk * 4 + wid;
    if (node >= N) continue;
    float4 xrv = *(const float4*)(xr + node * 64 + 4 * l);
    int st = offs[node];
    int dg = offs[node + 1] - st;
    int nb = (dg + 3) >> 2;
    float sden = 0.f;
    float a0 = 0.f, a1 = 0.f, a2 = 0.f, a3 = 0.f;

    // ---- pipeline prologue: batches 0 and 1 loads, batch 0 gather ----
    int i0 = st + g;
    uint4 UC = ea2[i0];              // batch 0 record
    uint4 UN = ea2[i0 + 4];          // batch 1 record (pad-safe)
    int scC, scN;
    if (PACKED) {
      scC = (int)(UC.w >> 16);
      scN = (int)(UN.w >> 16);
    } else {
      scC = csr_src[i0];
      scN = csr_src[i0 + 4];
    }
    scC = ((unsigned)scC < (unsigned)N) ? scC : 0;
    uint2 xwC = *(const uint2*)(xlb + scC * 64 + 4 * l);   // batch 0 gather

    for (int b = 0; b < nb; b++) {
      // stage A: issue record load for batch b+2 (max idx st+dg+10 < pad 16)
      int iA = st + (b + 2) * 4 + g;
      uint4 UA = ea2[iA];
      int scA = PACKED ? 0 : csr_src[iA];
      // stage B: issue gather for batch b+1 (UN/scN landed one iteration ago)
      int scg = PACKED ? (int)(UN.w >> 16) : scN;
      scg = ((unsigned)scg < (unsigned)N) ? scg : 0;
      uint2 xwN = *(const uint2*)(xlb + scg * 64 + 4 * l);
      // stage C: compute batch b from xwC/UC (issued >=1 iteration ago)
      bool valid = (b * 4 + g) < dg;
      float x0 = bflo(xwC.x), x1 = bfhi(xwC.x), x2 = bflo(xwC.y), x3 = bfhi(xwC.y);
      float e0 = bflo(UC.x), e1 = bfhi(UC.x), e2 = bflo(UC.y), e3 = bfhi(UC.y);
      float e4 = bflo(UC.z), e5 = bfhi(UC.z), e6 = bflo(UC.w);
      float m0 = x0 + xrv.x + e0*wq[0].x + e1*wq[1].x + e2*wq[2].x + e3*wq[3].x + e4*wq[4].x + e5*wq[5].x + e6*wq[6].x;
      float m1 = x1 + xrv.y + e0*wq[0].y + e1*wq[1].y + e2*wq[2].y + e3*wq[3].y + e4*wq[4].y + e5*wq[5].y + e6*wq[6].y;
      float m2 = x2 + xrv.z + e0*wq[0].z + e1*wq[1].z + e2*wq[2].z + e3*wq[3].z + e4*wq[4].z + e5*wq[5].z + e6*wq[6].z;
      float m3 = x3 + xrv.w + e0*wq[0].w + e1*wq[1].w + e2*wq[2].w + e3*wq[3].w + e4*wq[4].w + e5*wq[5].w + e6*wq[6].w;
      m0 = m0 > 0.f ? m0 : 0.2f * m0;
      m1 = m1 > 0.f ? m1 : 0.2f * m1;
      m2 = m2 > 0.f ? m2 : 0.2f * m2;
      m3 = m3 > 0.f ? m3 : 0.2f * m3;
      float pp = m0 * attv.x + m1 * attv.y + m2 * attv.z + m3 * attv.w;
      pp += __shfl_xor(pp, 1, 64);     // quad reduce: 4 lanes = 16 channels = head
      pp += __shfl_xor(pp, 2, 64);
      float ex = valid ? __expf(pp) : 0.f;
      sden += ex;
      a0 += ex * x0; a1 += ex * x1; a2 += ex * x2; a3 += ex * x3;
      // rotate pipeline registers
      xwC = xwN; UC = UN; UN = UA; scN = scA;
    }
    // sum over the 4 edge-groups
    a0 += __shfl_xor(a0, 16, 64); a0 += __shfl_xor(a0, 32, 64);
    a1 += __shfl_xor(a1, 16, 64); a1 += __shfl_xor(a1, 32, 64);
    a2 += __shfl_xor(a2, 16, 64); a2 += __shfl_xor(a2, 32, 64);
    a3 += __shfl_xor(a3, 16, 64); a3 += __shfl_xor(a3, 32, 64);
    sden += __shfl_xor(sden, 16, 64); sden += __shfl_xor(sden, 32, 64);
    float inv = 1.f / (sden * (float)dg);
    float val0 = a0 * inv, val1 = a1 * inv, val2 = a2 * inv, val3 = a3 * inv;
    if (g == 0) {
      float4 o = make_float4(val0, val1, val2, val3);
      *(float4*)(gat + node * 64 + 4 * l) = o;
      ts0 += val0; ts1 += val1; ts2 += val2; ts3 += val3;
      tq0 += val0 * val0; tq1 += val1 * val1; tq2 += val2 * val2; tq3 += val3 * val3;
    }
  }

  // ---- block-exit stats reduction: transpose to per-channel, 128 atomics ----
  if (g == 0) {
    sb[wid][4 * l + 0] = ts0; sb[wid][4 * l + 1] = ts1;
    sb[wid][4 * l + 2] = ts2; sb[wid][4 * l + 3] = ts3;
  }
  __syncthreads();
  if (tid < 64) {
    float v = sb[0][tid] + sb[1][tid] + sb[2][tid] + sb[3][tid];
    atomicAdd(&s3[tid], (double)v);
  }
  __syncthreads();
  if (g == 0) {
    sb[wid][4 * l + 0] = tq0; sb[wid][4 * l + 1] = tq1;
    sb[wid][4 * l + 2] = tq2; sb[wid][4 * l + 3] = tq3;
  }
  __syncthreads();
  if (tid < 64) {
    float v = sb[0][tid] + sb[1][tid] + sb[2][tid] + sb[3][tid];
    atomicAdd(&s3[64 + tid], (double)v);
  }
}

// ---------------- atomic fallback (if CSR doesn't fit) ----------------
__global__ void k_edge2(const int* __restrict__ ei, const float* __restrict__ eattr,
                        const u16* __restrict__ xlb, const float* __restrict__ xr,
                        const float* __restrict__ Wew, const float* __restrict__ attw,
                        float* __restrict__ agg, float* __restrict__ denom,
                        int* __restrict__ deg, int E, int N,
                        const int* __restrict__ i32flag) {
  __shared__ float sWe[448];
  __shared__ float satt[64];
  int tid = threadIdx.x;
  for (int k = tid; k < 448; k += 256) sWe[k] = Wew[k];
  if (tid < 64) satt[tid] = attw[tid];
  __syncthreads();
  int e = blockIdx.x * 4 + (tid >> 6);
  if (e >= E + N) return;
  int lane = tid & 63;
  int src, dst;
  if (e < E) {
    if (*i32flag) { src = ei[e]; dst = ei[E + e]; }
    else { const ll* el = (const ll*)ei; src = (int)el[e]; dst = (int)el[E + e]; }
  } else { src = e - E; dst = src; }
  float xlv = bf(xlb[src * 64 + lane]);
  float m = xlv + xr[dst * 64 + lane];
  if (e < E) {
#pragma unroll
    for (int k = 0; k < 7; k++) m += eattr[e * 7 + k] * sWe[k * 64 + lane];
  } else {
    m += sWe[6 * 64 + lane];
  }
  float lr = m > 0.f ? m : 0.2f * m;
  float p = lr * satt[lane];
  p += __shfl_xor(p, 1, 64);
  p += __shfl_xor(p, 2, 64);
  p += __shfl_xor(p, 4, 64);
  p += __shfl_xor(p, 8, 64);
  float ex = __expf(p);
  atomicAdd(&agg[dst * 64 + lane], ex * xlv);
  if ((lane & 15) == 0) atomicAdd(&denom[dst * 4 + (lane >> 4)], ex);
  if (lane == 0) atomicAdd(&deg[dst], 1);
}

__global__ void k_gatnorm(float* __restrict__ agg, const float* __restrict__ denom,
                          const int* __restrict__ deg, double* __restrict__ s3, int N) {
  __shared__ float red[256];
  int tid = threadIdx.x;
  int idx = blockIdx.x * 256 + tid;
  float v = 0.f;
  if (idx < N * 64) {
    int n = idx >> 6, c = idx & 63, h = c >> 4;
    v = agg[idx] / (denom[n * 4 + h] * (float)deg[n]);
    agg[idx] = v;
  }
  red[tid] = v; __syncthreads();
  if (tid < 64) atomicAdd(&s3[tid], (double)(red[tid] + red[tid + 64] + red[tid + 128] + red[tid + 192]));
  __syncthreads();
  red[tid] = v * v; __syncthreads();
  if (tid < 64) atomicAdd(&s3[64 + tid], (double)(red[tid] + red[tid + 64] + red[tid + 128] + red[tid + 192]));
}

// ---------------- h4 = elu(h3 + inorm(gat)) ----------------
__global__ void k_h4(const float* __restrict__ jk, const float* __restrict__ gat,
                     const float* __restrict__ gn_w, const float* __restrict__ gn_b,
                     const double* __restrict__ s3, float* __restrict__ h4, int N) {
  __shared__ float na[64], nb[64];
  int tid = threadIdx.x;
  if (tid < 64) norm_coeffs(s3, tid, N, gn_w, gn_b, na, nb);
  __syncthreads();
  int idx = blockIdx.x * 256 + tid;
  if (idx >= N * 64) return;
  int c = idx & 63;
  h4[idx] = elu_f(jk[idx] + gat[idx] * na[c] + nb[c]);
}

// ---------------- weight prep: fragment-ordered bf16 hi/lo for dW1..dW5 -----
// Tile t covers B[k][n]: k = kt*32 + (lane>>4)*8 + i, n = nt*16 + (lane&15).
// Storage: whi[(t*64+lane)*8 + i] -> B-frag load is one coalesced b128/lane.
// Tile bases: L1[128->256]=0(64), L2[256->128]=64(64), L3[128->64]=128(16),
//             L4[64->32]=144(4), L5[32->16]=148(1). Total 149 tiles.
__global__ void k_wprep(const float* __restrict__ dW1, const float* __restrict__ dW2,
                        const float* __restrict__ dW3, const float* __restrict__ dW4,
                        const float* __restrict__ dW5,
                        u16* __restrict__ whi, u16* __restrict__ wlo) {
  int t = blockIdx.x;
  int tid = threadIdx.x;
  const float* W; int LIN, LOUT, base;
  if (t < 64)       { W = dW1; LIN = 128; LOUT = 256; base = 0; }
  else if (t < 128) { W = dW2; LIN = 256; LOUT = 128; base = 64; }
  else if (t < 144) { W = dW3; LIN = 128; LOUT = 64;  base = 128; }
  else if (t < 148) { W = dW4; LIN = 64;  LOUT = 32;  base = 144; }
  else              { W = dW5; LIN = 32;  LOUT = 16;  base = 148; }
  int KT = LIN >> 5;
  int tl = t - base;
  int nt = tl / KT, kt = tl % KT;
#pragma unroll
  for (int half = 0; half < 2; half++) {
    int lane = (tid >> 3) + half * 32;
    int i = tid & 7;
    int kg = kt * 32 + (lane >> 4) * 8 + i;
    int ng = nt * 16 + (lane & 15);
    float v = W[kg * LOUT + ng];
    u16 hi = f2bf(v);
    u16 lo = f2bf(v - bf(hi));
    whi[((size_t)t * 64 + lane) * 8 + i] = hi;
    wlo[((size_t)t * 64 + lane) * 8 + i] = lo;
  }
}

// ---------------- decoder: MFMA split-bf16 layer -----------------------------
template <int LIN, int LOUT, int TBASE>
__device__ __forceinline__ void mfmaLayer(const u16* __restrict__ whi, const u16* __restrict__ wlo,
                                          const float* __restrict__ bias,
                                          const u16* __restrict__ Ahi, const u16* __restrict__ Alo,
                                          u16* __restrict__ Ohi, u16* __restrict__ Olo,
                                          int wid, int lane) {
  constexpr int KT = LIN / 32, NT = LOUT / 16;
  constexpr int SIN = LIN + 8, SOUT = LOUT + 8;
  int l15 = lane & 15, kg = lane >> 4;
  int aoff = l15 * SIN + kg * 8;
  for (int nt = wid; nt < NT; nt += 4) {
    float bn = bias[nt * 16 + l15];
    f32x4 acc = {bn, bn, bn, bn};
    for (int kt = 0; kt < KT; kt++) {
      s16x8 ah = *(const s16x8*)(Ahi + aoff + kt * 32);
      s16x8 al = *(const s16x8*)(Alo + aoff + kt * 32);
      const u16* wp = whi + ((size_t)(TBASE + nt * KT + kt) * 64 + lane) * 8;
      const u16* wq = wlo + ((size_t)(TBASE + nt * KT + kt) * 64 + lane) * 8;
      s16x8 wh = *(const s16x8*)(wp);
      s16x8 wl = *(const s16x8*)(wq);
      acc = __builtin_amdgcn_mfma_f32_16x16x32_bf16(ah, wh, acc, 0, 0, 0);
      acc = __builtin_amdgcn_mfma_f32_16x16x32_bf16(ah, wl, acc, 0, 0, 0);
      acc = __builtin_amdgcn_mfma_f32_16x16x32_bf16(al, wh, acc, 0, 0, 0);
    }
#pragma unroll
    for (int r = 0; r < 4; r++) {
      int m = kg * 4 + r;
      float v = elu_f(acc[r]);
      u16 hi = f2bf(v);
      u16 lo = f2bf(v - bf(hi));
      Ohi[m * SOUT + nt * 16 + l15] = hi;
      Olo[m * SOUT + nt * 16 + l15] = lo;
    }
  }
}

__global__ void k_dec(const float* __restrict__ jk, const float* __restrict__ h4,
                      const u16* __restrict__ whi, const u16* __restrict__ wlo,
                      const float* __restrict__ db1, const float* __restrict__ db2,
                      const float* __restrict__ db3, const float* __restrict__ db4,
                      const float* __restrict__ db5,
                      const float* __restrict__ dW6, const float* __restrict__ db6,
                      float* __restrict__ outdec, int N) {
  // ping-pong act buffers, bf16 hi/lo, [16 nodes][stride] (stride = LIN+8)
  __shared__ __align__(16) u16 bHi0[16 * 264], bLo0[16 * 264];
  __shared__ __align__(16) u16 bHi1[16 * 264], bLo1[16 * 264];
  int tid = threadIdx.x;
  int wid = tid >> 6, lane = tid & 63;
  int g0 = blockIdx.x * 16;
  // stage input: [node][136] = 128 ch of (jk | h4), bf16 hi/lo
  for (int k = tid; k < 16 * 128; k += 256) {
    int i = k & 127, node = k >> 7;
    int gn = g0 + node;
    float v = 0.f;
    if (gn < N) v = (i < 64) ? jk[gn * 64 + i] : h4[gn * 64 + (i - 64)];
    u16 hi = f2bf(v);
    u16 lo = f2bf(v - bf(hi));
    bHi0[node * 136 + i] = hi;
    bLo0[node * 136 + i] = lo;
  }
  __syncthreads();
  mfmaLayer<128, 256, 0>(whi, wlo, db1, bHi0, bLo0, bHi1, bLo1, wid, lane); __syncthreads();
  mfmaLayer<256, 128, 64>(whi, wlo, db2, bHi1, bLo1, bHi0, bLo0, wid, lane); __syncthreads();
  mfmaLayer<128, 64, 128>(whi, wlo, db3, bHi0, bLo0, bHi1, bLo1, wid, lane); __syncthreads();
  mfmaLayer<64, 32, 144>(whi, wlo, db4, bHi1, bLo1, bHi0, bLo0, wid, lane); __syncthreads();
  mfmaLayer<32, 16, 148>(whi, wlo, db5, bHi0, bLo0, bHi1, bLo1, wid, lane); __syncthreads();
  // final 16 -> 2 (fp32 scalar; act rows stride 24)
  if (tid < 32) {
    int node = tid >> 1, j = tid & 1;
    int gn = g0 + node;
    if (gn < N) {
      float s = db6[j];
#pragma unroll
      for (int i = 0; i < 16; i++) {
        float a = bf(bHi1[node * 24 + i]) + bf(bLo1[node * 24 + i]);
        s += a * dW6[i * 2 + j];
      }
      outdec[gn * 2 + j] = s;
    }
  }
}

// ---------------- recon MLP: 16-node chunks, transposed LDS ----------------
__global__ void k_recon(const float* __restrict__ h4,
                        const float* __restrict__ rW1, const float* __restrict__ rb1,
                        const float* __restrict__ rW2, const float* __restrict__ rb2,
                        const float* __restrict__ rW3, const float* __restrict__ rb3,
                        float* __restrict__ outrec, int N) {
  __shared__ float W1[4096], W2[4096], W3[4096];
  __shared__ float b1[64], b2[64], b3[64];
  __shared__ float A[64 * 16], Bb[64 * 16];
  int tid = threadIdx.x;
  for (int k = tid; k < 4096; k += 256) { W1[k] = rW1[k]; W2[k] = rW2[k]; W3[k] = rW3[k]; }
  if (tid < 64) { b1[tid] = rb1[tid]; b2[tid] = rb2[tid]; b3[tid] = rb3[tid]; }
  __syncthreads();
  int j = tid & 63, g = tid >> 6;
  int Nc = (N + 15) >> 4;
  for (int chunk = blockIdx.x; chunk < Nc; chunk += gridDim.x) {
    int g0 = chunk * 16;
    for (int k = tid; k < 16 * 64; k += 256) {
      int i = k & 63, node = k >> 6;
      int gn = g0 + node;
      A[i * 16 + node] = (gn < N) ? h4[gn * 64 + i] : 0.f;
    }
    __syncthreads();
    {
      float a0 = b1[j], a1 = b1[j], a2 = b1[j], a3 = b1[j];
#pragma unroll 4
      for (int i = 0; i < 64; i++) {
        float w = W1[i * 64 + j];
        float4 a = *(const float4*)(&A[i * 16 + g * 4]);
        a0 += a.x * w; a1 += a.y * w; a2 += a.z * w; a3 += a.w * w;
      }
      Bb[j * 16 + g * 4 + 0] = elu_f(a0);
      Bb[j * 16 + g * 4 + 1] = elu_f(a1);
      Bb[j * 16 + g * 4 + 2] = elu_f(a2);
      Bb[j * 16 + g * 4 + 3] = elu_f(a3);
    }
    __syncthreads();
    {
      float a0 = b2[j], a1 = b2[j], a2 = b2[j], a3 = b2[j];
#pragma unroll 4
      for (int i = 0; i < 64; i++) {
        float w = W2[i * 64 + j];
        float4 a = *(const float4*)(&Bb[i * 16 + g * 4]);
        a0 += a.x * w; a1 += a.y * w; a2 += a.z * w; a3 += a.w * w;
      }
      A[j * 16 + g * 4 + 0] = elu_f(a0);
      A[j * 16 + g * 4 + 1] = elu_f(a1);
      A[j * 16 + g * 4 + 2] = elu_f(a2);
      A[j * 16 + g * 4 + 3] = elu_f(a3);
    }
    __syncthreads();
    {
      float a0 = b3[j], a1 = b3[j], a2 = b3[j], a3 = b3[j];
#pragma unroll 4
      for (int i = 0; i < 64; i++) {
        float w = W3[i * 64 + j];
        float4 a = *(const float4*)(&A[i * 16 + g * 4]);
        a0 += a.x * w; a1 += a.y * w; a2 += a.z * w; a3 += a.w * w;
      }
      float o[4] = {a0, a1, a2, a3};
#pragma unroll
      for (int u = 0; u < 4; u++) {
        int gn = g0 + g * 4 + u;
        if (gn < N) outrec[gn * 64 + j] = o[u];
      }
    }
    __syncthreads();
  }
}

// ---------------- sentinel ----------------
__global__ void k_sentinel(float* __restrict__ out, float v) {
  if (threadIdx.x == 0) out[0] = v;
}

extern "C" void kernel_launch(void* const* d_in, const int* in_sizes, int n_in,
                              void* d_out, int out_size, void* d_ws, size_t ws_size,
                              hipStream_t stream) {
  (void)n_in; (void)out_size;
  const float* x     = (const float*)d_in[0];
  const int*   ei    = (const int*)d_in[1];
  const float* ea    = (const float*)d_in[2];
  const float* pre_w = (const float*)d_in[3];
  const float* pre_b = (const float*)d_in[4];
  const float* eW1   = (const float*)d_in[5];
  const float* en1w  = (const float*)d_in[6];
  const float* en1b  = (const float*)d_in[7];
  const float* eW2   = (const float*)d_in[8];
  const float* en2w  = (const float*)d_in[9];
  const float* en2b  = (const float*)d_in[10];
  const float* Wl    = (const float*)d_in[11];
  const float* Wr    = (const float*)d_in[12];
  const float* Wew   = (const float*)d_in[13];
  const float* attw  = (const float*)d_in[14];
  const float* gn_w  = (const float*)d_in[15];
  const float* gn_b  = (const float*)d_in[16];
  const float* dW1 = (const float*)d_in[17]; const float* db1 = (const float*)d_in[18];
  const float* dW2 = (const float*)d_in[19]; const float* db2 = (const float*)d_in[20];
  const float* dW3 = (const float*)d_in[21]; const float* db3 = (const float*)d_in[22];
  const float* dW4 = (const float*)d_in[23]; const float* db4 = (const float*)d_in[24];
  const float* dW5 = (const float*)d_in[25]; const float* db5 = (const float*)d_in[26];
  const float* dW6 = (const float*)d_in[27]; const float* db6 = (const float*)d_in[28];
  const float* rW1 = (const float*)d_in[29]; const float* rb1 = (const float*)d_in[30];
  const float* rW2 = (const float*)d_in[31]; const float* rb2 = (const float*)d_in[32];
  const float* rW3 = (const float*)d_in[33]; const float* rb3 = (const float*)d_in[34];

  int D  = in_sizes[3];
  int N  = in_sizes[0] / (D > 0 ? D : 1);
  int E  = in_sizes[1] / 2;
  int ED = E > 0 ? in_sizes[2] / E : 0;
  float* outdec = (float*)d_out;
  float* outrec = outdec + (size_t)N * 2;
  if (D != 64 || ED != 7 || in_sizes[14] != 64) {
    k_sentinel<<<1, 64, 0, stream>>>(outdec, 2000.f);
    return;
  }
  int Etot = E + N;

  char* w = (char*)d_ws;
  size_t off = 0;
  auto alloc = [&](size_t bytes) -> void* {
    void* p = w + off;
    off += (bytes + 255) & ~(size_t)255;
    return p;
  };
  const size_t FEATF = (size_t)N * 64 * 4;
  float* B1    = (float*)alloc(FEATF);             // t1 -> gat (or agg fallback)
  size_t ea2_bytes = ((size_t)Etot + 16) * 16;     // +16 pad: pipeline prefetch depth
  size_t b2ext = ea2_bytes > FEATF ? ea2_bytes : FEATF;
  float* B2    = (float*)alloc(b2ext);
  float* jk    = (float*)alloc(FEATF);
  u16*   xlb   = (u16*)  alloc((size_t)N * 64 * 2);
  float* xr    = (float*)alloc(FEATF);
  int*   offs  = (int*)  alloc(((size_t)N + 1) * 4);
  int*   deg8  = (int*)  alloc((size_t)N * 8 * 4);
  int*   cursor8=(int*)  alloc((size_t)N * 8 * 4);
  int*   bsum  = (int*)  alloc(4096);
  int*   bscan = (int*)  alloc(4096);
  double* stats = (double*)alloc(4 * 128 * 8);
  int* i32flag = (int*)alloc(256);
  float* denom = (float*)alloc((size_t)N * 4 * 4);  // fallback only
  u16* whi = (u16*)alloc((size_t)149 * 512 * 2);    // fragment-ordered bf16 hi
  u16* wlo = (u16*)alloc((size_t)149 * 512 * 2);    // fragment-ordered bf16 lo
  size_t base_off = off;
  int* csr_src = (int*)alloc(((size_t)Etot + 16) * 4);  // +16 pad (unpacked path)
  size_t csr_off = off;

  double* s0 = stats, *s1 = stats + 128, *s2 = stats + 256, *s3 = stats + 384;
  float* t1 = B1; float* gat = B1; float* agg = B1;
  float* t2 = B2; float* h4 = B2;
  uint4* ea2 = (uint4*)B2;   // aliases t2 (dead after k_enc3)

  bool packed = (N <= 65536);
  bool use_csr = packed ? (base_off <= ws_size) : (csr_off <= ws_size);
  if (!use_csr && base_off > ws_size) {
    k_sentinel<<<1, 64, 0, stream>>>(outdec, 1000.f);
    return;
  }

  hipMemsetAsync(stats, 0, 4 * 128 * 8, stream);
  hipMemsetAsync(i32flag, 0, 256, stream);
  hipMemsetAsync(deg8, 0, (size_t)N * 8 * 4, stream);

  int gN64 = (N * 64 + 255) / 256;
  int gE = (Etot + 255) / 256;
  int probeCnt = E < 1024 ? E : 1024;
  int NB = (N + 1023) / 1024;

  k_probe64<<<1, 256, 0, stream>>>(ei, probeCnt, i32flag);
  k_wprep<<<149, 256, 0, stream>>>(dW1, dW2, dW3, dW4, dW5, whi, wlo);
  k_stats_x<<<1024, 256, 0, stream>>>(x, N, s0);
  k_enc<false><<<1024, 256, 0, stream>>>(x, pre_w, pre_b, eW1, s0, t1, s1, N);
  k_enc<true><<<1024, 256, 0, stream>>>(t1, en1w, en1b, eW2, s1, t2, s2, N);
  k_enc3<<<1024, 256, 0, stream>>>(t2, en2w, en2b, Wl, Wr, s2, jk, xlb, xr, N);

  if (use_csr) {
    k_deg<<<gE, 256, 0, stream>>>(ei, deg8, E, N, i32flag);
    k_scanA<<<NB, 256, 0, stream>>>(deg8, bsum, N);
    k_scanB<<<1, 64, 0, stream>>>(bsum, bscan, offs, NB, N);
    k_scanC<<<NB, 256, 0, stream>>>(deg8, bscan, offs, cursor8, N);
    int ggat = 2048;
    int NcG = (N + 3) / 4;
    if (ggat > NcG) ggat = NcG;
    if (packed) {
      k_scatter<true><<<gE, 256, 0, stream>>>(ei, ea, cursor8, csr_src, ea2, E, N, i32flag);
      k_gat<true><<<ggat, 256, 0, stream>>>(offs, csr_src, ea2, xlb, xr, Wew, attw,
                                            gat, s3, N);
    } else {
      k_scatter<false><<<gE, 256, 0, stream>>>(ei, ea, cursor8, csr_src, ea2, E, N, i32flag);
      k_gat<false><<<ggat, 256, 0, stream>>>(offs, csr_src, ea2, xlb, xr, Wew, attw,
                                             gat, s3, N);
    }
  } else {
    hipMemsetAsync(agg, 0, FEATF, stream);
    hipMemsetAsync(denom, 0, (size_t)N * 4 * 4, stream);
    k_edge2<<<(Etot + 3) / 4, 256, 0, stream>>>(ei, ea, xlb, xr, Wew, attw, agg, denom,
                                                deg8, E, N, i32flag);
    k_gatnorm<<<gN64, 256, 0, stream>>>(agg, denom, deg8, s3, N);
  }

  k_h4<<<gN64, 256, 0, stream>>>(jk, gat, gn_w, gn_b, s3, h4, N);
  int NcD = (N + 15) / 16;
  k_dec<<<NcD, 256, 0, stream>>>(jk, h4, whi, wlo, db1, db2, db3, db4, db5,
                                 dW6, db6, outdec, N);
  k_recon<<<1024, 256, 0, stream>>>(h4, rW1, rb1, rW2, rb2, rW3, rb3, outrec, N);
}

// Round 12
// 625.193 us; speedup vs baseline: 1.3555x; 1.0666x over previous
//
#include <hip/hip_runtime.h>
#include <math.h>

// GAT model, MI355X. Round 25: RESUBMIT of R24 (bench infra failed twice;
// audit found no OOB/hang/race — same verified split-bf16 MFMA recipe as
// R22/R23). Encoder chain (k_encM x2, k_enc3M) and recon MLP (k_reconM) on
// MFMA; norm(+ELU) folded into A-staging; all weights prepped by k_wprep
// (205 tiles). Stats: per-lane register accum, shfl cross-kg reduce,
// block-exit atomics. R23 packed scatter/gat + R22 MFMA k_dec retained.

typedef long long ll;
typedef unsigned short u16;
typedef float f32x4 __attribute__((ext_vector_type(4)));
typedef short s16x8 __attribute__((ext_vector_type(8)));

__device__ __forceinline__ float bf(u16 u) { return __uint_as_float(((unsigned)u) << 16); }
__device__ __forceinline__ u16 f2bf(float f) {
  unsigned u = __float_as_uint(f);
  u += 0x7fffu + ((u >> 16) & 1u);   // RNE
  return (u16)(u >> 16);
}
__device__ __forceinline__ float bflo(unsigned u) { return __uint_as_float(u << 16); }
__device__ __forceinline__ float bfhi(unsigned u) { return __uint_as_float(u & 0xffff0000u); }
__device__ __forceinline__ float elu_f(float x) { return x > 0.f ? x : (__expf(x) - 1.f); }

// ---------------- probe: is edge_index int32 (flag=1) or int64 (flag=0)?
__global__ void k_probe64(const int* __restrict__ ei, int cnt, int* __restrict__ flag) {
  int tid = threadIdx.x;
  int nz = 0;
  for (int k = tid; k < cnt; k += 256) {
    if (ei[2 * k + 1] != 0) nz = 1;
  }
  if (nz) atomicOr(flag, 1);
}

// ---------------- stats of x ----------------
__global__ void k_stats_x(const float* __restrict__ x, int N, double* __restrict__ s0) {
  __shared__ float red[256];
  int tid = threadIdx.x;
  int c = tid & 63;
  float s = 0.f, ss = 0.f;
  for (int r = blockIdx.x * 4 + (tid >> 6); r < N; r += gridDim.x * 4) {
    float v = x[r * 64 + c];
    s += v; ss += v * v;
  }
  red[tid] = s; __syncthreads();
  if (tid < 64) atomicAdd(&s0[tid], (double)(red[tid] + red[tid + 64] + red[tid + 128] + red[tid + 192]));
  __syncthreads();
  red[tid] = ss; __syncthreads();
  if (tid < 64) atomicAdd(&s0[64 + tid], (double)(red[tid] + red[tid + 64] + red[tid + 128] + red[tid + 192]));
}

__device__ __forceinline__ void norm_coeffs(const double* s, int tid, int N,
                                            const float* w, const float* b,
                                            float* na, float* nb) {
  double invN = 1.0 / (double)N;
  double mean = s[tid] * invN;
  double var = s[64 + tid] * invN - mean * mean;
  float a = rsqrtf((float)var + 1e-5f) * w[tid];
  na[tid] = a; nb[tid] = b[tid] - (float)mean * a;
}

// ---------------- weight prep: fragment-ordered bf16 hi/lo ------------------
// Tile t covers B[k][n]: k = kt*32 + (lane>>4)*8 + i, n = nt*16 + (lane&15).
// Bases: dW1=0(64) dW2=64(64) dW3=128(16) dW4=144(4) dW5=148(1)
//        eW1=149(8) eW2=157(8) Wl=165(8) Wr=173(8) rW1=181(8) rW2=189(8)
//        rW3=197(8). Total 205 tiles.
__global__ void k_wprep(const float* __restrict__ dW1, const float* __restrict__ dW2,
                        const float* __restrict__ dW3, const float* __restrict__ dW4,
                        const float* __restrict__ dW5,
                        const float* __restrict__ eW1, const float* __restrict__ eW2,
                        const float* __restrict__ Wl, const float* __restrict__ Wr,
                        const float* __restrict__ rW1, const float* __restrict__ rW2,
                        const float* __restrict__ rW3,
                        u16* __restrict__ whi, u16* __restrict__ wlo) {
  int t = blockIdx.x;
  int tid = threadIdx.x;
  const float* W; int LIN, LOUT, base;
  if (t < 64)       { W = dW1; LIN = 128; LOUT = 256; base = 0; }
  else if (t < 128) { W = dW2; LIN = 256; LOUT = 128; base = 64; }
  else if (t < 144) { W = dW3; LIN = 128; LOUT = 64;  base = 128; }
  else if (t < 148) { W = dW4; LIN = 64;  LOUT = 32;  base = 144; }
  else if (t < 149) { W = dW5; LIN = 32;  LOUT = 16;  base = 148; }
  else if (t < 157) { W = eW1; LIN = 64;  LOUT = 64;  base = 149; }
  else if (t < 165) { W = eW2; LIN = 64;  LOUT = 64;  base = 157; }
  else if (t < 173) { W = Wl;  LIN = 64;  LOUT = 64;  base = 165; }
  else if (t < 181) { W = Wr;  LIN = 64;  LOUT = 64;  base = 173; }
  else if (t < 189) { W = rW1; LIN = 64;  LOUT = 64;  base = 181; }
  else if (t < 197) { W = rW2; LIN = 64;  LOUT = 64;  base = 189; }
  else              { W = rW3; LIN = 64;  LOUT = 64;  base = 197; }
  int KT = LIN >> 5;
  int tl = t - base;
  int nt = tl / KT, kt = tl % KT;
#pragma unroll
  for (int half = 0; half < 2; half++) {
    int lane = (tid >> 3) + half * 32;
    int i = tid & 7;
    int kg = kt * 32 + (lane >> 4) * 8 + i;
    int ng = nt * 16 + (lane & 15);
    float v = W[kg * LOUT + ng];
    u16 hi = f2bf(v);
    u16 lo = f2bf(v - bf(hi));
    whi[((size_t)t * 64 + lane) * 8 + i] = hi;
    wlo[((size_t)t * 64 + lane) * 8 + i] = lo;
  }
}

// ---------------- MFMA encoder layer: out = f(in*na+nb) @ W, + stats --------
template <bool INELU>
__global__ void k_encM(const float* __restrict__ in, const float* __restrict__ w,
                       const float* __restrict__ b, const u16* __restrict__ whi,
                       const u16* __restrict__ wlo, int TB,
                       const double* __restrict__ sin_, float* __restrict__ out,
                       double* __restrict__ sout, int N) {
  __shared__ __align__(16) u16 aHi[16 * 72], aLo[16 * 72];
  __shared__ float na[64], nb[64];
  __shared__ float sred[64];
  int tid = threadIdx.x;
  if (tid < 64) norm_coeffs(sin_, tid, N, w, b, na, nb);
  __syncthreads();
  int lane = tid & 63, wid = tid >> 6;
  int l15 = lane & 15, kg = lane >> 4;
  int Nc = (N + 15) >> 4;
  float ts = 0.f, tq = 0.f;
  for (int chunk = blockIdx.x; chunk < Nc; chunk += gridDim.x) {
    int g0 = chunk * 16;
    for (int k = tid; k < 1024; k += 256) {
      int i = k & 63, node = k >> 6;
      int gn = g0 + node;
      float v = 0.f;
      if (gn < N) {
        v = in[gn * 64 + i] * na[i] + nb[i];
        if (INELU) v = elu_f(v);
      }
      u16 hi = f2bf(v);
      aHi[node * 72 + i] = hi;
      aLo[node * 72 + i] = f2bf(v - bf(hi));
    }
    __syncthreads();
    f32x4 acc = {0.f, 0.f, 0.f, 0.f};
    int aoff = l15 * 72 + kg * 8;
#pragma unroll
    for (int kt = 0; kt < 2; kt++) {
      s16x8 ah = *(const s16x8*)(aHi + aoff + kt * 32);
      s16x8 al = *(const s16x8*)(aLo + aoff + kt * 32);
      const u16* wp = whi + ((size_t)(TB + wid * 2 + kt) * 64 + lane) * 8;
      const u16* wq = wlo + ((size_t)(TB + wid * 2 + kt) * 64 + lane) * 8;
      s16x8 wh = *(const s16x8*)wp;
      s16x8 wl = *(const s16x8*)wq;
      acc = __builtin_amdgcn_mfma_f32_16x16x32_bf16(ah, wh, acc, 0, 0, 0);
      acc = __builtin_amdgcn_mfma_f32_16x16x32_bf16(ah, wl, acc, 0, 0, 0);
      acc = __builtin_amdgcn_mfma_f32_16x16x32_bf16(al, wh, acc, 0, 0, 0);
    }
    int col = wid * 16 + l15;
#pragma unroll
    for (int r = 0; r < 4; r++) {
      int m = kg * 4 + r;
      int gn = g0 + m;
      if (gn < N) {
        float v = acc[r];
        out[gn * 64 + col] = v;
        ts += v; tq += v * v;
      }
    }
    __syncthreads();
  }
  ts += __shfl_xor(ts, 16, 64); ts += __shfl_xor(ts, 32, 64);
  tq += __shfl_xor(tq, 16, 64); tq += __shfl_xor(tq, 32, 64);
  if (kg == 0) sred[wid * 16 + l15] = ts;
  __syncthreads();
  if (tid < 64) atomicAdd(&sout[tid], (double)sred[tid]);
  __syncthreads();
  if (kg == 0) sred[wid * 16 + l15] = tq;
  __syncthreads();
  if (tid < 64) atomicAdd(&sout[64 + tid], (double)sred[tid]);
}

// ---------------- MFMA encoder layer 3: jk + xl(bf16) + xr ------------------
__global__ void k_enc3M(const float* __restrict__ t2, const float* __restrict__ w,
                        const float* __restrict__ b, const u16* __restrict__ whi,
                        const u16* __restrict__ wlo, const double* __restrict__ s2,
                        float* __restrict__ jk, u16* __restrict__ xlb,
                        float* __restrict__ xr, int N) {
  __shared__ __align__(16) u16 aHi[16 * 72], aLo[16 * 72];
  __shared__ float na[64], nb[64];
  int tid = threadIdx.x;
  if (tid < 64) norm_coeffs(s2, tid, N, w, b, na, nb);
  __syncthreads();
  int lane = tid & 63, wid = tid >> 6;
  int l15 = lane & 15, kg = lane >> 4;
  int Nc = (N + 15) >> 4;
  for (int chunk = blockIdx.x; chunk < Nc; chunk += gridDim.x) {
    int g0 = chunk * 16;
    for (int k = tid; k < 1024; k += 256) {
      int i = k & 63, node = k >> 6;
      int gn = g0 + node;
      float v = 0.f;
      if (gn < N) {
        v = elu_f(t2[gn * 64 + i] * na[i] + nb[i]);
        jk[gn * 64 + i] = v;
      }
      u16 hi = f2bf(v);
      aHi[node * 72 + i] = hi;
      aLo[node * 72 + i] = f2bf(v - bf(hi));
    }
    __syncthreads();
    int aoff = l15 * 72 + kg * 8;
    int col = wid * 16 + l15;
    // GEMM 1: Wl (base 165) -> xlb bf16
    {
      f32x4 acc = {0.f, 0.f, 0.f, 0.f};
#pragma unroll
      for (int kt = 0; kt < 2; kt++) {
        s16x8 ah = *(const s16x8*)(aHi + aoff + kt * 32);
        s16x8 al = *(const s16x8*)(aLo + aoff + kt * 32);
        const u16* wp = whi + ((size_t)(165 + wid * 2 + kt) * 64 + lane) * 8;
        const u16* wq = wlo + ((size_t)(165 + wid * 2 + kt) * 64 + lane) * 8;
        s16x8 wh = *(const s16x8*)wp;
        s16x8 wl = *(const s16x8*)wq;
        acc = __builtin_amdgcn_mfma_f32_16x16x32_bf16(ah, wh, acc, 0, 0, 0);
        acc = __builtin_amdgcn_mfma_f32_16x16x32_bf16(ah, wl, acc, 0, 0, 0);
        acc = __builtin_amdgcn_mfma_f32_16x16x32_bf16(al, wh, acc, 0, 0, 0);
      }
#pragma unroll
      for (int r = 0; r < 4; r++) {
        int gn = g0 + kg * 4 + r;
        if (gn < N) xlb[gn * 64 + col] = f2bf(acc[r]);
      }
    }
    // GEMM 2: Wr (base 173) -> xr fp32
    {
      f32x4 acc = {0.f, 0.f, 0.f, 0.f};
#pragma unroll
      for (int kt = 0; kt < 2; kt++) {
        s16x8 ah = *(const s16x8*)(aHi + aoff + kt * 32);
        s16x8 al = *(const s16x8*)(aLo + aoff + kt * 32);
        const u16* wp = whi + ((size_t)(173 + wid * 2 + kt) * 64 + lane) * 8;
        const u16* wq = wlo + ((size_t)(173 + wid * 2 + kt) * 64 + lane) * 8;
        s16x8 wh = *(const s16x8*)wp;
        s16x8 wl = *(const s16x8*)wq;
        acc = __builtin_amdgcn_mfma_f32_16x16x32_bf16(ah, wh, acc, 0, 0, 0);
        acc = __builtin_amdgcn_mfma_f32_16x16x32_bf16(ah, wl, acc, 0, 0, 0);
        acc = __builtin_amdgcn_mfma_f32_16x16x32_bf16(al, wh, acc, 0, 0, 0);
      }
#pragma unroll
      for (int r = 0; r < 4; r++) {
        int gn = g0 + kg * 4 + r;
        if (gn < N) xr[gn * 64 + col] = acc[r];
      }
    }
    __syncthreads();
  }
}

// ---------------- MFMA recon MLP: 3x (64->64), elu on 1-2 -------------------
__global__ void k_reconM(const float* __restrict__ h4, const u16* __restrict__ whi,
                         const u16* __restrict__ wlo,
                         const float* __restrict__ rb1, const float* __restrict__ rb2,
                         const float* __restrict__ rb3,
                         float* __restrict__ outrec, int N) {
  __shared__ __align__(16) u16 aHi[16 * 72], aLo[16 * 72];
  __shared__ __align__(16) u16 bHi[16 * 72], bLo[16 * 72];
  int tid = threadIdx.x;
  int lane = tid & 63, wid = tid >> 6;
  int l15 = lane & 15, kg = lane >> 4;
  int aoff = l15 * 72 + kg * 8;
  int col = wid * 16 + l15;
  int Nc = (N + 15) >> 4;
  for (int chunk = blockIdx.x; chunk < Nc; chunk += gridDim.x) {
    int g0 = chunk * 16;
    for (int k = tid; k < 1024; k += 256) {
      int i = k & 63, node = k >> 6;
      int gn = g0 + node;
      float v = (gn < N) ? h4[gn * 64 + i] : 0.f;
      u16 hi = f2bf(v);
      aHi[node * 72 + i] = hi;
      aLo[node * 72 + i] = f2bf(v - bf(hi));
    }
    __syncthreads();
    // layer 1: base 181, bias rb1, elu -> b
    {
      float bn = rb1[col];
      f32x4 acc = {bn, bn, bn, bn};
#pragma unroll
      for (int kt = 0; kt < 2; kt++) {
        s16x8 ah = *(const s16x8*)(aHi + aoff + kt * 32);
        s16x8 al = *(const s16x8*)(aLo + aoff + kt * 32);
        const u16* wp = whi + ((size_t)(181 + wid * 2 + kt) * 64 + lane) * 8;
        const u16* wq = wlo + ((size_t)(181 + wid * 2 + kt) * 64 + lane) * 8;
        s16x8 wh = *(const s16x8*)wp;
        s16x8 wl = *(const s16x8*)wq;
        acc = __builtin_amdgcn_mfma_f32_16x16x32_bf16(ah, wh, acc, 0, 0, 0);
        acc = __builtin_amdgcn_mfma_f32_16x16x32_bf16(ah, wl, acc, 0, 0, 0);
        acc = __builtin_amdgcn_mfma_f32_16x16x32_bf16(al, wh, acc, 0, 0, 0);
      }
#pragma unroll
      for (int r = 0; r < 4; r++) {
        int m = kg * 4 + r;
        float v = elu_f(acc[r]);
        u16 hi = f2bf(v);
        bHi[m * 72 + col] = hi;
        bLo[m * 72 + col] = f2bf(v - bf(hi));
      }
    }
    __syncthreads();
    // layer 2: base 189, bias rb2, elu -> a
    {
      float bn = rb2[col];
      f32x4 acc = {bn, bn, bn, bn};
#pragma unroll
      for (int kt = 0; kt < 2; kt++) {
        s16x8 ah = *(const s16x8*)(bHi + aoff + kt * 32);
        s16x8 al = *(const s16x8*)(bLo + aoff + kt * 32);
        const u16* wp = whi + ((size_t)(189 + wid * 2 + kt) * 64 + lane) * 8;
        const u16* wq = wlo + ((size_t)(189 + wid * 2 + kt) * 64 + lane) * 8;
        s16x8 wh = *(const s16x8*)wp;
        s16x8 wl = *(const s16x8*)wq;
        acc = __builtin_amdgcn_mfma_f32_16x16x32_bf16(ah, wh, acc, 0, 0, 0);
        acc = __builtin_amdgcn_mfma_f32_16x16x32_bf16(ah, wl, acc, 0, 0, 0);
        acc = __builtin_amdgcn_mfma_f32_16x16x32_bf16(al, wh, acc, 0, 0, 0);
      }
#pragma unroll
      for (int r = 0; r < 4; r++) {
        int m = kg * 4 + r;
        float v = elu_f(acc[r]);
        u16 hi = f2bf(v);
        aHi[m * 72 + col] = hi;
        aLo[m * 72 + col] = f2bf(v - bf(hi));
      }
    }
    __syncthreads();
    // layer 3: base 197, bias rb3, no act -> global
    {
      float bn = rb3[col];
      f32x4 acc = {bn, bn, bn, bn};
#pragma unroll
      for (int kt = 0; kt < 2; kt++) {
        s16x8 ah = *(const s16x8*)(aHi + aoff + kt * 32);
        s16x8 al = *(const s16x8*)(aLo + aoff + kt * 32);
        const u16* wp = whi + ((size_t)(197 + wid * 2 + kt) * 64 + lane) * 8;
        const u16* wq = wlo + ((size_t)(197 + wid * 2 + kt) * 64 + lane) * 8;
        s16x8 wh = *(const s16x8*)wp;
        s16x8 wl = *(const s16x8*)wq;
        acc = __builtin_amdgcn_mfma_f32_16x16x32_bf16(ah, wh, acc, 0, 0, 0);
        acc = __builtin_amdgcn_mfma_f32_16x16x32_bf16(ah, wl, acc, 0, 0, 0);
        acc = __builtin_amdgcn_mfma_f32_16x16x32_bf16(al, wh, acc, 0, 0, 0);
      }
#pragma unroll
      for (int r = 0; r < 4; r++) {
        int gn = g0 + kg * 4 + r;
        if (gn < N) outrec[gn * 64 + col] = acc[r];
      }
    }
    __syncthreads();
  }
}

// ---------------- degree count: 8-way XCD-replicated ----------------
__global__ void k_deg(const int* __restrict__ ei, int* __restrict__ deg8, int E, int N,
                      const int* __restrict__ i32flag) {
  int e = blockIdx.x * 256 + threadIdx.x;
  if (e >= E + N) return;
  int r = blockIdx.x & 7;
  int dst;
  if (e < E) {
    if (*i32flag) dst = ei[E + e];
    else { const ll* el = (const ll*)ei; dst = (int)el[E + e]; }
  } else dst = e - E;
  atomicAdd(&deg8[r * N + dst], 1);
}

// ---------------- coalesced scan: A (block sums), B (scan sums), C (final) --
__global__ void k_scanA(const int* __restrict__ deg8, int* __restrict__ bsum, int N) {
  __shared__ int red[256];
  int tid = threadIdx.x;
  int base = blockIdx.x * 1024;
  int s = 0;
#pragma unroll
  for (int q = 0; q < 4; q++) {
    int n = base + q * 256 + tid;
    if (n < N) {
#pragma unroll
      for (int r = 0; r < 8; r++) s += deg8[r * N + n];
    }
  }
  red[tid] = s; __syncthreads();
  for (int o = 128; o > 0; o >>= 1) {
    if (tid < o) red[tid] += red[tid + o];
    __syncthreads();
  }
  if (tid == 0) bsum[blockIdx.x] = red[0];
}

__global__ void k_scanB(const int* __restrict__ bsum, int* __restrict__ bscan,
                        int* __restrict__ offs, int NB, int N) {
  if (threadIdx.x == 0) {
    int run = 0;
    for (int b = 0; b < NB; b++) { bscan[b] = run; run += bsum[b]; }
    offs[N] = run;
  }
}

__global__ void k_scanC(const int* __restrict__ deg8, const int* __restrict__ bscan,
                        int* __restrict__ offs, int* __restrict__ cursor8, int N) {
  __shared__ int dt[1024];
  __shared__ int tp[256];
  int tid = threadIdx.x;
  int base = blockIdx.x * 1024;
#pragma unroll
  for (int q = 0; q < 4; q++) {
    int n = base + q * 256 + tid;
    int s = 0;
    if (n < N) {
#pragma unroll
      for (int r = 0; r < 8; r++) s += deg8[r * N + n];
    }
    dt[q * 256 + tid] = s;
  }
  __syncthreads();
  int t4 = tid * 4;
  int l0 = dt[t4], l1 = dt[t4 + 1], l2 = dt[t4 + 2], l3 = dt[t4 + 3];
  int tot = l0 + l1 + l2 + l3;
  tp[tid] = tot; __syncthreads();
  for (int o = 1; o < 256; o <<= 1) {
    int v = (tid >= o) ? tp[tid - o] : 0;
    __syncthreads();
    tp[tid] += v;
    __syncthreads();
  }
  int run = bscan[blockIdx.x] + tp[tid] - tot;
#pragma unroll
  for (int k = 0; k < 4; k++) {
    int n = base + t4 + k;
    if (n < N) {
      offs[n] = run;
      int b = run;
#pragma unroll
      for (int r = 0; r < 8; r++) { cursor8[r * N + n] = b; b += deg8[r * N + n]; }
      run = b;
    }
  }
}

// ---------------- scatter: bf16x8 eattr (+packed src) into CSR order --------
template <bool PACKED>
__global__ void k_scatter(const int* __restrict__ ei, const float* __restrict__ eattr,
                          int* __restrict__ cursor8, int* __restrict__ csr_src,
                          uint4* __restrict__ ea2, int E, int N,
                          const int* __restrict__ i32flag) {
  int e = blockIdx.x * 256 + threadIdx.x;
  if (e >= E + N) return;
  int r = blockIdx.x & 7;
  int src, dst;
  u16 p[8];
  if (e < E) {
    if (*i32flag) { src = ei[e]; dst = ei[E + e]; }
    else { const ll* el = (const ll*)ei; src = (int)el[e]; dst = (int)el[E + e]; }
    const float* ea = eattr + (size_t)e * 7;
#pragma unroll
    for (int q = 0; q < 7; q++) p[q] = f2bf(ea[q]);
    p[7] = 0;
  } else {
    src = e - E; dst = src;
#pragma unroll
    for (int q = 0; q < 8; q++) p[q] = 0;
    p[6] = 0x3F80;   // FILL: e_6 = 1.0
  }
  int pos = atomicAdd(&cursor8[r * N + dst], 1);
  uint4 U;
  U.x = ((unsigned)p[1] << 16) | p[0];
  U.y = ((unsigned)p[3] << 16) | p[2];
  U.z = ((unsigned)p[5] << 16) | p[4];
  if (PACKED) {
    U.w = ((unsigned)src << 16) | p[6];
  } else {
    U.w = ((unsigned)p[7] << 16) | p[6];
    csr_src[pos] = src;
  }
  ea2[pos] = U;
}

// ---------------- fused GAT: persistent, wave/node, 16 lanes/edge ----------
template <bool PACKED>
__global__ void k_gat(const int* __restrict__ offs, const int* __restrict__ csr_src,
                      const uint4* __restrict__ ea2,
                      const u16* __restrict__ xlb, const float* __restrict__ xr,
                      const float* __restrict__ Wew, const float* __restrict__ attw,
                      float* __restrict__ gat, double* __restrict__ s3, int N) {
  __shared__ float sb[4][64];
  int tid = threadIdx.x;
  int wid = tid >> 6;          // wave id in block = node slot
  int lane = tid & 63;
  int g = lane >> 4;           // edge slot within 4-edge batch
  int l = lane & 15;           // channel quad index: owns channels 4l..4l+3
  int Nc = (N + 3) >> 2;

  // per-lane constants in registers
  float4 wq[7];
#pragma unroll
  for (int q = 0; q < 7; q++) wq[q] = *(const float4*)(Wew + q * 64 + 4 * l);
  float4 attv = *(const float4*)(attw + 4 * l);

  // running per-channel stats (meaningful on g==0 lanes only)
  float ts0 = 0.f, ts1 = 0.f, ts2 = 0.f, ts3 = 0.f;
  float tq0 = 0.f, tq1 = 0.f, tq2 = 0.f, tq3 = 0.f;

  for (int chunk = blockIdx.x; chunk < Nc; chunk += gridDim.x) {
    int node = chunk * 4 + wid;
    if (node >= N) continue;
    float4 xrv = *(const float4*)(xr + node * 64 + 4 * l);
    int st = offs[node];
    int dg = offs[node + 1] - st;
    int nb = (dg + 3) >> 2;
    float sden = 0.f;
    float a0 = 0.f, a1 = 0.f, a2 = 0.f, a3 = 0.f;

    // ---- pipeline prologue: batches 0 and 1 loads, batch 0 gather ----
    int i0 = st + g;
    uint4 UC = ea2[i0];              // batch 0 record
    uint4 UN = ea2[i0 + 4];          // batch 1 record (pad-safe)
    int scC, scN;
    if (PACKED) {
      scC = (int)(UC.w >> 16);
      scN = (int)(UN.w >> 16);
    } else {
      scC = csr_src[i0];
      scN = csr_src[i0 + 4];
    }
    scC = ((unsigned)scC < (unsigned)N) ? scC : 0;
    uint2 xwC = *(const uint2*)(xlb + scC * 64 + 4 * l);   // batch 0 gather

    for (int b = 0; b < nb; b++) {
      // stage A: issue record load for batch b+2 (max idx st+dg+10 < pad 16)
      int iA = st + (b + 2) * 4 + g;
      uint4 UA = ea2[iA];
      int scA = PACKED ? 0 : csr_src[iA];
      // stage B: issue gather for batch b+1 (UN/scN landed one iteration ago)
      int scg = PACKED ? (int)(UN.w >> 16) : scN;
      scg = ((unsigned)scg < (unsigned)N) ? scg : 0;
      uint2 xwN = *(const uint2*)(xlb + scg * 64 + 4 * l);
      // stage C: compute batch b from xwC/UC (issued >=1 iteration ago)
      bool valid = (b * 4 + g) < dg;
      float x0 = bflo(xwC.x), x1 = bfhi(xwC.x), x2 = bflo(xwC.y), x3 = bfhi(xwC.y);
      float e0 = bflo(UC.x), e1 = bfhi(UC.x), e2 = bflo(UC.y), e3 = bfhi(UC.y);
      float e4 = bflo(UC.z), e5 = bfhi(UC.z), e6 = bflo(UC.w);
      float m0 = x0 + xrv.x + e0*wq[0].x + e1*wq[1].x + e2*wq[2].x + e3*wq[3].x + e4*wq[4].x + e5*wq[5].x + e6*wq[6].x;
      float m1 = x1 + xrv.y + e0*wq[0].y + e1*wq[1].y + e2*wq[2].y + e3*wq[3].y + e4*wq[4].y + e5*wq[5].y + e6*wq[6].y;
      float m2 = x2 + xrv.z + e0*wq[0].z + e1*wq[1].z + e2*wq[2].z + e3*wq[3].z + e4*wq[4].z + e5*wq[5].z + e6*wq[6].z;
      float m3 = x3 + xrv.w + e0*wq[0].w + e1*wq[1].w + e2*wq[2].w + e3*wq[3].w + e4*wq[4].w + e5*wq[5].w + e6*wq[6].w;
      m0 = m0 > 0.f ? m0 : 0.2f * m0;
      m1 = m1 > 0.f ? m1 : 0.2f * m1;
      m2 = m2 > 0.f ? m2 : 0.2f * m2;
      m3 = m3 > 0.f ? m3 : 0.2f * m3;
      float pp = m0 * attv.x + m1 * attv.y + m2 * attv.z + m3 * attv.w;
      pp += __shfl_xor(pp, 1, 64);     // quad reduce: 4 lanes = 16 channels = head
      pp += __shfl_xor(pp, 2, 64);
      float ex = valid ? __expf(pp) : 0.f;
      sden += ex;
      a0 += ex * x0; a1 += ex * x1; a2 += ex * x2; a3 += ex * x3;
      // rotate pipeline registers
      xwC = xwN; UC = UN; UN = UA; scN = scA;
    }
    // sum over the 4 edge-groups
    a0 += __shfl_xor(a0, 16, 64); a0 += __shfl_xor(a0, 32, 64);
    a1 += __shfl_xor(a1, 16, 64); a1 += __shfl_xor(a1, 32, 64);
    a2 += __shfl_xor(a2, 16, 64); a2 += __shfl_xor(a2, 32, 64);
    a3 += __shfl_xor(a3, 16, 64); a3 += __shfl_xor(a3, 32, 64);
    sden += __shfl_xor(sden, 16, 64); sden += __shfl_xor(sden, 32, 64);
    float inv = 1.f / (sden * (float)dg);
    float val0 = a0 * inv, val1 = a1 * inv, val2 = a2 * inv, val3 = a3 * inv;
    if (g == 0) {
      float4 o = make_float4(val0, val1, val2, val3);
      *(float4*)(gat + node * 64 + 4 * l) = o;
      ts0 += val0; ts1 += val1; ts2 += val2; ts3 += val3;
      tq0 += val0 * val0; tq1 += val1 * val1; tq2 += val2 * val2; tq3 += val3 * val3;
    }
  }

  // ---- block-exit stats reduction: transpose to per-channel, 128 atomics ----
  if (g == 0) {
    sb[wid][4 * l + 0] = ts0; sb[wid][4 * l + 1] = ts1;
    sb[wid][4 * l + 2] = ts2; sb[wid][4 * l + 3] = ts3;
  }
  __syncthreads();
  if (tid < 64) {
    float v = sb[0][tid] + sb[1][tid] + sb[2][tid] + sb[3][tid];
    atomicAdd(&s3[tid], (double)v);
  }
  __syncthreads();
  if (g == 0) {
    sb[wid][4 * l + 0] = tq0; sb[wid][4 * l + 1] = tq1;
    sb[wid][4 * l + 2] = tq2; sb[wid][4 * l + 3] = tq3;
  }
  __syncthreads();
  if (tid < 64) {
    float v = sb[0][tid] + sb[1][tid] + sb[2][tid] + sb[3][tid];
    atomicAdd(&s3[64 + tid], (double)v);
  }
}

// ---------------- atomic fallback (if CSR doesn't fit) ----------------
__global__ void k_edge2(const int* __restrict__ ei, const float* __restrict__ eattr,
                        const u16* __restrict__ xlb, const float* __restrict__ xr,
                        const float* __restrict__ Wew, const float* __restrict__ attw,
                        float* __restrict__ agg, float* __restrict__ denom,
                        int* __restrict__ deg, int E, int N,
                        const int* __restrict__ i32flag) {
  __shared__ float sWe[448];
  __shared__ float satt[64];
  int tid = threadIdx.x;
  for (int k = tid; k < 448; k += 256) sWe[k] = Wew[k];
  if (tid < 64) satt[tid] = attw[tid];
  __syncthreads();
  int e = blockIdx.x * 4 + (tid >> 6);
  if (e >= E + N) return;
  int lane = tid & 63;
  int src, dst;
  if (e < E) {
    if (*i32flag) { src = ei[e]; dst = ei[E + e]; }
    else { const ll* el = (const ll*)ei; src = (int)el[e]; dst = (int)el[E + e]; }
  } else { src = e - E; dst = src; }
  float xlv = bf(xlb[src * 64 + lane]);
  float m = xlv + xr[dst * 64 + lane];
  if (e < E) {
#pragma unroll
    for (int k = 0; k < 7; k++) m += eattr[e * 7 + k] * sWe[k * 64 + lane];
  } else {
    m += sWe[6 * 64 + lane];
  }
  float lr = m > 0.f ? m : 0.2f * m;
  float p = lr * satt[lane];
  p += __shfl_xor(p, 1, 64);
  p += __shfl_xor(p, 2, 64);
  p += __shfl_xor(p, 4, 64);
  p += __shfl_xor(p, 8, 64);
  float ex = __expf(p);
  atomicAdd(&agg[dst * 64 + lane], ex * xlv);
  if ((lane & 15) == 0) atomicAdd(&denom[dst * 4 + (lane >> 4)], ex);
  if (lane == 0) atomicAdd(&deg[dst], 1);
}

__global__ void k_gatnorm(float* __restrict__ agg, const float* __restrict__ denom,
                          const int* __restrict__ deg, double* __restrict__ s3, int N) {
  __shared__ float red[256];
  int tid = threadIdx.x;
  int idx = blockIdx.x * 256 + tid;
  float v = 0.f;
  if (idx < N * 64) {
    int n = idx >> 6, c = idx & 63, h = c >> 4;
    v = agg[idx] / (denom[n * 4 + h] * (float)deg[n]);
    agg[idx] = v;
  }
  red[tid] = v; __syncthreads();
  if (tid < 64) atomicAdd(&s3[tid], (double)(red[tid] + red[tid + 64] + red[tid + 128] + red[tid + 192]));
  __syncthreads();
  red[tid] = v * v; __syncthreads();
  if (tid < 64) atomicAdd(&s3[64 + tid], (double)(red[tid] + red[tid + 64] + red[tid + 128] + red[tid + 192]));
}

// ---------------- h4 = elu(h3 + inorm(gat)) ----------------
__global__ void k_h4(const float* __restrict__ jk, const float* __restrict__ gat,
                     const float* __restrict__ gn_w, const float* __restrict__ gn_b,
                     const double* __restrict__ s3, float* __restrict__ h4, int N) {
  __shared__ float na[64], nb[64];
  int tid = threadIdx.x;
  if (tid < 64) norm_coeffs(s3, tid, N, gn_w, gn_b, na, nb);
  __syncthreads();
  int idx = blockIdx.x * 256 + tid;
  if (idx >= N * 64) return;
  int c = idx & 63;
  h4[idx] = elu_f(jk[idx] + gat[idx] * na[c] + nb[c]);
}

// ---------------- decoder: MFMA split-bf16 layer -----------------------------
template <int LIN, int LOUT, int TBASE>
__device__ __forceinline__ void mfmaLayer(const u16* __restrict__ whi, const u16* __restrict__ wlo,
                                          const float* __restrict__ bias,
                                          const u16* __restrict__ Ahi, const u16* __restrict__ Alo,
                                          u16* __restrict__ Ohi, u16* __restrict__ Olo,
                                          int wid, int lane) {
  constexpr int KT = LIN / 32, NT = LOUT / 16;
  constexpr int SIN = LIN + 8, SOUT = LOUT + 8;
  int l15 = lane & 15, kg = lane >> 4;
  int aoff = l15 * SIN + kg * 8;
  for (int nt = wid; nt < NT; nt += 4) {
    float bn = bias[nt * 16 + l15];
    f32x4 acc = {bn, bn, bn, bn};
    for (int kt = 0; kt < KT; kt++) {
      s16x8 ah = *(const s16x8*)(Ahi + aoff + kt * 32);
      s16x8 al = *(const s16x8*)(Alo + aoff + kt * 32);
      const u16* wp = whi + ((size_t)(TBASE + nt * KT + kt) * 64 + lane) * 8;
      const u16* wq = wlo + ((size_t)(TBASE + nt * KT + kt) * 64 + lane) * 8;
      s16x8 wh = *(const s16x8*)(wp);
      s16x8 wl = *(const s16x8*)(wq);
      acc = __builtin_amdgcn_mfma_f32_16x16x32_bf16(ah, wh, acc, 0, 0, 0);
      acc = __builtin_amdgcn_mfma_f32_16x16x32_bf16(ah, wl, acc, 0, 0, 0);
      acc = __builtin_amdgcn_mfma_f32_16x16x32_bf16(al, wh, acc, 0, 0, 0);
    }
#pragma unroll
    for (int r = 0; r < 4; r++) {
      int m = kg * 4 + r;
      float v = elu_f(acc[r]);
      u16 hi = f2bf(v);
      u16 lo = f2bf(v - bf(hi));
      Ohi[m * SOUT + nt * 16 + l15] = hi;
      Olo[m * SOUT + nt * 16 + l15] = lo;
    }
  }
}

__global__ void k_dec(const float* __restrict__ jk, const float* __restrict__ h4,
                      const u16* __restrict__ whi, const u16* __restrict__ wlo,
                      const float* __restrict__ db1, const float* __restrict__ db2,
                      const float* __restrict__ db3, const float* __restrict__ db4,
                      const float* __restrict__ db5,
                      const float* __restrict__ dW6, const float* __restrict__ db6,
                      float* __restrict__ outdec, int N) {
  // ping-pong act buffers, bf16 hi/lo, [16 nodes][stride] (stride = LIN+8)
  __shared__ __align__(16) u16 bHi0[16 * 264], bLo0[16 * 264];
  __shared__ __align__(16) u16 bHi1[16 * 264], bLo1[16 * 264];
  int tid = threadIdx.x;
  int wid = tid >> 6, lane = tid & 63;
  int g0 = blockIdx.x * 16;
  // stage input: [node][136] = 128 ch of (jk | h4), bf16 hi/lo
  for (int k = tid; k < 16 * 128; k += 256) {
    int i = k & 127, node = k >> 7;
    int gn = g0 + node;
    float v = 0.f;
    if (gn < N) v = (i < 64) ? jk[gn * 64 + i] : h4[gn * 64 + (i - 64)];
    u16 hi = f2bf(v);
    u16 lo = f2bf(v - bf(hi));
    bHi0[node * 136 + i] = hi;
    bLo0[node * 136 + i] = lo;
  }
  __syncthreads();
  mfmaLayer<128, 256, 0>(whi, wlo, db1, bHi0, bLo0, bHi1, bLo1, wid, lane); __syncthreads();
  mfmaLayer<256, 128, 64>(whi, wlo, db2, bHi1, bLo1, bHi0, bLo0, wid, lane); __syncthreads();
  mfmaLayer<128, 64, 128>(whi, wlo, db3, bHi0, bLo0, bHi1, bLo1, wid, lane); __syncthreads();
  mfmaLayer<64, 32, 144>(whi, wlo, db4, bHi1, bLo1, bHi0, bLo0, wid, lane); __syncthreads();
  mfmaLayer<32, 16, 148>(whi, wlo, db5, bHi0, bLo0, bHi1, bLo1, wid, lane); __syncthreads();
  // final 16 -> 2 (fp32 scalar; act rows stride 24)
  if (tid < 32) {
    int node = tid >> 1, j = tid & 1;
    int gn = g0 + node;
    if (gn < N) {
      float s = db6[j];
#pragma unroll
      for (int i = 0; i < 16; i++) {
        float a = bf(bHi1[node * 24 + i]) + bf(bLo1[node * 24 + i]);
        s += a * dW6[i * 2 + j];
      }
      outdec[gn * 2 + j] = s;
    }
  }
}

// ---------------- sentinel ----------------
__global__ void k_sentinel(float* __restrict__ out, float v) {
  if (threadIdx.x == 0) out[0] = v;
}

extern "C" void kernel_launch(void* const* d_in, const int* in_sizes, int n_in,
                              void* d_out, int out_size, void* d_ws, size_t ws_size,
                              hipStream_t stream) {
  (void)n_in; (void)out_size;
  const float* x     = (const float*)d_in[0];
  const int*   ei    = (const int*)d_in[1];
  const float* ea    = (const float*)d_in[2];
  const float* pre_w = (const float*)d_in[3];
  const float* pre_b = (const float*)d_in[4];
  const float* eW1   = (const float*)d_in[5];
  const float* en1w  = (const float*)d_in[6];
  const float* en1b  = (const float*)d_in[7];
  const float* eW2   = (const float*)d_in[8];
  const float* en2w  = (const float*)d_in[9];
  const float* en2b  = (const float*)d_in[10];
  const float* Wl    = (const float*)d_in[11];
  const float* Wr    = (const float*)d_in[12];
  const float* Wew   = (const float*)d_in[13];
  const float* attw  = (const float*)d_in[14];
  const float* gn_w  = (const float*)d_in[15];
  const float* gn_b  = (const float*)d_in[16];
  const float* dW1 = (const float*)d_in[17]; const float* db1 = (const float*)d_in[18];
  const float* dW2 = (const float*)d_in[19]; const float* db2 = (const float*)d_in[20];
  const float* dW3 = (const float*)d_in[21]; const float* db3 = (const float*)d_in[22];
  const float* dW4 = (const float*)d_in[23]; const float* db4 = (const float*)d_in[24];
  const float* dW5 = (const float*)d_in[25]; const float* db5 = (const float*)d_in[26];
  const float* dW6 = (const float*)d_in[27]; const float* db6 = (const float*)d_in[28];
  const float* rW1 = (const float*)d_in[29]; const float* rb1 = (const float*)d_in[30];
  const float* rW2 = (const float*)d_in[31]; const float* rb2 = (const float*)d_in[32];
  const float* rW3 = (const float*)d_in[33]; const float* rb3 = (const float*)d_in[34];

  int D  = in_sizes[3];
  int N  = in_sizes[0] / (D > 0 ? D : 1);
  int E  = in_sizes[1] / 2;
  int ED = E > 0 ? in_sizes[2] / E : 0;
  float* outdec = (float*)d_out;
  float* outrec = outdec + (size_t)N * 2;
  if (D != 64 || ED != 7 || in_sizes[14] != 64) {
    k_sentinel<<<1, 64, 0, stream>>>(outdec, 2000.f);
    return;
  }
  int Etot = E + N;

  char* w = (char*)d_ws;
  size_t off = 0;
  auto alloc = [&](size_t bytes) -> void* {
    void* p = w + off;
    off += (bytes + 255) & ~(size_t)255;
    return p;
  };
  const size_t FEATF = (size_t)N * 64 * 4;
  float* B1    = (float*)alloc(FEATF);             // t1 -> gat (or agg fallback)
  size_t ea2_bytes = ((size_t)Etot + 16) * 16;     // +16 pad: pipeline prefetch depth
  size_t b2ext = ea2_bytes > FEATF ? ea2_bytes : FEATF;
  float* B2    = (float*)alloc(b2ext);
  float* jk    = (float*)alloc(FEATF);
  u16*   xlb   = (u16*)  alloc((size_t)N * 64 * 2);
  float* xr    = (float*)alloc(FEATF);
  int*   offs  = (int*)  alloc(((size_t)N + 1) * 4);
  int*   deg8  = (int*)  alloc((size_t)N * 8 * 4);
  int*   cursor8=(int*)  alloc((size_t)N * 8 * 4);
  int*   bsum  = (int*)  alloc(4096);
  int*   bscan = (int*)  alloc(4096);
  double* stats = (double*)alloc(4 * 128 * 8);
  int* i32flag = (int*)alloc(256);
  float* denom = (float*)alloc((size_t)N * 4 * 4);  // fallback only
  u16* whi = (u16*)alloc((size_t)205 * 512 * 2);    // fragment-ordered bf16 hi
  u16* wlo = (u16*)alloc((size_t)205 * 512 * 2);    // fragment-ordered bf16 lo
  size_t base_off = off;
  int* csr_src = (int*)alloc(((size_t)Etot + 16) * 4);  // +16 pad (unpacked path)
  size_t csr_off = off;

  double* s0 = stats, *s1 = stats + 128, *s2 = stats + 256, *s3 = stats + 384;
  float* t1 = B1; float* gat = B1; float* agg = B1;
  float* t2 = B2; float* h4 = B2;
  uint4* ea2 = (uint4*)B2;   // aliases t2 (dead after k_enc3M)

  bool packed = (N <= 65536);
  bool use_csr = packed ? (base_off <= ws_size) : (csr_off <= ws_size);
  if (!use_csr && base_off > ws_size) {
    k_sentinel<<<1, 64, 0, stream>>>(outdec, 1000.f);
    return;
  }

  hipMemsetAsync(stats, 0, 4 * 128 * 8, stream);
  hipMemsetAsync(i32flag, 0, 256, stream);
  hipMemsetAsync(deg8, 0, (size_t)N * 8 * 4, stream);

  int gN64 = (N * 64 + 255) / 256;
  int gE = (Etot + 255) / 256;
  int probeCnt = E < 1024 ? E : 1024;
  int NB = (N + 1023) / 1024;
  int Nc16 = (N + 15) / 16;
  int gEnc = Nc16 < 2048 ? Nc16 : 2048;

  k_probe64<<<1, 256, 0, stream>>>(ei, probeCnt, i32flag);
  k_wprep<<<205, 256, 0, stream>>>(dW1, dW2, dW3, dW4, dW5, eW1, eW2, Wl, Wr,
                                   rW1, rW2, rW3, whi, wlo);
  k_stats_x<<<1024, 256, 0, stream>>>(x, N, s0);
  k_encM<false><<<gEnc, 256, 0, stream>>>(x, pre_w, pre_b, whi, wlo, 149, s0, t1, s1, N);
  k_encM<true><<<gEnc, 256, 0, stream>>>(t1, en1w, en1b, whi, wlo, 157, s1, t2, s2, N);
  k_enc3M<<<gEnc, 256, 0, stream>>>(t2, en2w, en2b, whi, wlo, s2, jk, xlb, xr, N);

  if (use_csr) {
    k_deg<<<gE, 256, 0, stream>>>(ei, deg8, E, N, i32flag);
    k_scanA<<<NB, 256, 0, stream>>>(deg8, bsum, N);
    k_scanB<<<1, 64, 0, stream>>>(bsum, bscan, offs, NB, N);
    k_scanC<<<NB, 256, 0, stream>>>(deg8, bscan, offs, cursor8, N);
    int ggat = 2048;
    int NcG = (N + 3) / 4;
    if (ggat > NcG) ggat = NcG;
    if (packed) {
      k_scatter<true><<<gE, 256, 0, stream>>>(ei, ea, cursor8, csr_src, ea2, E, N, i32flag);
      k_gat<true><<<ggat, 256, 0, stream>>>(offs, csr_src, ea2, xlb, xr, Wew, attw,
                                            gat, s3, N);
    } else {
      k_scatter<false><<<gE, 256, 0, stream>>>(ei, ea, cursor8, csr_src, ea2, E, N, i32flag);
      k_gat<false><<<ggat, 256, 0, stream>>>(offs, csr_src, ea2, xlb, xr, Wew, attw,
                                             gat, s3, N);
    }
  } else {
    hipMemsetAsync(agg, 0, FEATF, stream);
    hipMemsetAsync(denom, 0, (size_t)N * 4 * 4, stream);
    k_edge2<<<(Etot + 3) / 4, 256, 0, stream>>>(ei, ea, xlb, xr, Wew, attw, agg, denom,
                                                deg8, E, N, i32flag);
    k_gatnorm<<<gN64, 256, 0, stream>>>(agg, denom, deg8, s3, N);
  }

  k_h4<<<gN64, 256, 0, stream>>>(jk, gat, gn_w, gn_b, s3, h4, N);
  k_dec<<<Nc16, 256, 0, stream>>>(jk, h4, whi, wlo, db1, db2, db3, db4, db5,
                                  dW6, db6, outdec, N);
  k_reconM<<<gEnc, 256, 0, stream>>>(h4, rW1 != 0 ? whi : whi, wlo, rb1, rb2, rb3, outrec, N);
}

// Round 13
// 622.104 us; speedup vs baseline: 1.3622x; 1.0050x over previous
//
#include <hip/hip_runtime.h>
#include <math.h>

// GAT model, MI355X. Round 26: k_gat pipeline deepened — 3 record loads in
// flight (b+1..b+3), 2 xlb gathers in flight (b+1,b+2). Gather issued 2
// iterations before use (~2x cover for the 200-500cy L2/L3 random-row read
// that was half of k_gat's 103us; VALUBusy 51%). +~10 VGPR (<=64 keeps 8
// waves/SIMD). Prefetch max st+dg+14 < +16 pad (ok at nb=1). Everything
// else identical to the 625us R25 build (MFMA enc/dec/recon, packed scatter).

typedef long long ll;
typedef unsigned short u16;
typedef float f32x4 __attribute__((ext_vector_type(4)));
typedef short s16x8 __attribute__((ext_vector_type(8)));

__device__ __forceinline__ float bf(u16 u) { return __uint_as_float(((unsigned)u) << 16); }
__device__ __forceinline__ u16 f2bf(float f) {
  unsigned u = __float_as_uint(f);
  u += 0x7fffu + ((u >> 16) & 1u);   // RNE
  return (u16)(u >> 16);
}
__device__ __forceinline__ float bflo(unsigned u) { return __uint_as_float(u << 16); }
__device__ __forceinline__ float bfhi(unsigned u) { return __uint_as_float(u & 0xffff0000u); }
__device__ __forceinline__ float elu_f(float x) { return x > 0.f ? x : (__expf(x) - 1.f); }

// ---------------- probe: is edge_index int32 (flag=1) or int64 (flag=0)?
__global__ void k_probe64(const int* __restrict__ ei, int cnt, int* __restrict__ flag) {
  int tid = threadIdx.x;
  int nz = 0;
  for (int k = tid; k < cnt; k += 256) {
    if (ei[2 * k + 1] != 0) nz = 1;
  }
  if (nz) atomicOr(flag, 1);
}

// ---------------- stats of x ----------------
__global__ void k_stats_x(const float* __restrict__ x, int N, double* __restrict__ s0) {
  __shared__ float red[256];
  int tid = threadIdx.x;
  int c = tid & 63;
  float s = 0.f, ss = 0.f;
  for (int r = blockIdx.x * 4 + (tid >> 6); r < N; r += gridDim.x * 4) {
    float v = x[r * 64 + c];
    s += v; ss += v * v;
  }
  red[tid] = s; __syncthreads();
  if (tid < 64) atomicAdd(&s0[tid], (double)(red[tid] + red[tid + 64] + red[tid + 128] + red[tid + 192]));
  __syncthreads();
  red[tid] = ss; __syncthreads();
  if (tid < 64) atomicAdd(&s0[64 + tid], (double)(red[tid] + red[tid + 64] + red[tid + 128] + red[tid + 192]));
}

__device__ __forceinline__ void norm_coeffs(const double* s, int tid, int N,
                                            const float* w, const float* b,
                                            float* na, float* nb) {
  double invN = 1.0 / (double)N;
  double mean = s[tid] * invN;
  double var = s[64 + tid] * invN - mean * mean;
  float a = rsqrtf((float)var + 1e-5f) * w[tid];
  na[tid] = a; nb[tid] = b[tid] - (float)mean * a;
}

// ---------------- weight prep: fragment-ordered bf16 hi/lo ------------------
// Tile t covers B[k][n]: k = kt*32 + (lane>>4)*8 + i, n = nt*16 + (lane&15).
// Bases: dW1=0(64) dW2=64(64) dW3=128(16) dW4=144(4) dW5=148(1)
//        eW1=149(8) eW2=157(8) Wl=165(8) Wr=173(8) rW1=181(8) rW2=189(8)
//        rW3=197(8). Total 205 tiles.
__global__ void k_wprep(const float* __restrict__ dW1, const float* __restrict__ dW2,
                        const float* __restrict__ dW3, const float* __restrict__ dW4,
                        const float* __restrict__ dW5,
                        const float* __restrict__ eW1, const float* __restrict__ eW2,
                        const float* __restrict__ Wl, const float* __restrict__ Wr,
                        const float* __restrict__ rW1, const float* __restrict__ rW2,
                        const float* __restrict__ rW3,
                        u16* __restrict__ whi, u16* __restrict__ wlo) {
  int t = blockIdx.x;
  int tid = threadIdx.x;
  const float* W; int LIN, LOUT, base;
  if (t < 64)       { W = dW1; LIN = 128; LOUT = 256; base = 0; }
  else if (t < 128) { W = dW2; LIN = 256; LOUT = 128; base = 64; }
  else if (t < 144) { W = dW3; LIN = 128; LOUT = 64;  base = 128; }
  else if (t < 148) { W = dW4; LIN = 64;  LOUT = 32;  base = 144; }
  else if (t < 149) { W = dW5; LIN = 32;  LOUT = 16;  base = 148; }
  else if (t < 157) { W = eW1; LIN = 64;  LOUT = 64;  base = 149; }
  else if (t < 165) { W = eW2; LIN = 64;  LOUT = 64;  base = 157; }
  else if (t < 173) { W = Wl;  LIN = 64;  LOUT = 64;  base = 165; }
  else if (t < 181) { W = Wr;  LIN = 64;  LOUT = 64;  base = 173; }
  else if (t < 189) { W = rW1; LIN = 64;  LOUT = 64;  base = 181; }
  else if (t < 197) { W = rW2; LIN = 64;  LOUT = 64;  base = 189; }
  else              { W = rW3; LIN = 64;  LOUT = 64;  base = 197; }
  int KT = LIN >> 5;
  int tl = t - base;
  int nt = tl / KT, kt = tl % KT;
#pragma unroll
  for (int half = 0; half < 2; half++) {
    int lane = (tid >> 3) + half * 32;
    int i = tid & 7;
    int kg = kt * 32 + (lane >> 4) * 8 + i;
    int ng = nt * 16 + (lane & 15);
    float v = W[kg * LOUT + ng];
    u16 hi = f2bf(v);
    u16 lo = f2bf(v - bf(hi));
    whi[((size_t)t * 64 + lane) * 8 + i] = hi;
    wlo[((size_t)t * 64 + lane) * 8 + i] = lo;
  }
}

// ---------------- MFMA encoder layer: out = f(in*na+nb) @ W, + stats --------
template <bool INELU>
__global__ void k_encM(const float* __restrict__ in, const float* __restrict__ w,
                       const float* __restrict__ b, const u16* __restrict__ whi,
                       const u16* __restrict__ wlo, int TB,
                       const double* __restrict__ sin_, float* __restrict__ out,
                       double* __restrict__ sout, int N) {
  __shared__ __align__(16) u16 aHi[16 * 72], aLo[16 * 72];
  __shared__ float na[64], nb[64];
  __shared__ float sred[64];
  int tid = threadIdx.x;
  if (tid < 64) norm_coeffs(sin_, tid, N, w, b, na, nb);
  __syncthreads();
  int lane = tid & 63, wid = tid >> 6;
  int l15 = lane & 15, kg = lane >> 4;
  int Nc = (N + 15) >> 4;
  float ts = 0.f, tq = 0.f;
  for (int chunk = blockIdx.x; chunk < Nc; chunk += gridDim.x) {
    int g0 = chunk * 16;
    for (int k = tid; k < 1024; k += 256) {
      int i = k & 63, node = k >> 6;
      int gn = g0 + node;
      float v = 0.f;
      if (gn < N) {
        v = in[gn * 64 + i] * na[i] + nb[i];
        if (INELU) v = elu_f(v);
      }
      u16 hi = f2bf(v);
      aHi[node * 72 + i] = hi;
      aLo[node * 72 + i] = f2bf(v - bf(hi));
    }
    __syncthreads();
    f32x4 acc = {0.f, 0.f, 0.f, 0.f};
    int aoff = l15 * 72 + kg * 8;
#pragma unroll
    for (int kt = 0; kt < 2; kt++) {
      s16x8 ah = *(const s16x8*)(aHi + aoff + kt * 32);
      s16x8 al = *(const s16x8*)(aLo + aoff + kt * 32);
      const u16* wp = whi + ((size_t)(TB + wid * 2 + kt) * 64 + lane) * 8;
      const u16* wq = wlo + ((size_t)(TB + wid * 2 + kt) * 64 + lane) * 8;
      s16x8 wh = *(const s16x8*)wp;
      s16x8 wl = *(const s16x8*)wq;
      acc = __builtin_amdgcn_mfma_f32_16x16x32_bf16(ah, wh, acc, 0, 0, 0);
      acc = __builtin_amdgcn_mfma_f32_16x16x32_bf16(ah, wl, acc, 0, 0, 0);
      acc = __builtin_amdgcn_mfma_f32_16x16x32_bf16(al, wh, acc, 0, 0, 0);
    }
    int col = wid * 16 + l15;
#pragma unroll
    for (int r = 0; r < 4; r++) {
      int m = kg * 4 + r;
      int gn = g0 + m;
      if (gn < N) {
        float v = acc[r];
        out[gn * 64 + col] = v;
        ts += v; tq += v * v;
      }
    }
    __syncthreads();
  }
  ts += __shfl_xor(ts, 16, 64); ts += __shfl_xor(ts, 32, 64);
  tq += __shfl_xor(tq, 16, 64); tq += __shfl_xor(tq, 32, 64);
  if (kg == 0) sred[wid * 16 + l15] = ts;
  __syncthreads();
  if (tid < 64) atomicAdd(&sout[tid], (double)sred[tid]);
  __syncthreads();
  if (kg == 0) sred[wid * 16 + l15] = tq;
  __syncthreads();
  if (tid < 64) atomicAdd(&sout[64 + tid], (double)sred[tid]);
}

// ---------------- MFMA encoder layer 3: jk + xl(bf16) + xr ------------------
__global__ void k_enc3M(const float* __restrict__ t2, const float* __restrict__ w,
                        const float* __restrict__ b, const u16* __restrict__ whi,
                        const u16* __restrict__ wlo, const double* __restrict__ s2,
                        float* __restrict__ jk, u16* __restrict__ xlb,
                        float* __restrict__ xr, int N) {
  __shared__ __align__(16) u16 aHi[16 * 72], aLo[16 * 72];
  __shared__ float na[64], nb[64];
  int tid = threadIdx.x;
  if (tid < 64) norm_coeffs(s2, tid, N, w, b, na, nb);
  __syncthreads();
  int lane = tid & 63, wid = tid >> 6;
  int l15 = lane & 15, kg = lane >> 4;
  int Nc = (N + 15) >> 4;
  for (int chunk = blockIdx.x; chunk < Nc; chunk += gridDim.x) {
    int g0 = chunk * 16;
    for (int k = tid; k < 1024; k += 256) {
      int i = k & 63, node = k >> 6;
      int gn = g0 + node;
      float v = 0.f;
      if (gn < N) {
        v = elu_f(t2[gn * 64 + i] * na[i] + nb[i]);
        jk[gn * 64 + i] = v;
      }
      u16 hi = f2bf(v);
      aHi[node * 72 + i] = hi;
      aLo[node * 72 + i] = f2bf(v - bf(hi));
    }
    __syncthreads();
    int aoff = l15 * 72 + kg * 8;
    int col = wid * 16 + l15;
    // GEMM 1: Wl (base 165) -> xlb bf16
    {
      f32x4 acc = {0.f, 0.f, 0.f, 0.f};
#pragma unroll
      for (int kt = 0; kt < 2; kt++) {
        s16x8 ah = *(const s16x8*)(aHi + aoff + kt * 32);
        s16x8 al = *(const s16x8*)(aLo + aoff + kt * 32);
        const u16* wp = whi + ((size_t)(165 + wid * 2 + kt) * 64 + lane) * 8;
        const u16* wq = wlo + ((size_t)(165 + wid * 2 + kt) * 64 + lane) * 8;
        s16x8 wh = *(const s16x8*)wp;
        s16x8 wl = *(const s16x8*)wq;
        acc = __builtin_amdgcn_mfma_f32_16x16x32_bf16(ah, wh, acc, 0, 0, 0);
        acc = __builtin_amdgcn_mfma_f32_16x16x32_bf16(ah, wl, acc, 0, 0, 0);
        acc = __builtin_amdgcn_mfma_f32_16x16x32_bf16(al, wh, acc, 0, 0, 0);
      }
#pragma unroll
      for (int r = 0; r < 4; r++) {
        int gn = g0 + kg * 4 + r;
        if (gn < N) xlb[gn * 64 + col] = f2bf(acc[r]);
      }
    }
    // GEMM 2: Wr (base 173) -> xr fp32
    {
      f32x4 acc = {0.f, 0.f, 0.f, 0.f};
#pragma unroll
      for (int kt = 0; kt < 2; kt++) {
        s16x8 ah = *(const s16x8*)(aHi + aoff + kt * 32);
        s16x8 al = *(const s16x8*)(aLo + aoff + kt * 32);
        const u16* wp = whi + ((size_t)(173 + wid * 2 + kt) * 64 + lane) * 8;
        const u16* wq = wlo + ((size_t)(173 + wid * 2 + kt) * 64 + lane) * 8;
        s16x8 wh = *(const s16x8*)wp;
        s16x8 wl = *(const s16x8*)wq;
        acc = __builtin_amdgcn_mfma_f32_16x16x32_bf16(ah, wh, acc, 0, 0, 0);
        acc = __builtin_amdgcn_mfma_f32_16x16x32_bf16(ah, wl, acc, 0, 0, 0);
        acc = __builtin_amdgcn_mfma_f32_16x16x32_bf16(al, wh, acc, 0, 0, 0);
      }
#pragma unroll
      for (int r = 0; r < 4; r++) {
        int gn = g0 + kg * 4 + r;
        if (gn < N) xr[gn * 64 + col] = acc[r];
      }
    }
    __syncthreads();
  }
}

// ---------------- MFMA recon MLP: 3x (64->64), elu on 1-2 -------------------
__global__ void k_reconM(const float* __restrict__ h4, const u16* __restrict__ whi,
                         const u16* __restrict__ wlo,
                         const float* __restrict__ rb1, const float* __restrict__ rb2,
                         const float* __restrict__ rb3,
                         float* __restrict__ outrec, int N) {
  __shared__ __align__(16) u16 aHi[16 * 72], aLo[16 * 72];
  __shared__ __align__(16) u16 bHi[16 * 72], bLo[16 * 72];
  int tid = threadIdx.x;
  int lane = tid & 63, wid = tid >> 6;
  int l15 = lane & 15, kg = lane >> 4;
  int aoff = l15 * 72 + kg * 8;
  int col = wid * 16 + l15;
  int Nc = (N + 15) >> 4;
  for (int chunk = blockIdx.x; chunk < Nc; chunk += gridDim.x) {
    int g0 = chunk * 16;
    for (int k = tid; k < 1024; k += 256) {
      int i = k & 63, node = k >> 6;
      int gn = g0 + node;
      float v = (gn < N) ? h4[gn * 64 + i] : 0.f;
      u16 hi = f2bf(v);
      aHi[node * 72 + i] = hi;
      aLo[node * 72 + i] = f2bf(v - bf(hi));
    }
    __syncthreads();
    // layer 1: base 181, bias rb1, elu -> b
    {
      float bn = rb1[col];
      f32x4 acc = {bn, bn, bn, bn};
#pragma unroll
      for (int kt = 0; kt < 2; kt++) {
        s16x8 ah = *(const s16x8*)(aHi + aoff + kt * 32);
        s16x8 al = *(const s16x8*)(aLo + aoff + kt * 32);
        const u16* wp = whi + ((size_t)(181 + wid * 2 + kt) * 64 + lane) * 8;
        const u16* wq = wlo + ((size_t)(181 + wid * 2 + kt) * 64 + lane) * 8;
        s16x8 wh = *(const s16x8*)wp;
        s16x8 wl = *(const s16x8*)wq;
        acc = __builtin_amdgcn_mfma_f32_16x16x32_bf16(ah, wh, acc, 0, 0, 0);
        acc = __builtin_amdgcn_mfma_f32_16x16x32_bf16(ah, wl, acc, 0, 0, 0);
        acc = __builtin_amdgcn_mfma_f32_16x16x32_bf16(al, wh, acc, 0, 0, 0);
      }
#pragma unroll
      for (int r = 0; r < 4; r++) {
        int m = kg * 4 + r;
        float v = elu_f(acc[r]);
        u16 hi = f2bf(v);
        bHi[m * 72 + col] = hi;
        bLo[m * 72 + col] = f2bf(v - bf(hi));
      }
    }
    __syncthreads();
    // layer 2: base 189, bias rb2, elu -> a
    {
      float bn = rb2[col];
      f32x4 acc = {bn, bn, bn, bn};
#pragma unroll
      for (int kt = 0; kt < 2; kt++) {
        s16x8 ah = *(const s16x8*)(bHi + aoff + kt * 32);
        s16x8 al = *(const s16x8*)(bLo + aoff + kt * 32);
        const u16* wp = whi + ((size_t)(189 + wid * 2 + kt) * 64 + lane) * 8;
        const u16* wq = wlo + ((size_t)(189 + wid * 2 + kt) * 64 + lane) * 8;
        s16x8 wh = *(const s16x8*)wp;
        s16x8 wl = *(const s16x8*)wq;
        acc = __builtin_amdgcn_mfma_f32_16x16x32_bf16(ah, wh, acc, 0, 0, 0);
        acc = __builtin_amdgcn_mfma_f32_16x16x32_bf16(ah, wl, acc, 0, 0, 0);
        acc = __builtin_amdgcn_mfma_f32_16x16x32_bf16(al, wh, acc, 0, 0, 0);
      }
#pragma unroll
      for (int r = 0; r < 4; r++) {
        int m = kg * 4 + r;
        float v = elu_f(acc[r]);
        u16 hi = f2bf(v);
        aHi[m * 72 + col] = hi;
        aLo[m * 72 + col] = f2bf(v - bf(hi));
      }
    }
    __syncthreads();
    // layer 3: base 197, bias rb3, no act -> global
    {
      float bn = rb3[col];
      f32x4 acc = {bn, bn, bn, bn};
#pragma unroll
      for (int kt = 0; kt < 2; kt++) {
        s16x8 ah = *(const s16x8*)(aHi + aoff + kt * 32);
        s16x8 al = *(const s16x8*)(aLo + aoff + kt * 32);
        const u16* wp = whi + ((size_t)(197 + wid * 2 + kt) * 64 + lane) * 8;
        const u16* wq = wlo + ((size_t)(197 + wid * 2 + kt) * 64 + lane) * 8;
        s16x8 wh = *(const s16x8*)wp;
        s16x8 wl = *(const s16x8*)wq;
        acc = __builtin_amdgcn_mfma_f32_16x16x32_bf16(ah, wh, acc, 0, 0, 0);
        acc = __builtin_amdgcn_mfma_f32_16x16x32_bf16(ah, wl, acc, 0, 0, 0);
        acc = __builtin_amdgcn_mfma_f32_16x16x32_bf16(al, wh, acc, 0, 0, 0);
      }
#pragma unroll
      for (int r = 0; r < 4; r++) {
        int gn = g0 + kg * 4 + r;
        if (gn < N) outrec[gn * 64 + col] = acc[r];
      }
    }
    __syncthreads();
  }
}

// ---------------- degree count: 8-way XCD-replicated ----------------
__global__ void k_deg(const int* __restrict__ ei, int* __restrict__ deg8, int E, int N,
                      const int* __restrict__ i32flag) {
  int e = blockIdx.x * 256 + threadIdx.x;
  if (e >= E + N) return;
  int r = blockIdx.x & 7;
  int dst;
  if (e < E) {
    if (*i32flag) dst = ei[E + e];
    else { const ll* el = (const ll*)ei; dst = (int)el[E + e]; }
  } else dst = e - E;
  atomicAdd(&deg8[r * N + dst], 1);
}

// ---------------- coalesced scan: A (block sums), B (scan sums), C (final) --
__global__ void k_scanA(const int* __restrict__ deg8, int* __restrict__ bsum, int N) {
  __shared__ int red[256];
  int tid = threadIdx.x;
  int base = blockIdx.x * 1024;
  int s = 0;
#pragma unroll
  for (int q = 0; q < 4; q++) {
    int n = base + q * 256 + tid;
    if (n < N) {
#pragma unroll
      for (int r = 0; r < 8; r++) s += deg8[r * N + n];
    }
  }
  red[tid] = s; __syncthreads();
  for (int o = 128; o > 0; o >>= 1) {
    if (tid < o) red[tid] += red[tid + o];
    __syncthreads();
  }
  if (tid == 0) bsum[blockIdx.x] = red[0];
}

__global__ void k_scanB(const int* __restrict__ bsum, int* __restrict__ bscan,
                        int* __restrict__ offs, int NB, int N) {
  if (threadIdx.x == 0) {
    int run = 0;
    for (int b = 0; b < NB; b++) { bscan[b] = run; run += bsum[b]; }
    offs[N] = run;
  }
}

__global__ void k_scanC(const int* __restrict__ deg8, const int* __restrict__ bscan,
                        int* __restrict__ offs, int* __restrict__ cursor8, int N) {
  __shared__ int dt[1024];
  __shared__ int tp[256];
  int tid = threadIdx.x;
  int base = blockIdx.x * 1024;
#pragma unroll
  for (int q = 0; q < 4; q++) {
    int n = base + q * 256 + tid;
    int s = 0;
    if (n < N) {
#pragma unroll
      for (int r = 0; r < 8; r++) s += deg8[r * N + n];
    }
    dt[q * 256 + tid] = s;
  }
  __syncthreads();
  int t4 = tid * 4;
  int l0 = dt[t4], l1 = dt[t4 + 1], l2 = dt[t4 + 2], l3 = dt[t4 + 3];
  int tot = l0 + l1 + l2 + l3;
  tp[tid] = tot; __syncthreads();
  for (int o = 1; o < 256; o <<= 1) {
    int v = (tid >= o) ? tp[tid - o] : 0;
    __syncthreads();
    tp[tid] += v;
    __syncthreads();
  }
  int run = bscan[blockIdx.x] + tp[tid] - tot;
#pragma unroll
  for (int k = 0; k < 4; k++) {
    int n = base + t4 + k;
    if (n < N) {
      offs[n] = run;
      int b = run;
#pragma unroll
      for (int r = 0; r < 8; r++) { cursor8[r * N + n] = b; b += deg8[r * N + n]; }
      run = b;
    }
  }
}

// ---------------- scatter: bf16x8 eattr (+packed src) into CSR order --------
template <bool PACKED>
__global__ void k_scatter(const int* __restrict__ ei, const float* __restrict__ eattr,
                          int* __restrict__ cursor8, int* __restrict__ csr_src,
                          uint4* __restrict__ ea2, int E, int N,
                          const int* __restrict__ i32flag) {
  int e = blockIdx.x * 256 + threadIdx.x;
  if (e >= E + N) return;
  int r = blockIdx.x & 7;
  int src, dst;
  u16 p[8];
  if (e < E) {
    if (*i32flag) { src = ei[e]; dst = ei[E + e]; }
    else { const ll* el = (const ll*)ei; src = (int)el[e]; dst = (int)el[E + e]; }
    const float* ea = eattr + (size_t)e * 7;
#pragma unroll
    for (int q = 0; q < 7; q++) p[q] = f2bf(ea[q]);
    p[7] = 0;
  } else {
    src = e - E; dst = src;
#pragma unroll
    for (int q = 0; q < 8; q++) p[q] = 0;
    p[6] = 0x3F80;   // FILL: e_6 = 1.0
  }
  int pos = atomicAdd(&cursor8[r * N + dst], 1);
  uint4 U;
  U.x = ((unsigned)p[1] << 16) | p[0];
  U.y = ((unsigned)p[3] << 16) | p[2];
  U.z = ((unsigned)p[5] << 16) | p[4];
  if (PACKED) {
    U.w = ((unsigned)src << 16) | p[6];
  } else {
    U.w = ((unsigned)p[7] << 16) | p[6];
    csr_src[pos] = src;
  }
  ea2[pos] = U;
}

// ---------------- fused GAT: persistent, wave/node, 16 lanes/edge ----------
// R26: depth-3 pipeline — records for b+1..b+3 in flight, gathers for
// b+1,b+2 in flight (2 iterations of latency cover on the random xlb read).
template <bool PACKED>
__global__ void k_gat(const int* __restrict__ offs, const int* __restrict__ csr_src,
                      const uint4* __restrict__ ea2,
                      const u16* __restrict__ xlb, const float* __restrict__ xr,
                      const float* __restrict__ Wew, const float* __restrict__ attw,
                      float* __restrict__ gat, double* __restrict__ s3, int N) {
  __shared__ float sb[4][64];
  int tid = threadIdx.x;
  int wid = tid >> 6;          // wave id in block = node slot
  int lane = tid & 63;
  int g = lane >> 4;           // edge slot within 4-edge batch
  int l = lane & 15;           // channel quad index: owns channels 4l..4l+3
  int Nc = (N + 3) >> 2;

  // per-lane constants in registers
  float4 wq[7];
#pragma unroll
  for (int q = 0; q < 7; q++) wq[q] = *(const float4*)(Wew + q * 64 + 4 * l);
  float4 attv = *(const float4*)(attw + 4 * l);

  // running per-channel stats (meaningful on g==0 lanes only)
  float ts0 = 0.f, ts1 = 0.f, ts2 = 0.f, ts3 = 0.f;
  float tq0 = 0.f, tq1 = 0.f, tq2 = 0.f, tq3 = 0.f;

  for (int chunk = blockIdx.x; chunk < Nc; chunk += gridDim.x) {
    int node = chunk * 4 + wid;
    if (node >= N) continue;
    float4 xrv = *(const float4*)(xr + node * 64 + 4 * l);
    int st = offs[node];
    int dg = offs[node + 1] - st;
    int nb = (dg + 3) >> 2;
    float sden = 0.f;
    float a0 = 0.f, a1 = 0.f, a2 = 0.f, a3 = 0.f;

    // ---- prologue: records b0,b1,b2; gathers b0,b1 (pad-safe to +16) ----
    int i0 = st + g;
    uint4 U0 = ea2[i0];
    uint4 U1 = ea2[i0 + 4];
    uint4 U2 = ea2[i0 + 8];
    int sc0, sc1, scQ;
    if (PACKED) {
      sc0 = (int)(U0.w >> 16);
      sc1 = (int)(U1.w >> 16);
      scQ = 0;
    } else {
      sc0 = csr_src[i0];
      sc1 = csr_src[i0 + 4];
      scQ = csr_src[i0 + 8];     // src for batch b+2 (non-packed)
    }
    sc0 = ((unsigned)sc0 < (unsigned)N) ? sc0 : 0;
    sc1 = ((unsigned)sc1 < (unsigned)N) ? sc1 : 0;
    uint2 xw0 = *(const uint2*)(xlb + sc0 * 64 + 4 * l);   // batch 0 gather
    uint2 xw1 = *(const uint2*)(xlb + sc1 * 64 + 4 * l);   // batch 1 gather

    for (int b = 0; b < nb; b++) {
      // stage A: issue record load for batch b+3 (max idx st+dg+14 < pad 16)
      int iA = st + (b + 3) * 4 + g;
      uint4 UA = ea2[iA];
      int scA = PACKED ? 0 : csr_src[iA];
      // stage B: issue gather for batch b+2 (U2/scQ landed >=1 iter ago)
      int scg = PACKED ? (int)(U2.w >> 16) : scQ;
      scg = ((unsigned)scg < (unsigned)N) ? scg : 0;
      uint2 xw2 = *(const uint2*)(xlb + scg * 64 + 4 * l);
      // stage C: compute batch b from U0/xw0 (gather issued 2 iters ago)
      bool valid = (b * 4 + g) < dg;
      float x0 = bflo(xw0.x), x1 = bfhi(xw0.x), x2 = bflo(xw0.y), x3 = bfhi(xw0.y);
      float e0 = bflo(U0.x), e1 = bfhi(U0.x), e2 = bflo(U0.y), e3 = bfhi(U0.y);
      float e4 = bflo(U0.z), e5 = bfhi(U0.z), e6 = bflo(U0.w);
      float m0 = x0 + xrv.x + e0*wq[0].x + e1*wq[1].x + e2*wq[2].x + e3*wq[3].x + e4*wq[4].x + e5*wq[5].x + e6*wq[6].x;
      float m1 = x1 + xrv.y + e0*wq[0].y + e1*wq[1].y + e2*wq[2].y + e3*wq[3].y + e4*wq[4].y + e5*wq[5].y + e6*wq[6].y;
      float m2 = x2 + xrv.z + e0*wq[0].z + e1*wq[1].z + e2*wq[2].z + e3*wq[3].z + e4*wq[4].z + e5*wq[5].z + e6*wq[6].z;
      float m3 = x3 + xrv.w + e0*wq[0].w + e1*wq[1].w + e2*wq[2].w + e3*wq[3].w + e4*wq[4].w + e5*wq[5].w + e6*wq[6].w;
      m0 = m0 > 0.f ? m0 : 0.2f * m0;
      m1 = m1 > 0.f ? m1 : 0.2f * m1;
      m2 = m2 > 0.f ? m2 : 0.2f * m2;
      m3 = m3 > 0.f ? m3 : 0.2f * m3;
      float pp = m0 * attv.x + m1 * attv.y + m2 * attv.z + m3 * attv.w;
      pp += __shfl_xor(pp, 1, 64);     // quad reduce: 4 lanes = 16 channels = head
      pp += __shfl_xor(pp, 2, 64);
      float ex = valid ? __expf(pp) : 0.f;
      sden += ex;
      a0 += ex * x0; a1 += ex * x1; a2 += ex * x2; a3 += ex * x3;
      // rotate pipeline registers
      xw0 = xw1; xw1 = xw2;
      U0 = U1; U1 = U2; U2 = UA;
      scQ = scA;
    }
    // sum over the 4 edge-groups
    a0 += __shfl_xor(a0, 16, 64); a0 += __shfl_xor(a0, 32, 64);
    a1 += __shfl_xor(a1, 16, 64); a1 += __shfl_xor(a1, 32, 64);
    a2 += __shfl_xor(a2, 16, 64); a2 += __shfl_xor(a2, 32, 64);
    a3 += __shfl_xor(a3, 16, 64); a3 += __shfl_xor(a3, 32, 64);
    sden += __shfl_xor(sden, 16, 64); sden += __shfl_xor(sden, 32, 64);
    float inv = 1.f / (sden * (float)dg);
    float val0 = a0 * inv, val1 = a1 * inv, val2 = a2 * inv, val3 = a3 * inv;
    if (g == 0) {
      float4 o = make_float4(val0, val1, val2, val3);
      *(float4*)(gat + node * 64 + 4 * l) = o;
      ts0 += val0; ts1 += val1; ts2 += val2; ts3 += val3;
      tq0 += val0 * val0; tq1 += val1 * val1; tq2 += val2 * val2; tq3 += val3 * val3;
    }
  }

  // ---- block-exit stats reduction: transpose to per-channel, 128 atomics ----
  if (g == 0) {
    sb[wid][4 * l + 0] = ts0; sb[wid][4 * l + 1] = ts1;
    sb[wid][4 * l + 2] = ts2; sb[wid][4 * l + 3] = ts3;
  }
  __syncthreads();
  if (tid < 64) {
    float v = sb[0][tid] + sb[1][tid] + sb[2][tid] + sb[3][tid];
    atomicAdd(&s3[tid], (double)v);
  }
  __syncthreads();
  if (g == 0) {
    sb[wid][4 * l + 0] = tq0; sb[wid][4 * l + 1] = tq1;
    sb[wid][4 * l + 2] = tq2; sb[wid][4 * l + 3] = tq3;
  }
  __syncthreads();
  if (tid < 64) {
    float v = sb[0][tid] + sb[1][tid] + sb[2][tid] + sb[3][tid];
    atomicAdd(&s3[64 + tid], (double)v);
  }
}

// ---------------- atomic fallback (if CSR doesn't fit) ----------------
__global__ void k_edge2(const int* __restrict__ ei, const float* __restrict__ eattr,
                        const u16* __restrict__ xlb, const float* __restrict__ xr,
                        const float* __restrict__ Wew, const float* __restrict__ attw,
                        float* __restrict__ agg, float* __restrict__ denom,
                        int* __restrict__ deg, int E, int N,
                        const int* __restrict__ i32flag) {
  __shared__ float sWe[448];
  __shared__ float satt[64];
  int tid = threadIdx.x;
  for (int k = tid; k < 448; k += 256) sWe[k] = Wew[k];
  if (tid < 64) satt[tid] = attw[tid];
  __syncthreads();
  int e = blockIdx.x * 4 + (tid >> 6);
  if (e >= E + N) return;
  int lane = tid & 63;
  int src, dst;
  if (e < E) {
    if (*i32flag) { src = ei[e]; dst = ei[E + e]; }
    else { const ll* el = (const ll*)ei; src = (int)el[e]; dst = (int)el[E + e]; }
  } else { src = e - E; dst = src; }
  float xlv = bf(xlb[src * 64 + lane]);
  float m = xlv + xr[dst * 64 + lane];
  if (e < E) {
#pragma unroll
    for (int k = 0; k < 7; k++) m += eattr[e * 7 + k] * sWe[k * 64 + lane];
  } else {
    m += sWe[6 * 64 + lane];
  }
  float lr = m > 0.f ? m : 0.2f * m;
  float p = lr * satt[lane];
  p += __shfl_xor(p, 1, 64);
  p += __shfl_xor(p, 2, 64);
  p += __shfl_xor(p, 4, 64);
  p += __shfl_xor(p, 8, 64);
  float ex = __expf(p);
  atomicAdd(&agg[dst * 64 + lane], ex * xlv);
  if ((lane & 15) == 0) atomicAdd(&denom[dst * 4 + (lane >> 4)], ex);
  if (lane == 0) atomicAdd(&deg[dst], 1);
}

__global__ void k_gatnorm(float* __restrict__ agg, const float* __restrict__ denom,
                          const int* __restrict__ deg, double* __restrict__ s3, int N) {
  __shared__ float red[256];
  int tid = threadIdx.x;
  int idx = blockIdx.x * 256 + tid;
  float v = 0.f;
  if (idx < N * 64) {
    int n = idx >> 6, c = idx & 63, h = c >> 4;
    v = agg[idx] / (denom[n * 4 + h] * (float)deg[n]);
    agg[idx] = v;
  }
  red[tid] = v; __syncthreads();
  if (tid < 64) atomicAdd(&s3[tid], (double)(red[tid] + red[tid + 64] + red[tid + 128] + red[tid + 192]));
  __syncthreads();
  red[tid] = v * v; __syncthreads();
  if (tid < 64) atomicAdd(&s3[64 + tid], (double)(red[tid] + red[tid + 64] + red[tid + 128] + red[tid + 192]));
}

// ---------------- h4 = elu(h3 + inorm(gat)) ----------------
__global__ void k_h4(const float* __restrict__ jk, const float* __restrict__ gat,
                     const float* __restrict__ gn_w, const float* __restrict__ gn_b,
                     const double* __restrict__ s3, float* __restrict__ h4, int N) {
  __shared__ float na[64], nb[64];
  int tid = threadIdx.x;
  if (tid < 64) norm_coeffs(s3, tid, N, gn_w, gn_b, na, nb);
  __syncthreads();
  int idx = blockIdx.x * 256 + tid;
  if (idx >= N * 64) return;
  int c = idx & 63;
  h4[idx] = elu_f(jk[idx] + gat[idx] * na[c] + nb[c]);
}

// ---------------- decoder: MFMA split-bf16 layer -----------------------------
template <int LIN, int LOUT, int TBASE>
__device__ __forceinline__ void mfmaLayer(const u16* __restrict__ whi, const u16* __restrict__ wlo,
                                          const float* __restrict__ bias,
                                          const u16* __restrict__ Ahi, const u16* __restrict__ Alo,
                                          u16* __restrict__ Ohi, u16* __restrict__ Olo,
                                          int wid, int lane) {
  constexpr int KT = LIN / 32, NT = LOUT / 16;
  constexpr int SIN = LIN + 8, SOUT = LOUT + 8;
  int l15 = lane & 15, kg = lane >> 4;
  int aoff = l15 * SIN + kg * 8;
  for (int nt = wid; nt < NT; nt += 4) {
    float bn = bias[nt * 16 + l15];
    f32x4 acc = {bn, bn, bn, bn};
    for (int kt = 0; kt < KT; kt++) {
      s16x8 ah = *(const s16x8*)(Ahi + aoff + kt * 32);
      s16x8 al = *(const s16x8*)(Alo + aoff + kt * 32);
      const u16* wp = whi + ((size_t)(TBASE + nt * KT + kt) * 64 + lane) * 8;
      const u16* wq = wlo + ((size_t)(TBASE + nt * KT + kt) * 64 + lane) * 8;
      s16x8 wh = *(const s16x8*)(wp);
      s16x8 wl = *(const s16x8*)(wq);
      acc = __builtin_amdgcn_mfma_f32_16x16x32_bf16(ah, wh, acc, 0, 0, 0);
      acc = __builtin_amdgcn_mfma_f32_16x16x32_bf16(ah, wl, acc, 0, 0, 0);
      acc = __builtin_amdgcn_mfma_f32_16x16x32_bf16(al, wh, acc, 0, 0, 0);
    }
#pragma unroll
    for (int r = 0; r < 4; r++) {
      int m = kg * 4 + r;
      float v = elu_f(acc[r]);
      u16 hi = f2bf(v);
      u16 lo = f2bf(v - bf(hi));
      Ohi[m * SOUT + nt * 16 + l15] = hi;
      Olo[m * SOUT + nt * 16 + l15] = lo;
    }
  }
}

__global__ void k_dec(const float* __restrict__ jk, const float* __restrict__ h4,
                      const u16* __restrict__ whi, const u16* __restrict__ wlo,
                      const float* __restrict__ db1, const float* __restrict__ db2,
                      const float* __restrict__ db3, const float* __restrict__ db4,
                      const float* __restrict__ db5,
                      const float* __restrict__ dW6, const float* __restrict__ db6,
                      float* __restrict__ outdec, int N) {
  // ping-pong act buffers, bf16 hi/lo, [16 nodes][stride] (stride = LIN+8)
  __shared__ __align__(16) u16 bHi0[16 * 264], bLo0[16 * 264];
  __shared__ __align__(16) u16 bHi1[16 * 264], bLo1[16 * 264];
  int tid = threadIdx.x;
  int wid = tid >> 6, lane = tid & 63;
  int g0 = blockIdx.x * 16;
  // stage input: [node][136] = 128 ch of (jk | h4), bf16 hi/lo
  for (int k = tid; k < 16 * 128; k += 256) {
    int i = k & 127, node = k >> 7;
    int gn = g0 + node;
    float v = 0.f;
    if (gn < N) v = (i < 64) ? jk[gn * 64 + i] : h4[gn * 64 + (i - 64)];
    u16 hi = f2bf(v);
    u16 lo = f2bf(v - bf(hi));
    bHi0[node * 136 + i] = hi;
    bLo0[node * 136 + i] = lo;
  }
  __syncthreads();
  mfmaLayer<128, 256, 0>(whi, wlo, db1, bHi0, bLo0, bHi1, bLo1, wid, lane); __syncthreads();
  mfmaLayer<256, 128, 64>(whi, wlo, db2, bHi1, bLo1, bHi0, bLo0, wid, lane); __syncthreads();
  mfmaLayer<128, 64, 128>(whi, wlo, db3, bHi0, bLo0, bHi1, bLo1, wid, lane); __syncthreads();
  mfmaLayer<64, 32, 144>(whi, wlo, db4, bHi1, bLo1, bHi0, bLo0, wid, lane); __syncthreads();
  mfmaLayer<32, 16, 148>(whi, wlo, db5, bHi0, bLo0, bHi1, bLo1, wid, lane); __syncthreads();
  // final 16 -> 2 (fp32 scalar; act rows stride 24)
  if (tid < 32) {
    int node = tid >> 1, j = tid & 1;
    int gn = g0 + node;
    if (gn < N) {
      float s = db6[j];
#pragma unroll
      for (int i = 0; i < 16; i++) {
        float a = bf(bHi1[node * 24 + i]) + bf(bLo1[node * 24 + i]);
        s += a * dW6[i * 2 + j];
      }
      outdec[gn * 2 + j] = s;
    }
  }
}

// ---------------- sentinel ----------------
__global__ void k_sentinel(float* __restrict__ out, float v) {
  if (threadIdx.x == 0) out[0] = v;
}

extern "C" void kernel_launch(void* const* d_in, const int* in_sizes, int n_in,
                              void* d_out, int out_size, void* d_ws, size_t ws_size,
                              hipStream_t stream) {
  (void)n_in; (void)out_size;
  const float* x     = (const float*)d_in[0];
  const int*   ei    = (const int*)d_in[1];
  const float* ea    = (const float*)d_in[2];
  const float* pre_w = (const float*)d_in[3];
  const float* pre_b = (const float*)d_in[4];
  const float* eW1   = (const float*)d_in[5];
  const float* en1w  = (const float*)d_in[6];
  const float* en1b  = (const float*)d_in[7];
  const float* eW2   = (const float*)d_in[8];
  const float* en2w  = (const float*)d_in[9];
  const float* en2b  = (const float*)d_in[10];
  const float* Wl    = (const float*)d_in[11];
  const float* Wr    = (const float*)d_in[12];
  const float* Wew   = (const float*)d_in[13];
  const float* attw  = (const float*)d_in[14];
  const float* gn_w  = (const float*)d_in[15];
  const float* gn_b  = (const float*)d_in[16];
  const float* dW1 = (const float*)d_in[17]; const float* db1 = (const float*)d_in[18];
  const float* dW2 = (const float*)d_in[19]; const float* db2 = (const float*)d_in[20];
  const float* dW3 = (const float*)d_in[21]; const float* db3 = (const float*)d_in[22];
  const float* dW4 = (const float*)d_in[23]; const float* db4 = (const float*)d_in[24];
  const float* dW5 = (const float*)d_in[25]; const float* db5 = (const float*)d_in[26];
  const float* dW6 = (const float*)d_in[27]; const float* db6 = (const float*)d_in[28];
  const float* rW1 = (const float*)d_in[29]; const float* rb1 = (const float*)d_in[30];
  const float* rW2 = (const float*)d_in[31]; const float* rb2 = (const float*)d_in[32];
  const float* rW3 = (const float*)d_in[33]; const float* rb3 = (const float*)d_in[34];

  int D  = in_sizes[3];
  int N  = in_sizes[0] / (D > 0 ? D : 1);
  int E  = in_sizes[1] / 2;
  int ED = E > 0 ? in_sizes[2] / E : 0;
  float* outdec = (float*)d_out;
  float* outrec = outdec + (size_t)N * 2;
  if (D != 64 || ED != 7 || in_sizes[14] != 64) {
    k_sentinel<<<1, 64, 0, stream>>>(outdec, 2000.f);
    return;
  }
  int Etot = E + N;

  char* w = (char*)d_ws;
  size_t off = 0;
  auto alloc = [&](size_t bytes) -> void* {
    void* p = w + off;
    off += (bytes + 255) & ~(size_t)255;
    return p;
  };
  const size_t FEATF = (size_t)N * 64 * 4;
  float* B1    = (float*)alloc(FEATF);             // t1 -> gat (or agg fallback)
  size_t ea2_bytes = ((size_t)Etot + 16) * 16;     // +16 pad: pipeline prefetch depth
  size_t b2ext = ea2_bytes > FEATF ? ea2_bytes : FEATF;
  float* B2    = (float*)alloc(b2ext);
  float* jk    = (float*)alloc(FEATF);
  u16*   xlb   = (u16*)  alloc((size_t)N * 64 * 2);
  float* xr    = (float*)alloc(FEATF);
  int*   offs  = (int*)  alloc(((size_t)N + 1) * 4);
  int*   deg8  = (int*)  alloc((size_t)N * 8 * 4);
  int*   cursor8=(int*)  alloc((size_t)N * 8 * 4);
  int*   bsum  = (int*)  alloc(4096);
  int*   bscan = (int*)  alloc(4096);
  double* stats = (double*)alloc(4 * 128 * 8);
  int* i32flag = (int*)alloc(256);
  float* denom = (float*)alloc((size_t)N * 4 * 4);  // fallback only
  u16* whi = (u16*)alloc((size_t)205 * 512 * 2);    // fragment-ordered bf16 hi
  u16* wlo = (u16*)alloc((size_t)205 * 512 * 2);    // fragment-ordered bf16 lo
  size_t base_off = off;
  int* csr_src = (int*)alloc(((size_t)Etot + 16) * 4);  // +16 pad (unpacked path)
  size_t csr_off = off;

  double* s0 = stats, *s1 = stats + 128, *s2 = stats + 256, *s3 = stats + 384;
  float* t1 = B1; float* gat = B1; float* agg = B1;
  float* t2 = B2; float* h4 = B2;
  uint4* ea2 = (uint4*)B2;   // aliases t2 (dead after k_enc3M)

  bool packed = (N <= 65536);
  bool use_csr = packed ? (base_off <= ws_size) : (csr_off <= ws_size);
  if (!use_csr && base_off > ws_size) {
    k_sentinel<<<1, 64, 0, stream>>>(outdec, 1000.f);
    return;
  }

  hipMemsetAsync(stats, 0, 4 * 128 * 8, stream);
  hipMemsetAsync(i32flag, 0, 256, stream);
  hipMemsetAsync(deg8, 0, (size_t)N * 8 * 4, stream);

  int gN64 = (N * 64 + 255) / 256;
  int gE = (Etot + 255) / 256;
  int probeCnt = E < 1024 ? E : 1024;
  int NB = (N + 1023) / 1024;
  int Nc16 = (N + 15) / 16;
  int gEnc = Nc16 < 2048 ? Nc16 : 2048;

  k_probe64<<<1, 256, 0, stream>>>(ei, probeCnt, i32flag);
  k_wprep<<<205, 256, 0, stream>>>(dW1, dW2, dW3, dW4, dW5, eW1, eW2, Wl, Wr,
                                   rW1, rW2, rW3, whi, wlo);
  k_stats_x<<<1024, 256, 0, stream>>>(x, N, s0);
  k_encM<false><<<gEnc, 256, 0, stream>>>(x, pre_w, pre_b, whi, wlo, 149, s0, t1, s1, N);
  k_encM<true><<<gEnc, 256, 0, stream>>>(t1, en1w, en1b, whi, wlo, 157, s1, t2, s2, N);
  k_enc3M<<<gEnc, 256, 0, stream>>>(t2, en2w, en2b, whi, wlo, s2, jk, xlb, xr, N);

  if (use_csr) {
    k_deg<<<gE, 256, 0, stream>>>(ei, deg8, E, N, i32flag);
    k_scanA<<<NB, 256, 0, stream>>>(deg8, bsum, N);
    k_scanB<<<1, 64, 0, stream>>>(bsum, bscan, offs, NB, N);
    k_scanC<<<NB, 256, 0, stream>>>(deg8, bscan, offs, cursor8, N);
    int ggat = 2048;
    int NcG = (N + 3) / 4;
    if (ggat > NcG) ggat = NcG;
    if (packed) {
      k_scatter<true><<<gE, 256, 0, stream>>>(ei, ea, cursor8, csr_src, ea2, E, N, i32flag);
      k_gat<true><<<ggat, 256, 0, stream>>>(offs, csr_src, ea2, xlb, xr, Wew, attw,
                                            gat, s3, N);
    } else {
      k_scatter<false><<<gE, 256, 0, stream>>>(ei, ea, cursor8, csr_src, ea2, E, N, i32flag);
      k_gat<false><<<ggat, 256, 0, stream>>>(offs, csr_src, ea2, xlb, xr, Wew, attw,
                                             gat, s3, N);
    }
  } else {
    hipMemsetAsync(agg, 0, FEATF, stream);
    hipMemsetAsync(denom, 0, (size_t)N * 4 * 4, stream);
    k_edge2<<<(Etot + 3) / 4, 256, 0, stream>>>(ei, ea, xlb, xr, Wew, attw, agg, denom,
                                                deg8, E, N, i32flag);
    k_gatnorm<<<gN64, 256, 0, stream>>>(agg, denom, deg8, s3, N);
  }

  k_h4<<<gN64, 256, 0, stream>>>(jk, gat, gn_w, gn_b, s3, h4, N);
  k_dec<<<Nc16, 256, 0, stream>>>(jk, h4, whi, wlo, db1, db2, db3, db4, db5,
                                  dW6, db6, outdec, N);
  k_reconM<<<gEnc, 256, 0, stream>>>(h4, whi, wlo, rb1, rb2, rb3, outrec, N);
}